// Round 3
// baseline (13003.076 us; speedup 1.0000x reference)
//
#include <hip/hip_runtime.h>
#include <math.h>

#define D_    1024
#define B_    2
#define N_    512
#define SEG_  128
#define NSEG_ 4
#define NPT_  16
#define T_    272
#define NH_   16
#define HD_   64
#define W_    128
#define V_    32000

#define THETA_ 0.1f
#define ETA_   0.9f
#define PDEC_  0.99f
#define EPSN_  1e-6f
#define NBLK_ 16

// ---------------- workspace layout (float offsets) ----------------
static const size_t XEMB = 0;                       // [B,N,D]
static const size_t OUTS = XEMB + (size_t)B_*N_*D_; // [B,N,D]
static const size_t PW1  = OUTS + (size_t)B_*N_*D_; // [B,1024,128]
static const size_t PB1  = PW1  + (size_t)B_*D_*W_; // [B,128]
static const size_t PW2T = PB1  + (size_t)B_*W_;    // [B,1024,128]  (W2 transposed: [j][h])
static const size_t PB2  = PW2T + (size_t)B_*D_*W_; // [B,1024]
static const size_t MOM  = PB2  + (size_t)B_*D_;    // momentum block (contiguous, memset 0)
static const size_t MW1  = MOM;
static const size_t MB1  = MW1  + (size_t)B_*D_*W_;
static const size_t MW2T = MB1  + (size_t)B_*W_;
static const size_t MB2  = MW2T + (size_t)B_*D_*W_;
static const size_t MOMSZ = (size_t)B_*(D_*W_ + W_ + D_*W_ + D_);
static const size_t Q1   = MOM  + MOMSZ;            // [B,128,1024]
static const size_t AH   = Q1   + (size_t)B_*SEG_*D_; // [B,128,128]
static const size_t HBUF = AH   + (size_t)B_*SEG_*W_; // [B,128,1024]
static const size_t COMB = HBUF + (size_t)B_*SEG_*D_; // [B,272,1024]
static const size_t QKV  = COMB + (size_t)B_*T_*D_;   // [B,272,3072]
static const size_t ATTN = QKV  + (size_t)B_*T_*3*D_; // [B,128,1024]
static const size_t SEGO = ATTN + (size_t)B_*SEG_*D_; // [B,128,1024]
static const size_t KM   = SEGO + (size_t)B_*SEG_*D_; // [B,128,1024]
static const size_t VM   = KM   + (size_t)B_*SEG_*D_; // [B,128,1024]
static const size_t MEMO = VM   + (size_t)B_*SEG_*D_; // [B,128,1024]
static const size_t WSEND = MEMO + (size_t)B_*SEG_*D_;

// scan-phase buffers ALIAS the QKV region (QKV consumed by k_attn before these
// are written; recon reads them before next segment's QKV GEMM overwrites).
static const size_t AQ1K  = QKV;                 // [B,128,128]
static const size_t AQ1KM = AQ1K  + 32768;       // [B,128,128]
static const size_t AGRAM = AQ1KM + 32768;       // [B,128,128]
static const size_t ADZ1  = AGRAM + 32768;       // [B,128,128]
static const size_t AA1H  = ADZ1  + 32768;       // [B,128,128]
static const size_t AEH   = AA1H  + 32768;       // [B,128,1024]
static const size_t AEXA1 = AEH + (size_t)B_*SEG_*D_;  // [2][B][128]
static const size_t AEXSP = AEXA1 + 512;         // [2][B][16][128]
static const size_t AEXR  = AEXSP + 8192;
static const size_t AEXEE = AEXR  + 8192;
// persistent tail (must NOT alias QKV)
static const size_t COEF  = WSEND;               // A[128], etaPow[128], betaPow[129]
static const size_t ZEROB = COEF + 512;          // 128 zeros (GEMM zero-bias)
static const size_t CBAR  = ZEROB + 128;         // 16 ints barrier state

__device__ __forceinline__ float sigf(float x) { return 1.f/(1.f+expf(-x)); }

// ---------------- generic tiled fp32 GEMM ----------------
template<int BT, int SILU>
__global__ __launch_bounds__(256) void k_gemm(
    const float* __restrict__ A, const float* __restrict__ Bm,
    const float* __restrict__ bias, float* __restrict__ C,
    int M, int N, int K, long sA, long sB, long sC, long sBias)
{
  __shared__ float As[16][68];
  __shared__ float Bs[16][68];
  int bz = blockIdx.z;
  A += bz*sA; Bm += bz*sB; C += bz*sC; bias += bz*sBias;
  int n0 = blockIdx.x*64, m0 = blockIdx.y*64;
  int tid = threadIdx.x;
  int tx = tid & 15, ty = tid >> 4;
  int r  = tid >> 2;
  int kq = (tid & 3) * 4;
  float acc[4][4] = {};
  for (int k0 = 0; k0 < K; k0 += 16) {
    {
      int row = m0 + r;
      float4 v = make_float4(0.f,0.f,0.f,0.f);
      if (row < M) v = *(const float4*)(A + (long)row*K + k0 + kq);
      As[kq+0][r]=v.x; As[kq+1][r]=v.y; As[kq+2][r]=v.z; As[kq+3][r]=v.w;
    }
    if (BT) {
      int row = n0 + r;
      float4 v = *(const float4*)(Bm + (long)row*K + k0 + kq);
      Bs[kq+0][r]=v.x; Bs[kq+1][r]=v.y; Bs[kq+2][r]=v.z; Bs[kq+3][r]=v.w;
    } else {
      int c = tid & 63, r4 = tid >> 6;
      #pragma unroll
      for (int p = 0; p < 4; p++) {
        int kk = r4 + p*4;
        Bs[kk][c] = Bm[(long)(k0+kk)*N + n0 + c];
      }
    }
    __syncthreads();
    #pragma unroll
    for (int kk = 0; kk < 16; kk++) {
      float av[4], bv[4];
      #pragma unroll
      for (int i=0;i<4;i++) av[i] = As[kk][ty*4+i];
      #pragma unroll
      for (int j=0;j<4;j++) bv[j] = Bs[kk][tx*4+j];
      #pragma unroll
      for (int i=0;i<4;i++)
        #pragma unroll
        for (int j=0;j<4;j++)
          acc[i][j] = fmaf(av[i], bv[j], acc[i][j]);
    }
    __syncthreads();
  }
  #pragma unroll
  for (int i=0;i<4;i++) {
    int row = m0 + ty*4 + i;
    if (row >= M) continue;
    #pragma unroll
    for (int j=0;j<4;j++) {
      int col = n0 + tx*4 + j;
      float v = acc[i][j] + bias[col];
      if (SILU) v = v * sigf(v);
      C[(long)row*N + col] = v;
    }
  }
}

// ---------------- small kernels ----------------
__global__ void k_embed(const int* __restrict__ x, const float* __restrict__ emb,
                        float* __restrict__ xe)
{
  int row = blockIdx.x, tid = threadIdx.x;
  int idx = x[row];
  float4 v = *(const float4*)(emb + (long)idx*D_ + tid*4);
  *(float4*)(xe + (long)row*D_ + tid*4) = v;
}

#define PER_ 263296L
__global__ void k_init(const float* __restrict__ mW1in, const float* __restrict__ mb1in,
                       const float* __restrict__ mW2in, const float* __restrict__ mb2in,
                       float* __restrict__ pW1, float* __restrict__ pb1,
                       float* __restrict__ pW2T, float* __restrict__ pb2)
{
  long g = (long)blockIdx.x*256 + threadIdx.x;
  if (g >= 2*PER_) return;
  int b = (int)(g / PER_);
  long rr = g % PER_;
  if (rr < 131072)       pW1[(long)b*131072 + rr] = mW1in[rr];
  else if (rr < 131200)  pb1[b*W_ + (rr-131072)] = mb1in[rr-131072];
  else if (rr < 262272) { long l = rr-131200; int j=(int)(l>>7), h=(int)(l&127);
                          pW2T[(long)b*131072 + l] = mW2in[(long)h*D_ + j]; }
  else                   pb2[b*D_ + (rr-262272)] = mb2in[rr-262272];
}

__global__ void k_coef(float* __restrict__ c)
{
  if (blockIdx.x == 0 && threadIdx.x == 0) {
    c[0] = 1.f; c[128] = 1.f;
    float A = 1.f, eta_d = 1.f;
    for (int d = 1; d < 128; d++) {
      eta_d *= ETA_;
      A = PDEC_*A + eta_d;
      c[d] = A;
      c[128 + d] = eta_d;
    }
    c[256] = 1.f;
    float bp = 1.f;
    for (int t = 1; t <= 128; t++) { bp *= PDEC_; c[256 + t] = bp; }
  }
}

__global__ __launch_bounds__(256) void k_l2n(float* __restrict__ X)
{
  long row = blockIdx.x;
  float* p = X + row*D_;
  int tid = threadIdx.x;
  float4 v = *(float4*)(p + tid*4);
  float ss = v.x*v.x + v.y*v.y + v.z*v.z + v.w*v.w;
  for (int o=32;o;o>>=1) ss += __shfl_xor(ss,o);
  __shared__ float wsum[4];
  if ((tid&63)==0) wsum[tid>>6] = ss;
  __syncthreads();
  float tot = wsum[0]+wsum[1]+wsum[2]+wsum[3];
  float sc = 1.f/(sqrtf(tot)+EPSN_);
  v.x*=sc; v.y*=sc; v.z*=sc; v.w*=sc;
  *(float4*)(p + tid*4) = v;
}

__global__ void k_concat(const float* __restrict__ pers, const float* __restrict__ h,
                         const float* __restrict__ xemb, int s, float* __restrict__ comb)
{
  int row = blockIdx.x, b = blockIdx.y, tid = threadIdx.x;
  const float* src;
  if (row < NPT_)            src = pers + (long)row*D_;
  else if (row < NPT_+SEG_)  src = h    + ((long)b*SEG_ + (row-NPT_))*D_;
  else                       src = xemb + ((long)b*N_ + s*SEG_ + (row-NPT_-SEG_))*D_;
  float4 v = *(const float4*)(src + tid*4);
  *(float4*)(comb + ((long)b*T_ + row)*D_ + tid*4) = v;
}

__global__ __launch_bounds__(256) void k_attn(const float* __restrict__ qkv,
                                              float* __restrict__ outp)
{
  __shared__ float sQ[16][68];
  __shared__ float sKV[64][68];
  __shared__ float sS[16][273];
  int qt = blockIdx.x, head = blockIdx.y, b = blockIdx.z;
  int tid = threadIdx.x;
  const float* base = qkv + (long)b*T_*3*D_;
  int qoff = head*HD_, koff = D_ + head*HD_, voff = 2*D_ + head*HD_;
  int qrow0 = NPT_ + SEG_ + qt*16;
  {
    int rr = tid>>4, c4 = (tid&15)*4;
    float4 v = *(const float4*)(base + (long)(qrow0+rr)*3*D_ + qoff + c4);
    sQ[rr][c4]=v.x; sQ[rr][c4+1]=v.y; sQ[rr][c4+2]=v.z; sQ[rr][c4+3]=v.w;
  }
  __syncthreads();
  for (int j0 = 0; j0 < T_; j0 += 64) {
    int chunk = min(64, T_ - j0);
    {
      int jj = tid>>2, cq = (tid&3)*16;
      if (jj < chunk) {
        #pragma unroll
        for (int q4=0;q4<4;q4++) {
          float4 v = *(const float4*)(base + (long)(j0+jj)*3*D_ + koff + cq + q4*4);
          sKV[jj][cq+q4*4]=v.x; sKV[jj][cq+q4*4+1]=v.y; sKV[jj][cq+q4*4+2]=v.z; sKV[jj][cq+q4*4+3]=v.w;
        }
      }
    }
    __syncthreads();
    int rr = tid>>4, jj0 = tid&15;
    #pragma unroll
    for (int p=0;p<4;p++) {
      int jj = jj0 + p*16;
      if (jj < chunk) {
        float s = 0.f;
        #pragma unroll 8
        for (int c=0;c<HD_;c++) s = fmaf(sQ[rr][c], sKV[jj][c], s);
        s *= 0.125f;
        int jg = j0 + jj, qg = qrow0 + rr;
        if (jg > qg) s = -3.0e38f;
        sS[rr][jg] = s;
      }
    }
    __syncthreads();
  }
  {
    int rr = tid>>4, l16 = tid&15;
    float m = -3.4e38f;
    for (int j=l16; j<T_; j+=16) m = fmaxf(m, sS[rr][j]);
    for (int o=8;o;o>>=1) m = fmaxf(m, __shfl_xor(m,o));
    float sum = 0.f;
    for (int j=l16; j<T_; j+=16) { float e = expf(sS[rr][j]-m); sS[rr][j] = e; sum += e; }
    for (int o=8;o;o>>=1) sum += __shfl_xor(sum,o);
    float inv = 1.f/sum;
    for (int j=l16; j<T_; j+=16) sS[rr][j] *= inv;
  }
  __syncthreads();
  float acc[4] = {0.f,0.f,0.f,0.f};
  int rr = tid>>4, c4 = (tid&15)*4;
  for (int j0 = 0; j0 < T_; j0 += 64) {
    int chunk = min(64, T_ - j0);
    {
      int jj = tid>>2, cq = (tid&3)*16;
      if (jj < chunk) {
        #pragma unroll
        for (int q4=0;q4<4;q4++) {
          float4 v = *(const float4*)(base + (long)(j0+jj)*3*D_ + voff + cq + q4*4);
          sKV[jj][cq+q4*4]=v.x; sKV[jj][cq+q4*4+1]=v.y; sKV[jj][cq+q4*4+2]=v.z; sKV[jj][cq+q4*4+3]=v.w;
        }
      }
    }
    __syncthreads();
    for (int jj=0; jj<chunk; jj++) {
      float p = sS[rr][j0+jj];
      #pragma unroll
      for (int i=0;i<4;i++) acc[i] = fmaf(p, sKV[jj][c4+i], acc[i]);
    }
    __syncthreads();
  }
  float4 o4 = make_float4(acc[0],acc[1],acc[2],acc[3]);
  *(float4*)(outp + ((long)(b*SEG_) + qt*16 + rr)*D_ + head*HD_ + c4) = o4;
}

// ---------------- device-wide sense barrier (per sample, NBLK_ blocks) ------
__device__ __forceinline__ void gbarrier(int* cnt, int* gen)
{
  __syncthreads();
  if (threadIdx.x == 0) {
    __threadfence();
    int g = __hip_atomic_load(gen, __ATOMIC_RELAXED, __HIP_MEMORY_SCOPE_AGENT);
    int a = __hip_atomic_fetch_add(cnt, 1, __ATOMIC_ACQ_REL, __HIP_MEMORY_SCOPE_AGENT);
    if (a == NBLK_ - 1) {
      __hip_atomic_store(cnt, 0, __ATOMIC_RELAXED, __HIP_MEMORY_SCOPE_AGENT);
      __hip_atomic_fetch_add(gen, 1, __ATOMIC_RELEASE, __HIP_MEMORY_SCOPE_AGENT);
    } else {
      while (__hip_atomic_load(gen, __ATOMIC_ACQUIRE, __HIP_MEMORY_SCOPE_AGENT) == g)
        __builtin_amdgcn_s_sleep(4);
    }
    __threadfence();
  }
  __syncthreads();
}

// ---------------- persistent token-space scan (one launch per segment) ------
// grid (NBLK_=16, B_), 256 threads. Block owns j-slice [j0,j0+64) and h-slice
// [h0,h0+8). W2T_0/mW2T_0 slices LDS-resident for all 128 tokens.
__global__ __launch_bounds__(256) void k_scan(
  const float* __restrict__ pW2T, const float* __restrict__ mW2T,
  float* __restrict__ pb1, float* __restrict__ mb1,
  float* __restrict__ pb2, float* __restrict__ mb2,
  const float* __restrict__ Vm,
  const float* __restrict__ q1k, const float* __restrict__ q1km,
  const float* __restrict__ G,
  float* __restrict__ dz1o, float* __restrict__ a1o, float* __restrict__ eo,
  float* __restrict__ exA1, float* __restrict__ exSP,
  float* __restrict__ exR, float* __restrict__ exEE,
  const float* __restrict__ coef, int* __restrict__ barbase)
{
  __shared__ float sW[64][132];
  __shared__ float sMW[64][132];
  __shared__ float sEh[128][66];
  __shared__ float sA1h[128][9];
  __shared__ float sDZ[128][9];
  __shared__ float sAt[128];
  __shared__ float sBp[129];
  __shared__ float sB1[8], sMB1[8], sZ1[8], sR[8];
  __shared__ float sB2[64], sMB2[64], sE[64];
  __shared__ float sA1t[128];
  __shared__ float sS[128];
  __shared__ float sEEc[128];

  int b = blockIdx.y, blk = blockIdx.x, tid = threadIdx.x;
  int j0 = blk*64, h0 = blk*8;
  int* cnt = barbase + b*2;
  int* gen = barbase + b*2 + 1;

  for (int i = tid; i < 64*128; i += 256) {
    int jj = i >> 7, h = i & 127;
    sW[jj][h]  = pW2T[(long)b*131072 + (long)(j0+jj)*128 + h];
    sMW[jj][h] = mW2T[(long)b*131072 + (long)(j0+jj)*128 + h];
  }
  if (tid < 128) sAt[tid] = coef[tid];
  for (int i = tid; i < 129; i += 256) sBp[i] = coef[256 + i];
  if (tid < 8)  { sB1[tid] = pb1[b*W_ + h0 + tid]; sMB1[tid] = mb1[b*W_ + h0 + tid]; }
  if (tid >= 64 && tid < 128) {
    int jj = tid - 64;
    sB2[jj] = pb2[b*D_ + j0 + jj]; sMB2[jj] = mb2[b*D_ + j0 + jj];
  }
  __syncthreads();

  for (int t = 0; t < SEG_; ++t) {
    int par = t & 1;
    float bp = sBp[t];
    float ca = (t > 0) ? ETA_*sAt[t-1] : 0.f;

    // ---- phase 1: b1 update, z1/a1 (h slice), sp partials ----
    if (t > 0 && tid < 8) {
      float mm = ETA_*sMB1[tid] - THETA_*sDZ[t-1][tid];
      sMB1[tid] = mm; sB1[tid] = PDEC_*sB1[tid] + mm;
    }
    __syncthreads();
    {
      int hh = tid >> 5, lane = tid & 31;
      float acc = 0.f;
      const float* Grow = G + ((long)b*SEG_ + t)*SEG_;
      for (int u = lane; u < t; u += 32)
        acc += sAt[t-1-u] * Grow[u] * sDZ[u][hh];
      for (int o = 16; o; o >>= 1) acc += __shfl_xor(acc, o);
      if (lane == 0) {
        int h = h0 + hh;
        float z1 = bp*q1k[((long)b*SEG_ + t)*W_ + h] + ca*q1km[((long)b*SEG_ + t)*W_ + h]
                 + sB1[hh] - THETA_*acc;
        sZ1[hh] = z1;
        float a1 = z1 * sigf(z1);
        sA1h[t][hh] = a1;
        exA1[(long)par*(B_*W_) + b*W_ + h] = a1;
        a1o[((long)b*SEG_ + t)*W_ + h] = a1;
      }
    }
    __syncthreads();
    if (tid < t) {
      float acc = 0.f;
      #pragma unroll
      for (int hh2 = 0; hh2 < 8; hh2++) acc += sA1h[tid][hh2]*sA1h[t][hh2];
      exSP[(((long)par*B_ + b)*NBLK_ + blk)*W_ + tid] = acc;
    }
    gbarrier(cnt, gen);

    // ---- phase 2: gather a1/s, b2 update, z2/e (j slice), r/ee partials ----
    if (tid < 128) {
      sA1t[tid] = exA1[(long)par*(B_*W_) + b*W_ + tid];
    } else {
      int u = tid - 128;
      if (u < t) {
        float s = 0.f;
        #pragma unroll 4
        for (int k2 = 0; k2 < NBLK_; k2++)
          s += exSP[(((long)par*B_ + b)*NBLK_ + k2)*W_ + u];
        sS[u] = -2.f*THETA_*sAt[t-1-u]*s;
      }
    }
    __syncthreads();
    if (t > 0 && tid < 64) {
      float mm = ETA_*sMB2[tid] - 2.f*THETA_*sEh[t-1][tid];
      sMB2[tid] = mm; sB2[tid] = PDEC_*sB2[tid] + mm;
    }
    __syncthreads();
    {
      int jj = tid >> 2, l4 = tid & 3;
      float g0 = 0.f, gm = 0.f;
      for (int h = l4; h < 128; h += 4) {
        g0 = fmaf(sW[jj][h],  sA1t[h], g0);
        gm = fmaf(sMW[jj][h], sA1t[h], gm);
      }
      float corr = 0.f;
      for (int u = l4; u < t; u += 4) corr = fmaf(sS[u], sEh[u][jj], corr);
      float tot = bp*g0 + ca*gm + corr;
      tot += __shfl_xor(tot, 1); tot += __shfl_xor(tot, 2);
      if (l4 == 0) {
        float e = tot + sB2[jj] - Vm[((long)b*SEG_ + t)*D_ + j0 + jj];
        sEh[t][jj] = e; sE[jj] = e;
        eo[((long)b*SEG_ + t)*D_ + j0 + jj] = e;
      }
    }
    __syncthreads();
    {
      int h = tid >> 1, l = tid & 1;
      float r0 = 0.f, rm = 0.f;
      for (int jj = l*32; jj < l*32+32; jj++) {
        r0 = fmaf(sW[jj][h],  sE[jj], r0);
        rm = fmaf(sMW[jj][h], sE[jj], rm);
      }
      float rc = bp*r0 + ca*rm;
      rc += __shfl_xor(rc, 1);
      if (l == 0) exR[(((long)par*B_ + b)*NBLK_ + blk)*W_ + h] = rc;
    }
    {
      int u = tid >> 1, l = tid & 1;
      if (u < t) {
        float acc = 0.f;
        for (int jj = l*32; jj < l*32+32; jj++) acc = fmaf(sEh[u][jj], sE[jj], acc);
        acc += __shfl_xor(acc, 1);
        if (l == 0) exEE[(((long)par*B_ + b)*NBLK_ + blk)*W_ + u] = acc;
      }
    }
    gbarrier(cnt, gen);

    // ---- phase 3: reduce r/ee, dz1 (h slice) ----
    if (tid < t) {
      float s = 0.f;
      #pragma unroll 4
      for (int k2 = 0; k2 < NBLK_; k2++)
        s += exEE[(((long)par*B_ + b)*NBLK_ + k2)*W_ + tid];
      sEEc[tid] = -2.f*THETA_*sAt[t-1-tid]*s;
    }
    if (tid >= 128 && tid < 136) {
      int hh = tid - 128;
      float s = 0.f;
      #pragma unroll 4
      for (int k2 = 0; k2 < NBLK_; k2++)
        s += exR[(((long)par*B_ + b)*NBLK_ + k2)*W_ + h0 + hh];
      sR[hh] = s;
    }
    __syncthreads();
    {
      int hh = tid >> 5, lane = tid & 31;
      float acc = 0.f;
      for (int u = lane; u < t; u += 32) acc = fmaf(sEEc[u], sA1h[u][hh], acc);
      for (int o = 16; o; o >>= 1) acc += __shfl_xor(acc, o);
      if (lane == 0) {
        float z = sZ1[hh];
        float sg = sigf(z);
        float dz = 2.f*(sR[hh] + acc) * sg*(1.f + z*(1.f - sg));
        sDZ[t][hh] = dz;
        dz1o[((long)b*SEG_ + t)*W_ + h0 + hh] = dz;
      }
    }
    __syncthreads();
  }

  // final bias state (t=128) writeback
  if (tid < 8) {
    float mm = ETA_*sMB1[tid] - THETA_*sDZ[127][tid];
    mb1[b*W_ + h0 + tid] = mm;
    pb1[b*W_ + h0 + tid] = PDEC_*sB1[tid] + mm;
  } else if (tid >= 64 && tid < 128) {
    int jj = tid - 64;
    float mm = ETA_*sMB2[jj] - 2.f*THETA_*sEh[127][jj];
    mb2[b*D_ + j0 + jj] = mm;
    pb2[b*D_ + j0 + jj] = PDEC_*sB2[jj] + mm;
  }
}

// ---------------- weight/momentum reconstruction --------------------------
// P_new = beta^128 P + eta*A[127] M + sum_u f*A[127-u]  in1[u][d] in2[u][h]
// M_new = eta^128 M            + sum_u f*eta^{127-u} in1[u][d] in2[u][h]
// kind 0: in1=KM, in2=DZ1, f=-theta, P=pW1;  kind 1: in1=Eh, in2=A1h, f=-2theta, P=pW2T
__global__ __launch_bounds__(256) void k_recon(
  float* __restrict__ pW1, float* __restrict__ mW1,
  float* __restrict__ pW2T, float* __restrict__ mW2T,
  const float* __restrict__ KMp, const float* __restrict__ Eh,
  const float* __restrict__ DZ1, const float* __restrict__ A1h,
  const float* __restrict__ coef)
{
  __shared__ float s1[16][33];
  __shared__ float s2[16][65];
  __shared__ float sCA[128], sCE[128];
  int dt = blockIdx.x, ht = blockIdx.y, kb = blockIdx.z;
  int kind = kb >> 1, b = kb & 1;
  int tid = threadIdx.x;
  int d0 = dt*32, hb = ht*64;
  const float* in1 = (kind ? Eh : KMp) + (long)b*SEG_*D_;
  const float* in2 = (kind ? A1h : DZ1) + (long)b*SEG_*W_;
  float* Pb = (kind ? pW2T : pW1) + (long)b*131072;
  float* Mb = (kind ? mW2T : mW1) + (long)b*131072;
  float f = kind ? -2.f*THETA_ : -THETA_;
  if (tid < 128) {
    sCA[tid] = f*coef[127 - tid];
    sCE[tid] = f*coef[128 + 127 - tid];
  }
  __syncthreads();
  int dd = tid >> 3, le = tid & 7;
  float accP[8] = {}, accM[8] = {};
  for (int u0 = 0; u0 < 128; u0 += 16) {
    for (int i = tid; i < 16*32; i += 256) {
      int uu = i >> 5, d2 = i & 31;
      s1[uu][d2] = in1[(long)(u0+uu)*D_ + d0 + d2];
    }
    for (int i = tid; i < 16*64; i += 256) {
      int uu = i >> 6, hl = i & 63;
      s2[uu][hl] = in2[(long)(u0+uu)*W_ + hb + hl];
    }
    __syncthreads();
    #pragma unroll
    for (int uu = 0; uu < 16; uu++) {
      float a = s1[uu][dd];
      float cAu = sCA[u0+uu], cEu = sCE[u0+uu];
      #pragma unroll
      for (int k = 0; k < 8; k++) {
        float v = a * s2[uu][k*8 + le];
        accP[k] = fmaf(cAu, v, accP[k]);
        accM[k] = fmaf(cEu, v, accM[k]);
      }
    }
    __syncthreads();
  }
  float b128 = coef[256 + 128];
  float eA   = ETA_*coef[127];
  float e128 = ETA_*coef[128 + 127];
  #pragma unroll
  for (int k = 0; k < 8; k++) {
    long idx = (long)(d0+dd)*W_ + hb + k*8 + le;
    float Po = Pb[idx], Mo = Mb[idx];
    Pb[idx] = b128*Po + eA*Mo + accP[k];
    Mb[idx] = e128*Mo + accM[k];
  }
}

__global__ void k_mul(const float* __restrict__ so, const float* __restrict__ mo,
                      float* __restrict__ outs, int s)
{
  int l = blockIdx.x, b = blockIdx.y, tid = threadIdx.x;
  long src = ((long)b*SEG_ + l)*D_ + tid*4;
  float4 a = *(const float4*)(so + src);
  float4 c = *(const float4*)(mo + src);
  a.x*=c.x; a.y*=c.y; a.z*=c.z; a.w*=c.w;
  *(float4*)(outs + ((long)b*N_ + s*SEG_ + l)*D_ + tid*4) = a;
}

// ---------------- host launcher ----------------
static inline void gemm(const float* A, const float* Bm, const float* bias, float* C,
                        int M, int N, int K, long sA, long sB, long sC, long sBias,
                        int batch, int bt, int silu_, hipStream_t st)
{
  dim3 g(N/64, (M+63)/64, batch), blk(256);
  if (!bt && !silu_) k_gemm<0,0><<<g,blk,0,st>>>(A,Bm,bias,C,M,N,K,sA,sB,sC,sBias);
  else if (!bt && silu_) k_gemm<0,1><<<g,blk,0,st>>>(A,Bm,bias,C,M,N,K,sA,sB,sC,sBias);
  else k_gemm<1,0><<<g,blk,0,st>>>(A,Bm,bias,C,M,N,K,sA,sB,sC,sBias);
}

extern "C" void kernel_launch(void* const* d_in, const int* in_sizes, int n_in,
                              void* d_out, int out_size, void* d_ws, size_t ws_size,
                              hipStream_t stream)
{
  (void)in_sizes; (void)n_in; (void)out_size; (void)ws_size;
  const int*   x     = (const int*)  d_in[0];
  const float* emb   = (const float*)d_in[1];
  const float* pers  = (const float*)d_in[2];
  const float* Wq    = (const float*)d_in[3];
  const float* bq    = (const float*)d_in[4];
  const float* Wk    = (const float*)d_in[5];
  const float* bk    = (const float*)d_in[6];
  const float* Wv    = (const float*)d_in[7];
  const float* bv    = (const float*)d_in[8];
  const float* aiw   = (const float*)d_in[9];
  const float* aib   = (const float*)d_in[10];
  const float* aow   = (const float*)d_in[11];
  const float* aob   = (const float*)d_in[12];
  const float* mW1in = (const float*)d_in[13];
  const float* mb1in = (const float*)d_in[14];
  const float* mW2in = (const float*)d_in[15];
  const float* mb2in = (const float*)d_in[16];
  const float* headw = (const float*)d_in[17];
  const float* headb = (const float*)d_in[18];
  float* out = (float*)d_out;
  float* ws  = (float*)d_ws;

  hipMemsetAsync(ws + MOM, 0, MOMSZ*sizeof(float), stream);
  hipMemsetAsync(ws + ZEROB, 0, 128*sizeof(float), stream);
  hipMemsetAsync(ws + CBAR, 0, 16*sizeof(int), stream);
  k_embed<<<dim3(B_*N_), dim3(256), 0, stream>>>(x, emb, ws+XEMB);
  k_init<<<dim3((2*PER_+255)/256), dim3(256), 0, stream>>>(
      mW1in, mb1in, mW2in, mb2in, ws+PW1, ws+PB1, ws+PW2T, ws+PB2);
  k_coef<<<dim3(1), dim3(64), 0, stream>>>(ws+COEF);

  for (int s = 0; s < NSEG_; s++) {
    const float* segA = ws + XEMB + (size_t)s*SEG_*D_;
    // h = mlp(p, l2n(seg @ Wq + bq))
    gemm(segA, Wq, bq, ws+Q1, SEG_, D_, D_, (long)N_*D_, 0, (long)SEG_*D_, 0, B_, 0, 0, stream);
    k_l2n<<<dim3(B_*SEG_), dim3(256), 0, stream>>>(ws+Q1);
    gemm(ws+Q1, ws+PW1, ws+PB1, ws+AH, SEG_, W_, D_, (long)SEG_*D_, (long)D_*W_, (long)SEG_*W_, W_, B_, 0, 1, stream);
    gemm(ws+AH, ws+PW2T, ws+PB2, ws+HBUF, SEG_, D_, W_, (long)SEG_*W_, (long)D_*W_, (long)SEG_*D_, D_, B_, 1, 0, stream);
    // attention
    k_concat<<<dim3(T_, B_), dim3(256), 0, stream>>>(pers, ws+HBUF, ws+XEMB, s, ws+COMB);
    gemm(ws+COMB, aiw, aib, ws+QKV, B_*T_, 3*D_, D_, 0, 0, 0, 0, 1, 0, 0, stream);
    k_attn<<<dim3(8, NH_, B_), dim3(256), 0, stream>>>(ws+QKV, ws+ATTN);
    gemm(ws+ATTN, aow, aob, ws+SEGO, B_*SEG_, D_, D_, 0, 0, 0, 0, 1, 0, 0, stream);
    // K/V projections
    gemm(ws+SEGO, Wk, bk, ws+KM, B_*SEG_, D_, D_, 0, 0, 0, 0, 1, 0, 0, stream);
    k_l2n<<<dim3(B_*SEG_), dim3(256), 0, stream>>>(ws+KM);
    gemm(ws+SEGO, Wv, bv, ws+VM, B_*SEG_, D_, D_, 0, 0, 0, 0, 1, 0, 0, stream);
    // token-space scan precompute: Q1K = K@W1, Q1Km = K@mW1, G = K@K^T
    gemm(ws+KM, ws+PW1, ws+ZEROB, ws+AQ1K,  SEG_, W_, D_, (long)SEG_*D_, (long)D_*W_, (long)SEG_*W_, 0, B_, 0, 0, stream);
    gemm(ws+KM, ws+MW1, ws+ZEROB, ws+AQ1KM, SEG_, W_, D_, (long)SEG_*D_, (long)D_*W_, (long)SEG_*W_, 0, B_, 0, 0, stream);
    gemm(ws+KM, ws+KM,  ws+ZEROB, ws+AGRAM, SEG_, SEG_, D_, (long)SEG_*D_, (long)SEG_*D_, (long)SEG_*SEG_, 0, B_, 1, 0, stream);
    // the scan itself (one launch)
    k_scan<<<dim3(NBLK_, B_), dim3(256), 0, stream>>>(
        ws+PW2T, ws+MW2T, ws+PB1, ws+MB1, ws+PB2, ws+MB2, ws+VM,
        ws+AQ1K, ws+AQ1KM, ws+AGRAM,
        ws+ADZ1, ws+AA1H, ws+AEH,
        ws+AEXA1, ws+AEXSP, ws+AEXR, ws+AEXEE,
        ws+COEF, (int*)(ws+CBAR));
    // reconstruct W1/mW1/W2T/mW2T
    k_recon<<<dim3(32, 2, 4), dim3(256), 0, stream>>>(
        ws+PW1, ws+MW1, ws+PW2T, ws+MW2T,
        ws+KM, ws+AEH, ws+ADZ1, ws+AA1H, ws+COEF);
    // mem_out = mlp(p, l2n(seg_out @ Wq + bq)); outs = seg_out * mem_out
    gemm(ws+SEGO, Wq, bq, ws+Q1, B_*SEG_, D_, D_, 0, 0, 0, 0, 1, 0, 0, stream);
    k_l2n<<<dim3(B_*SEG_), dim3(256), 0, stream>>>(ws+Q1);
    gemm(ws+Q1, ws+PW1, ws+PB1, ws+AH, SEG_, W_, D_, (long)SEG_*D_, (long)D_*W_, (long)SEG_*W_, W_, B_, 0, 1, stream);
    gemm(ws+AH, ws+PW2T, ws+PB2, ws+MEMO, SEG_, D_, W_, (long)SEG_*W_, (long)D_*W_, (long)SEG_*D_, D_, B_, 1, 0, stream);
    k_mul<<<dim3(SEG_, B_), dim3(256), 0, stream>>>(ws+SEGO, ws+MEMO, ws+OUTS, s);
  }
  // head: out = full @ head_w + head_b
  gemm(ws+OUTS, headw, headb, out, B_*N_, V_, D_, 0, 0, 0, 0, 1, 0, 0, stream);
}

// Round 4
// 11096.606 us; speedup vs baseline: 1.1718x; 1.1718x over previous
//
#include <hip/hip_runtime.h>
#include <math.h>

#define D_    1024
#define B_    2
#define N_    512
#define SEG_  128
#define NSEG_ 4
#define NPT_  16
#define T_    272
#define NH_   16
#define HD_   64
#define W_    128
#define V_    32000

#define THETA_ 0.1f
#define ETA_   0.9f
#define PDEC_  0.99f
#define EPSN_  1e-6f
#define NBLK_ 16
#define FSTR_ 16   // flag stride in ints (64B)

// ---------------- workspace layout (float offsets) ----------------
static const size_t XEMB = 0;                       // [B,N,D]
static const size_t OUTS = XEMB + (size_t)B_*N_*D_; // [B,N,D]
static const size_t PW1  = OUTS + (size_t)B_*N_*D_; // [B,1024,128]
static const size_t PB1  = PW1  + (size_t)B_*D_*W_; // [B,128]
static const size_t PW2T = PB1  + (size_t)B_*W_;    // [B,1024,128]  (W2 transposed: [j][h])
static const size_t PB2  = PW2T + (size_t)B_*D_*W_; // [B,1024]
static const size_t MOM  = PB2  + (size_t)B_*D_;    // momentum block (contiguous, memset 0)
static const size_t MW1  = MOM;
static const size_t MB1  = MW1  + (size_t)B_*D_*W_;
static const size_t MW2T = MB1  + (size_t)B_*W_;
static const size_t MB2  = MW2T + (size_t)B_*D_*W_;
static const size_t MOMSZ = (size_t)B_*(D_*W_ + W_ + D_*W_ + D_);
static const size_t Q1   = MOM  + MOMSZ;            // [B,128,1024]
static const size_t AH   = Q1   + (size_t)B_*SEG_*D_; // [B,128,128]
static const size_t HBUF = AH   + (size_t)B_*SEG_*W_; // [B,128,1024]
static const size_t COMB = HBUF + (size_t)B_*SEG_*D_; // [B,272,1024]
static const size_t QKV  = COMB + (size_t)B_*T_*D_;   // [B,272,3072]
static const size_t ATTN = QKV  + (size_t)B_*T_*3*D_; // [B,128,1024]
static const size_t SEGO = ATTN + (size_t)B_*SEG_*D_; // [B,128,1024]
static const size_t KM   = SEGO + (size_t)B_*SEG_*D_; // [B,128,1024]
static const size_t VM   = KM   + (size_t)B_*SEG_*D_; // [B,128,1024]
static const size_t MEMO = VM   + (size_t)B_*SEG_*D_; // [B,128,1024]
static const size_t WSEND = MEMO + (size_t)B_*SEG_*D_;

// scan-phase buffers ALIAS the QKV region
static const size_t AQ1K  = QKV;                 // [B,128,128]
static const size_t AQ1KM = AQ1K  + 32768;       // [B,128,128]
static const size_t AGRAM = AQ1KM + 32768;       // [B,128,128]
static const size_t ADZ1  = AGRAM + 32768;       // [B,128,128]
static const size_t AA1H  = ADZ1  + 32768;       // [B,128,128]
static const size_t AEH   = AA1H  + 32768;       // [B,128,1024]
static const size_t AEXA1 = AEH + (size_t)B_*SEG_*D_;  // [2][B][128]
static const size_t AEXSP = AEXA1 + 512;         // [2][B][16][128]
static const size_t AEXR  = AEXSP + 8192;
static const size_t AEXEE = AEXR  + 8192;
// persistent tail (must NOT alias QKV)
static const size_t COEF  = WSEND;               // A[128], etaPow[128], betaPow[129]
static const size_t ZEROB = COEF + 512;          // 128 zeros (GEMM zero-bias)
static const size_t CBAR  = ZEROB + 128;         // [B][NBLK][FSTR] ints = 512 ints

__device__ __forceinline__ float sigf(float x) { return 1.f/(1.f+expf(-x)); }

// ---------------- generic tiled fp32 GEMM (64x64) ----------------
template<int BT, int SILU>
__global__ __launch_bounds__(256) void k_gemm(
    const float* __restrict__ A, const float* __restrict__ Bm,
    const float* __restrict__ bias, float* __restrict__ C,
    int M, int N, int K, long sA, long sB, long sC, long sBias)
{
  __shared__ float As[16][68];
  __shared__ float Bs[16][68];
  int bz = blockIdx.z;
  A += bz*sA; Bm += bz*sB; C += bz*sC; bias += bz*sBias;
  int n0 = blockIdx.x*64, m0 = blockIdx.y*64;
  int tid = threadIdx.x;
  int tx = tid & 15, ty = tid >> 4;
  int r  = tid >> 2;
  int kq = (tid & 3) * 4;
  float acc[4][4] = {};
  for (int k0 = 0; k0 < K; k0 += 16) {
    {
      int row = m0 + r;
      float4 v = make_float4(0.f,0.f,0.f,0.f);
      if (row < M) v = *(const float4*)(A + (long)row*K + k0 + kq);
      As[kq+0][r]=v.x; As[kq+1][r]=v.y; As[kq+2][r]=v.z; As[kq+3][r]=v.w;
    }
    if (BT) {
      int row = n0 + r;
      float4 v = *(const float4*)(Bm + (long)row*K + k0 + kq);
      Bs[kq+0][r]=v.x; Bs[kq+1][r]=v.y; Bs[kq+2][r]=v.z; Bs[kq+3][r]=v.w;
    } else {
      int c = tid & 63, r4 = tid >> 6;
      #pragma unroll
      for (int p = 0; p < 4; p++) {
        int kk = r4 + p*4;
        Bs[kk][c] = Bm[(long)(k0+kk)*N + n0 + c];
      }
    }
    __syncthreads();
    #pragma unroll
    for (int kk = 0; kk < 16; kk++) {
      float av[4], bv[4];
      #pragma unroll
      for (int i=0;i<4;i++) av[i] = As[kk][ty*4+i];
      #pragma unroll
      for (int j=0;j<4;j++) bv[j] = Bs[kk][tx*4+j];
      #pragma unroll
      for (int i=0;i<4;i++)
        #pragma unroll
        for (int j=0;j<4;j++)
          acc[i][j] = fmaf(av[i], bv[j], acc[i][j]);
    }
    __syncthreads();
  }
  #pragma unroll
  for (int i=0;i<4;i++) {
    int row = m0 + ty*4 + i;
    if (row >= M) continue;
    #pragma unroll
    for (int j=0;j<4;j++) {
      int col = n0 + tx*4 + j;
      float v = acc[i][j] + bias[col];
      if (SILU) v = v * sigf(v);
      C[(long)row*N + col] = v;
    }
  }
}

// ---------------- 128x128 tile fp32 GEMM (head only; M,N multiples of 128) --
__global__ __launch_bounds__(256) void k_gemm128(
    const float* __restrict__ A, const float* __restrict__ Bm,
    const float* __restrict__ bias, float* __restrict__ C,
    int M, int N, int K)
{
  __shared__ float As[16][132];
  __shared__ float Bs[16][132];
  int n0 = blockIdx.x*128, m0 = blockIdx.y*128;
  int tid = threadIdx.x;
  int tx = tid & 15, ty = tid >> 4;
  int ar = tid >> 1, ak = (tid & 1) * 8;
  int bk = tid >> 4, bn = (tid & 15) * 8;
  float acc[8][8] = {};
  for (int k0 = 0; k0 < K; k0 += 16) {
    {
      const float* ap = A + (long)(m0+ar)*K + k0 + ak;
      float4 v0 = *(const float4*)(ap);
      float4 v1 = *(const float4*)(ap+4);
      As[ak+0][ar]=v0.x; As[ak+1][ar]=v0.y; As[ak+2][ar]=v0.z; As[ak+3][ar]=v0.w;
      As[ak+4][ar]=v1.x; As[ak+5][ar]=v1.y; As[ak+6][ar]=v1.z; As[ak+7][ar]=v1.w;
      const float* bp = Bm + (long)(k0+bk)*N + n0 + bn;
      float4 w0 = *(const float4*)(bp);
      float4 w1 = *(const float4*)(bp+4);
      *(float4*)(&Bs[bk][bn])   = w0;
      *(float4*)(&Bs[bk][bn+4]) = w1;
    }
    __syncthreads();
    #pragma unroll
    for (int kk = 0; kk < 16; kk++) {
      float av[8], bv[8];
      #pragma unroll
      for (int i=0;i<8;i++) av[i] = As[kk][ty*8+i];
      #pragma unroll
      for (int j=0;j<8;j++) bv[j] = Bs[kk][tx*8+j];
      #pragma unroll
      for (int i=0;i<8;i++)
        #pragma unroll
        for (int j=0;j<8;j++)
          acc[i][j] = fmaf(av[i], bv[j], acc[i][j]);
    }
    __syncthreads();
  }
  #pragma unroll
  for (int i=0;i<8;i++) {
    int row = m0 + ty*8 + i;
    #pragma unroll
    for (int j=0;j<8;j++) acc[i][j] += bias[n0 + tx*8 + j];
    *(float4*)(C + (long)row*N + n0 + tx*8)     = make_float4(acc[i][0],acc[i][1],acc[i][2],acc[i][3]);
    *(float4*)(C + (long)row*N + n0 + tx*8 + 4) = make_float4(acc[i][4],acc[i][5],acc[i][6],acc[i][7]);
  }
}

// ---------------- small kernels ----------------
__global__ void k_embed(const int* __restrict__ x, const float* __restrict__ emb,
                        float* __restrict__ xe)
{
  int row = blockIdx.x, tid = threadIdx.x;
  int idx = x[row];
  float4 v = *(const float4*)(emb + (long)idx*D_ + tid*4);
  *(float4*)(xe + (long)row*D_ + tid*4) = v;
}

#define PER_ 263296L
__global__ void k_init(const float* __restrict__ mW1in, const float* __restrict__ mb1in,
                       const float* __restrict__ mW2in, const float* __restrict__ mb2in,
                       float* __restrict__ pW1, float* __restrict__ pb1,
                       float* __restrict__ pW2T, float* __restrict__ pb2)
{
  long g = (long)blockIdx.x*256 + threadIdx.x;
  if (g >= 2*PER_) return;
  int b = (int)(g / PER_);
  long rr = g % PER_;
  if (rr < 131072)       pW1[(long)b*131072 + rr] = mW1in[rr];
  else if (rr < 131200)  pb1[b*W_ + (rr-131072)] = mb1in[rr-131072];
  else if (rr < 262272) { long l = rr-131200; int j=(int)(l>>7), h=(int)(l&127);
                          pW2T[(long)b*131072 + l] = mW2in[(long)h*D_ + j]; }
  else                   pb2[b*D_ + (rr-262272)] = mb2in[rr-262272];
}

__global__ void k_coef(float* __restrict__ c)
{
  if (blockIdx.x == 0 && threadIdx.x == 0) {
    c[0] = 1.f; c[128] = 1.f;
    float A = 1.f, eta_d = 1.f;
    for (int d = 1; d < 128; d++) {
      eta_d *= ETA_;
      A = PDEC_*A + eta_d;
      c[d] = A;
      c[128 + d] = eta_d;
    }
    c[256] = 1.f;
    float bp = 1.f;
    for (int t = 1; t <= 128; t++) { bp *= PDEC_; c[256 + t] = bp; }
  }
}

__global__ __launch_bounds__(256) void k_l2n(float* __restrict__ X)
{
  long row = blockIdx.x;
  float* p = X + row*D_;
  int tid = threadIdx.x;
  float4 v = *(float4*)(p + tid*4);
  float ss = v.x*v.x + v.y*v.y + v.z*v.z + v.w*v.w;
  for (int o=32;o;o>>=1) ss += __shfl_xor(ss,o);
  __shared__ float wsum[4];
  if ((tid&63)==0) wsum[tid>>6] = ss;
  __syncthreads();
  float tot = wsum[0]+wsum[1]+wsum[2]+wsum[3];
  float sc = 1.f/(sqrtf(tot)+EPSN_);
  v.x*=sc; v.y*=sc; v.z*=sc; v.w*=sc;
  *(float4*)(p + tid*4) = v;
}

__global__ void k_concat(const float* __restrict__ pers, const float* __restrict__ h,
                         const float* __restrict__ xemb, int s, float* __restrict__ comb)
{
  int row = blockIdx.x, b = blockIdx.y, tid = threadIdx.x;
  const float* src;
  if (row < NPT_)            src = pers + (long)row*D_;
  else if (row < NPT_+SEG_)  src = h    + ((long)b*SEG_ + (row-NPT_))*D_;
  else                       src = xemb + ((long)b*N_ + s*SEG_ + (row-NPT_-SEG_))*D_;
  float4 v = *(const float4*)(src + tid*4);
  *(float4*)(comb + ((long)b*T_ + row)*D_ + tid*4) = v;
}

__global__ __launch_bounds__(256) void k_attn(const float* __restrict__ qkv,
                                              float* __restrict__ outp)
{
  __shared__ float sQ[16][68];
  __shared__ float sKV[64][68];
  __shared__ float sS[16][273];
  int qt = blockIdx.x, head = blockIdx.y, b = blockIdx.z;
  int tid = threadIdx.x;
  const float* base = qkv + (long)b*T_*3*D_;
  int qoff = head*HD_, koff = D_ + head*HD_, voff = 2*D_ + head*HD_;
  int qrow0 = NPT_ + SEG_ + qt*16;
  {
    int rr = tid>>4, c4 = (tid&15)*4;
    float4 v = *(const float4*)(base + (long)(qrow0+rr)*3*D_ + qoff + c4);
    sQ[rr][c4]=v.x; sQ[rr][c4+1]=v.y; sQ[rr][c4+2]=v.z; sQ[rr][c4+3]=v.w;
  }
  __syncthreads();
  for (int j0 = 0; j0 < T_; j0 += 64) {
    int chunk = min(64, T_ - j0);
    {
      int jj = tid>>2, cq = (tid&3)*16;
      if (jj < chunk) {
        #pragma unroll
        for (int q4=0;q4<4;q4++) {
          float4 v = *(const float4*)(base + (long)(j0+jj)*3*D_ + koff + cq + q4*4);
          sKV[jj][cq+q4*4]=v.x; sKV[jj][cq+q4*4+1]=v.y; sKV[jj][cq+q4*4+2]=v.z; sKV[jj][cq+q4*4+3]=v.w;
        }
      }
    }
    __syncthreads();
    int rr = tid>>4, jj0 = tid&15;
    #pragma unroll
    for (int p=0;p<4;p++) {
      int jj = jj0 + p*16;
      if (jj < chunk) {
        float s = 0.f;
        #pragma unroll 8
        for (int c=0;c<HD_;c++) s = fmaf(sQ[rr][c], sKV[jj][c], s);
        s *= 0.125f;
        int jg = j0 + jj, qg = qrow0 + rr;
        if (jg > qg) s = -3.0e38f;
        sS[rr][jg] = s;
      }
    }
    __syncthreads();
  }
  {
    int rr = tid>>4, l16 = tid&15;
    float m = -3.4e38f;
    for (int j=l16; j<T_; j+=16) m = fmaxf(m, sS[rr][j]);
    for (int o=8;o;o>>=1) m = fmaxf(m, __shfl_xor(m,o));
    float sum = 0.f;
    for (int j=l16; j<T_; j+=16) { float e = expf(sS[rr][j]-m); sS[rr][j] = e; sum += e; }
    for (int o=8;o;o>>=1) sum += __shfl_xor(sum,o);
    float inv = 1.f/sum;
    for (int j=l16; j<T_; j+=16) sS[rr][j] *= inv;
  }
  __syncthreads();
  float acc[4] = {0.f,0.f,0.f,0.f};
  int rr = tid>>4, c4 = (tid&15)*4;
  for (int j0 = 0; j0 < T_; j0 += 64) {
    int chunk = min(64, T_ - j0);
    {
      int jj = tid>>2, cq = (tid&3)*16;
      if (jj < chunk) {
        #pragma unroll
        for (int q4=0;q4<4;q4++) {
          float4 v = *(const float4*)(base + (long)(j0+jj)*3*D_ + voff + cq + q4*4);
          sKV[jj][cq+q4*4]=v.x; sKV[jj][cq+q4*4+1]=v.y; sKV[jj][cq+q4*4+2]=v.z; sKV[jj][cq+q4*4+3]=v.w;
        }
      }
    }
    __syncthreads();
    for (int jj=0; jj<chunk; jj++) {
      float p = sS[rr][j0+jj];
      #pragma unroll
      for (int i=0;i<4;i++) acc[i] = fmaf(p, sKV[jj][c4+i], acc[i]);
    }
    __syncthreads();
  }
  float4 o4 = make_float4(acc[0],acc[1],acc[2],acc[3]);
  *(float4*)(outp + ((long)(b*SEG_) + qt*16 + rr)*D_ + head*HD_ + c4) = o4;
}

// ---------------- flag-broadcast device barrier (per sample) ----------------
// Each block release-stores a monotonically increasing generation into its own
// 64B-padded slot; 16 threads poll the 16 slots in parallel (no serialized RMW).
__device__ __forceinline__ void gbar(int* flags, int blk, int gen)
{
  __syncthreads();
  if (threadIdx.x == 0) {
    __threadfence();
    __hip_atomic_store(flags + blk*FSTR_, gen, __ATOMIC_RELEASE, __HIP_MEMORY_SCOPE_AGENT);
  }
  if (threadIdx.x < NBLK_) {
    while (__hip_atomic_load(flags + threadIdx.x*FSTR_, __ATOMIC_ACQUIRE,
                             __HIP_MEMORY_SCOPE_AGENT) < gen)
      __builtin_amdgcn_s_sleep(2);
    __threadfence();
  }
  __syncthreads();
}

// ---------------- persistent token-space scan (one launch per segment) ------
__global__ __launch_bounds__(256) void k_scan(
  const float* __restrict__ pW2T, const float* __restrict__ mW2T,
  float* __restrict__ pb1, float* __restrict__ mb1,
  float* __restrict__ pb2, float* __restrict__ mb2,
  const float* __restrict__ Vm,
  const float* __restrict__ q1k, const float* __restrict__ q1km,
  const float* __restrict__ G,
  float* __restrict__ dz1o, float* __restrict__ a1o, float* __restrict__ eo,
  float* __restrict__ exA1, float* __restrict__ exSP,
  float* __restrict__ exR, float* __restrict__ exEE,
  const float* __restrict__ coef, int* __restrict__ barbase, int seg)
{
  __shared__ float sW[64][132];
  __shared__ float sMW[64][132];
  __shared__ float sEh[128][66];
  __shared__ float sA1h[128][9];
  __shared__ float sDZ[128][9];
  __shared__ float sAt[128];
  __shared__ float sBp[129];
  __shared__ float sB1[8], sMB1[8], sZ1[8], sR[8];
  __shared__ float sB2[64], sMB2[64], sE[64];
  __shared__ float sA1t[128];
  __shared__ float sS[128];
  __shared__ float sEEc[128];

  int b = blockIdx.y, blk = blockIdx.x, tid = threadIdx.x;
  int j0 = blk*64, h0 = blk*8;
  int* flags = barbase + b*(NBLK_*FSTR_);
  int gbase = seg*1000;

  for (int i = tid; i < 64*128; i += 256) {
    int jj = i >> 7, h = i & 127;
    sW[jj][h]  = pW2T[(long)b*131072 + (long)(j0+jj)*128 + h];
    sMW[jj][h] = mW2T[(long)b*131072 + (long)(j0+jj)*128 + h];
  }
  if (tid < 128) sAt[tid] = coef[tid];
  for (int i = tid; i < 129; i += 256) sBp[i] = coef[256 + i];
  if (tid < 8)  { sB1[tid] = pb1[b*W_ + h0 + tid]; sMB1[tid] = mb1[b*W_ + h0 + tid]; }
  if (tid >= 64 && tid < 128) {
    int jj = tid - 64;
    sB2[jj] = pb2[b*D_ + j0 + jj]; sMB2[jj] = mb2[b*D_ + j0 + jj];
  }
  __syncthreads();

  for (int t = 0; t < SEG_; ++t) {
    int par = t & 1;
    float bp = sBp[t];
    float ca = (t > 0) ? ETA_*sAt[t-1] : 0.f;

    // ---- phase 1: b1 update, z1/a1 (h slice), sp partials ----
    if (t > 0 && tid < 8) {
      float mm = ETA_*sMB1[tid] - THETA_*sDZ[t-1][tid];
      sMB1[tid] = mm; sB1[tid] = PDEC_*sB1[tid] + mm;
    }
    __syncthreads();
    {
      int hh = tid >> 5, lane = tid & 31;
      float acc = 0.f;
      const float* Grow = G + ((long)b*SEG_ + t)*SEG_;
      for (int u = lane; u < t; u += 32)
        acc += sAt[t-1-u] * Grow[u] * sDZ[u][hh];
      for (int o = 16; o; o >>= 1) acc += __shfl_xor(acc, o);
      if (lane == 0) {
        int h = h0 + hh;
        float z1 = bp*q1k[((long)b*SEG_ + t)*W_ + h] + ca*q1km[((long)b*SEG_ + t)*W_ + h]
                 + sB1[hh] - THETA_*acc;
        sZ1[hh] = z1;
        float a1 = z1 * sigf(z1);
        sA1h[t][hh] = a1;
        exA1[(long)par*(B_*W_) + b*W_ + h] = a1;
        a1o[((long)b*SEG_ + t)*W_ + h] = a1;
      }
    }
    __syncthreads();
    if (tid < t) {
      float acc = 0.f;
      #pragma unroll
      for (int hh2 = 0; hh2 < 8; hh2++) acc += sA1h[tid][hh2]*sA1h[t][hh2];
      exSP[(((long)par*B_ + b)*NBLK_ + blk)*W_ + tid] = acc;
    }
    gbar(flags, blk, gbase + t*2 + 1);

    // ---- phase 2: gather a1/s, b2 update, z2/e (j slice), r/ee partials ----
    if (tid < 128) {
      sA1t[tid] = exA1[(long)par*(B_*W_) + b*W_ + tid];
    } else {
      int u = tid - 128;
      if (u < t) {
        float s = 0.f;
        #pragma unroll 4
        for (int k2 = 0; k2 < NBLK_; k2++)
          s += exSP[(((long)par*B_ + b)*NBLK_ + k2)*W_ + u];
        sS[u] = -2.f*THETA_*sAt[t-1-u]*s;
      }
    }
    __syncthreads();
    if (t > 0 && tid < 64) {
      float mm = ETA_*sMB2[tid] - 2.f*THETA_*sEh[t-1][tid];
      sMB2[tid] = mm; sB2[tid] = PDEC_*sB2[tid] + mm;
    }
    __syncthreads();
    {
      int jj = tid >> 2, l4 = tid & 3;
      float g0 = 0.f, gm = 0.f;
      for (int h = l4; h < 128; h += 4) {
        g0 = fmaf(sW[jj][h],  sA1t[h], g0);
        gm = fmaf(sMW[jj][h], sA1t[h], gm);
      }
      float corr = 0.f;
      for (int u = l4; u < t; u += 4) corr = fmaf(sS[u], sEh[u][jj], corr);
      float tot = bp*g0 + ca*gm + corr;
      tot += __shfl_xor(tot, 1); tot += __shfl_xor(tot, 2);
      if (l4 == 0) {
        float e = tot + sB2[jj] - Vm[((long)b*SEG_ + t)*D_ + j0 + jj];
        sEh[t][jj] = e; sE[jj] = e;
        eo[((long)b*SEG_ + t)*D_ + j0 + jj] = e;
      }
    }
    __syncthreads();
    {
      int h = tid >> 1, l = tid & 1;
      float r0 = 0.f, rm = 0.f;
      for (int jj = l*32; jj < l*32+32; jj++) {
        r0 = fmaf(sW[jj][h],  sE[jj], r0);
        rm = fmaf(sMW[jj][h], sE[jj], rm);
      }
      float rc = bp*r0 + ca*rm;
      rc += __shfl_xor(rc, 1);
      if (l == 0) exR[(((long)par*B_ + b)*NBLK_ + blk)*W_ + h] = rc;
    }
    {
      int u = tid >> 1, l = tid & 1;
      if (u < t) {
        float acc = 0.f;
        for (int jj = l*32; jj < l*32+32; jj++) acc = fmaf(sEh[u][jj], sE[jj], acc);
        acc += __shfl_xor(acc, 1);
        if (l == 0) exEE[(((long)par*B_ + b)*NBLK_ + blk)*W_ + u] = acc;
      }
    }
    gbar(flags, blk, gbase + t*2 + 2);

    // ---- phase 3: reduce r/ee, dz1 (h slice) ----
    if (tid < t) {
      float s = 0.f;
      #pragma unroll 4
      for (int k2 = 0; k2 < NBLK_; k2++)
        s += exEE[(((long)par*B_ + b)*NBLK_ + k2)*W_ + tid];
      sEEc[tid] = -2.f*THETA_*sAt[t-1-tid]*s;
    }
    if (tid >= 128 && tid < 136) {
      int hh = tid - 128;
      float s = 0.f;
      #pragma unroll 4
      for (int k2 = 0; k2 < NBLK_; k2++)
        s += exR[(((long)par*B_ + b)*NBLK_ + k2)*W_ + h0 + hh];
      sR[hh] = s;
    }
    __syncthreads();
    {
      int hh = tid >> 5, lane = tid & 31;
      float acc = 0.f;
      for (int u = lane; u < t; u += 32) acc = fmaf(sEEc[u], sA1h[u][hh], acc);
      for (int o = 16; o; o >>= 1) acc += __shfl_xor(acc, o);
      if (lane == 0) {
        float z = sZ1[hh];
        float sg = sigf(z);
        float dz = 2.f*(sR[hh] + acc) * sg*(1.f + z*(1.f - sg));
        sDZ[t][hh] = dz;
        dz1o[((long)b*SEG_ + t)*W_ + h0 + hh] = dz;
      }
    }
    __syncthreads();
  }

  // final bias state (t=128) writeback
  if (tid < 8) {
    float mm = ETA_*sMB1[tid] - THETA_*sDZ[127][tid];
    mb1[b*W_ + h0 + tid] = mm;
    pb1[b*W_ + h0 + tid] = PDEC_*sB1[tid] + mm;
  } else if (tid >= 64 && tid < 128) {
    int jj = tid - 64;
    float mm = ETA_*sMB2[jj] - 2.f*THETA_*sEh[127][jj];
    mb2[b*D_ + j0 + jj] = mm;
    pb2[b*D_ + j0 + jj] = PDEC_*sB2[jj] + mm;
  }
}

// ---------------- weight/momentum reconstruction --------------------------
__global__ __launch_bounds__(256) void k_recon(
  float* __restrict__ pW1, float* __restrict__ mW1,
  float* __restrict__ pW2T, float* __restrict__ mW2T,
  const float* __restrict__ KMp, const float* __restrict__ Eh,
  const float* __restrict__ DZ1, const float* __restrict__ A1h,
  const float* __restrict__ coef)
{
  __shared__ float s1[16][33];
  __shared__ float s2[16][65];
  __shared__ float sCA[128], sCE[128];
  int dt = blockIdx.x, ht = blockIdx.y, kb = blockIdx.z;
  int kind = kb >> 1, b = kb & 1;
  int tid = threadIdx.x;
  int d0 = dt*32, hb = ht*64;
  const float* in1 = (kind ? Eh : KMp) + (long)b*SEG_*D_;
  const float* in2 = (kind ? A1h : DZ1) + (long)b*SEG_*W_;
  float* Pb = (kind ? pW2T : pW1) + (long)b*131072;
  float* Mb = (kind ? mW2T : mW1) + (long)b*131072;
  float f = kind ? -2.f*THETA_ : -THETA_;
  if (tid < 128) {
    sCA[tid] = f*coef[127 - tid];
    sCE[tid] = f*coef[128 + 127 - tid];
  }
  __syncthreads();
  int dd = tid >> 3, le = tid & 7;
  float accP[8] = {}, accM[8] = {};
  for (int u0 = 0; u0 < 128; u0 += 16) {
    for (int i = tid; i < 16*32; i += 256) {
      int uu = i >> 5, d2 = i & 31;
      s1[uu][d2] = in1[(long)(u0+uu)*D_ + d0 + d2];
    }
    for (int i = tid; i < 16*64; i += 256) {
      int uu = i >> 6, hl = i & 63;
      s2[uu][hl] = in2[(long)(u0+uu)*W_ + hb + hl];
    }
    __syncthreads();
    #pragma unroll
    for (int uu = 0; uu < 16; uu++) {
      float a = s1[uu][dd];
      float cAu = sCA[u0+uu], cEu = sCE[u0+uu];
      #pragma unroll
      for (int k = 0; k < 8; k++) {
        float v = a * s2[uu][k*8 + le];
        accP[k] = fmaf(cAu, v, accP[k]);
        accM[k] = fmaf(cEu, v, accM[k]);
      }
    }
    __syncthreads();
  }
  float b128 = coef[256 + 128];
  float eA   = ETA_*coef[127];
  float e128 = ETA_*coef[128 + 127];
  #pragma unroll
  for (int k = 0; k < 8; k++) {
    long idx = (long)(d0+dd)*W_ + hb + k*8 + le;
    float Po = Pb[idx], Mo = Mb[idx];
    Pb[idx] = b128*Po + eA*Mo + accP[k];
    Mb[idx] = e128*Mo + accM[k];
  }
}

__global__ void k_mul(const float* __restrict__ so, const float* __restrict__ mo,
                      float* __restrict__ outs, int s)
{
  int l = blockIdx.x, b = blockIdx.y, tid = threadIdx.x;
  long src = ((long)b*SEG_ + l)*D_ + tid*4;
  float4 a = *(const float4*)(so + src);
  float4 c = *(const float4*)(mo + src);
  a.x*=c.x; a.y*=c.y; a.z*=c.z; a.w*=c.w;
  *(float4*)(outs + ((long)b*N_ + s*SEG_ + l)*D_ + tid*4) = a;
}

// ---------------- host launcher ----------------
static inline void gemm(const float* A, const float* Bm, const float* bias, float* C,
                        int M, int N, int K, long sA, long sB, long sC, long sBias,
                        int batch, int bt, int silu_, hipStream_t st)
{
  dim3 g(N/64, (M+63)/64, batch), blk(256);
  if (!bt && !silu_) k_gemm<0,0><<<g,blk,0,st>>>(A,Bm,bias,C,M,N,K,sA,sB,sC,sBias);
  else if (!bt && silu_) k_gemm<0,1><<<g,blk,0,st>>>(A,Bm,bias,C,M,N,K,sA,sB,sC,sBias);
  else k_gemm<1,0><<<g,blk,0,st>>>(A,Bm,bias,C,M,N,K,sA,sB,sC,sBias);
}

extern "C" void kernel_launch(void* const* d_in, const int* in_sizes, int n_in,
                              void* d_out, int out_size, void* d_ws, size_t ws_size,
                              hipStream_t stream)
{
  (void)in_sizes; (void)n_in; (void)out_size; (void)ws_size;
  const int*   x     = (const int*)  d_in[0];
  const float* emb   = (const float*)d_in[1];
  const float* pers  = (const float*)d_in[2];
  const float* Wq    = (const float*)d_in[3];
  const float* bq    = (const float*)d_in[4];
  const float* Wk    = (const float*)d_in[5];
  const float* bk    = (const float*)d_in[6];
  const float* Wv    = (const float*)d_in[7];
  const float* bv    = (const float*)d_in[8];
  const float* aiw   = (const float*)d_in[9];
  const float* aib   = (const float*)d_in[10];
  const float* aow   = (const float*)d_in[11];
  const float* aob   = (const float*)d_in[12];
  const float* mW1in = (const float*)d_in[13];
  const float* mb1in = (const float*)d_in[14];
  const float* mW2in = (const float*)d_in[15];
  const float* mb2in = (const float*)d_in[16];
  const float* headw = (const float*)d_in[17];
  const float* headb = (const float*)d_in[18];
  float* out = (float*)d_out;
  float* ws  = (float*)d_ws;

  hipMemsetAsync(ws + MOM, 0, MOMSZ*sizeof(float), stream);
  hipMemsetAsync(ws + ZEROB, 0, 128*sizeof(float), stream);
  hipMemsetAsync(ws + CBAR, 0, 512*sizeof(int), stream);
  k_embed<<<dim3(B_*N_), dim3(256), 0, stream>>>(x, emb, ws+XEMB);
  k_init<<<dim3((2*PER_+255)/256), dim3(256), 0, stream>>>(
      mW1in, mb1in, mW2in, mb2in, ws+PW1, ws+PB1, ws+PW2T, ws+PB2);
  k_coef<<<dim3(1), dim3(64), 0, stream>>>(ws+COEF);

  for (int s = 0; s < NSEG_; s++) {
    const float* segA = ws + XEMB + (size_t)s*SEG_*D_;
    // h = mlp(p, l2n(seg @ Wq + bq))
    gemm(segA, Wq, bq, ws+Q1, SEG_, D_, D_, (long)N_*D_, 0, (long)SEG_*D_, 0, B_, 0, 0, stream);
    k_l2n<<<dim3(B_*SEG_), dim3(256), 0, stream>>>(ws+Q1);
    gemm(ws+Q1, ws+PW1, ws+PB1, ws+AH, SEG_, W_, D_, (long)SEG_*D_, (long)D_*W_, (long)SEG_*W_, W_, B_, 0, 1, stream);
    gemm(ws+AH, ws+PW2T, ws+PB2, ws+HBUF, SEG_, D_, W_, (long)SEG_*W_, (long)D_*W_, (long)SEG_*D_, D_, B_, 1, 0, stream);
    // attention
    k_concat<<<dim3(T_, B_), dim3(256), 0, stream>>>(pers, ws+HBUF, ws+XEMB, s, ws+COMB);
    gemm(ws+COMB, aiw, aib, ws+QKV, B_*T_, 3*D_, D_, 0, 0, 0, 0, 1, 0, 0, stream);
    k_attn<<<dim3(8, NH_, B_), dim3(256), 0, stream>>>(ws+QKV, ws+ATTN);
    gemm(ws+ATTN, aow, aob, ws+SEGO, B_*SEG_, D_, D_, 0, 0, 0, 0, 1, 0, 0, stream);
    // K/V projections
    gemm(ws+SEGO, Wk, bk, ws+KM, B_*SEG_, D_, D_, 0, 0, 0, 0, 1, 0, 0, stream);
    k_l2n<<<dim3(B_*SEG_), dim3(256), 0, stream>>>(ws+KM);
    gemm(ws+SEGO, Wv, bv, ws+VM, B_*SEG_, D_, D_, 0, 0, 0, 0, 1, 0, 0, stream);
    // token-space scan precompute: Q1K = K@W1, Q1Km = K@mW1, G = K@K^T
    gemm(ws+KM, ws+PW1, ws+ZEROB, ws+AQ1K,  SEG_, W_, D_, (long)SEG_*D_, (long)D_*W_, (long)SEG_*W_, 0, B_, 0, 0, stream);
    gemm(ws+KM, ws+MW1, ws+ZEROB, ws+AQ1KM, SEG_, W_, D_, (long)SEG_*D_, (long)D_*W_, (long)SEG_*W_, 0, B_, 0, 0, stream);
    gemm(ws+KM, ws+KM,  ws+ZEROB, ws+AGRAM, SEG_, SEG_, D_, (long)SEG_*D_, (long)SEG_*D_, (long)SEG_*SEG_, 0, B_, 1, 0, stream);
    // the scan itself (one launch)
    k_scan<<<dim3(NBLK_, B_), dim3(256), 0, stream>>>(
        ws+PW2T, ws+MW2T, ws+PB1, ws+MB1, ws+PB2, ws+MB2, ws+VM,
        ws+AQ1K, ws+AQ1KM, ws+AGRAM,
        ws+ADZ1, ws+AA1H, ws+AEH,
        ws+AEXA1, ws+AEXSP, ws+AEXR, ws+AEXEE,
        ws+COEF, (int*)(ws+CBAR), s);
    // reconstruct W1/mW1/W2T/mW2T
    k_recon<<<dim3(32, 2, 4), dim3(256), 0, stream>>>(
        ws+PW1, ws+MW1, ws+PW2T, ws+MW2T,
        ws+KM, ws+AEH, ws+ADZ1, ws+AA1H, ws+COEF);
    // mem_out = mlp(p, l2n(seg_out @ Wq + bq)); outs = seg_out * mem_out
    gemm(ws+SEGO, Wq, bq, ws+Q1, B_*SEG_, D_, D_, 0, 0, 0, 0, 1, 0, 0, stream);
    k_l2n<<<dim3(B_*SEG_), dim3(256), 0, stream>>>(ws+Q1);
    gemm(ws+Q1, ws+PW1, ws+PB1, ws+AH, SEG_, W_, D_, (long)SEG_*D_, (long)D_*W_, (long)SEG_*W_, W_, B_, 0, 1, stream);
    gemm(ws+AH, ws+PW2T, ws+PB2, ws+MEMO, SEG_, D_, W_, (long)SEG_*W_, (long)D_*W_, (long)SEG_*D_, D_, B_, 1, 0, stream);
    k_mul<<<dim3(SEG_, B_), dim3(256), 0, stream>>>(ws+SEGO, ws+MEMO, ws+OUTS, s);
  }
  // head: out = full @ head_w + head_b (128x128-tile GEMM)
  k_gemm128<<<dim3(V_/128, (B_*N_)/128), dim3(256), 0, stream>>>(
      ws+OUTS, headw, headb, out, B_*N_, V_, D_);
}

// Round 6
// 9737.369 us; speedup vs baseline: 1.3354x; 1.1396x over previous
//
#include <hip/hip_runtime.h>
#include <math.h>

#define D_    1024
#define B_    2
#define N_    512
#define SEG_  128
#define NSEG_ 4
#define NPT_  16
#define T_    272
#define NH_   16
#define HD_   64
#define W_    128
#define V_    32000

#define THETA_ 0.1f
#define ETA_   0.9f
#define PDEC_  0.99f
#define EPSN_  1e-6f
#define NBLK_ 16
#define FSTR_ 32   // flag stride in ints (128B = 1 cacheline)

// ---------------- workspace layout (float offsets) ----------------
static const size_t XEMB = 0;                       // [B,N,D]
static const size_t OUTS = XEMB + (size_t)B_*N_*D_; // [B,N,D]
static const size_t PW1  = OUTS + (size_t)B_*N_*D_; // [B,1024,128]
static const size_t PB1  = PW1  + (size_t)B_*D_*W_; // [B,128]
static const size_t PW2T = PB1  + (size_t)B_*W_;    // [B,1024,128]  (W2 transposed: [j][h])
static const size_t PB2  = PW2T + (size_t)B_*D_*W_; // [B,1024]
static const size_t MOM  = PB2  + (size_t)B_*D_;    // momentum block (contiguous, memset 0)
static const size_t MW1  = MOM;
static const size_t MB1  = MW1  + (size_t)B_*D_*W_;
static const size_t MW2T = MB1  + (size_t)B_*W_;
static const size_t MB2  = MW2T + (size_t)B_*D_*W_;
static const size_t MOMSZ = (size_t)B_*(D_*W_ + W_ + D_*W_ + D_);
static const size_t Q1   = MOM  + MOMSZ;            // [B,128,1024]
static const size_t AH   = Q1   + (size_t)B_*SEG_*D_; // [B,128,128]
static const size_t HBUF = AH   + (size_t)B_*SEG_*W_; // [B,128,1024]
static const size_t COMB = HBUF + (size_t)B_*SEG_*D_; // [B,272,1024]
static const size_t QKV  = COMB + (size_t)B_*T_*D_;   // [B,272,3072]
static const size_t ATTN = QKV  + (size_t)B_*T_*3*D_; // [B,128,1024]
static const size_t SEGO = ATTN + (size_t)B_*SEG_*D_; // [B,128,1024]
static const size_t KM   = SEGO + (size_t)B_*SEG_*D_; // [B,128,1024]
static const size_t VM   = KM   + (size_t)B_*SEG_*D_; // [B,128,1024]
static const size_t MEMO = VM   + (size_t)B_*SEG_*D_; // [B,128,1024]
static const size_t WSEND = MEMO + (size_t)B_*SEG_*D_;

// scan-phase buffers ALIAS the QKV region
static const size_t AQ1K  = QKV;                 // [B,128,128]
static const size_t AQ1KM = AQ1K  + 32768;       // [B,128,128]
static const size_t AGRAM = AQ1KM + 32768;       // [B,128,128]
static const size_t ADZ1  = AGRAM + 32768;       // [B,128,128]
static const size_t AA1H  = ADZ1  + 32768;       // [B,128,128]
static const size_t AEH   = AA1H  + 32768;       // [B,128,1024]
static const size_t AEXA1 = AEH + (size_t)B_*SEG_*D_;  // [2][B][128]
static const size_t AEXSP = AEXA1 + 512;         // [2][B][16][128]
static const size_t AEXR  = AEXSP + 8192;
static const size_t AEXEE = AEXR  + 8192;
// persistent tail (must NOT alias QKV)
static const size_t COEF  = WSEND;               // A[128], etaPow[128], betaPow[129]
static const size_t ZEROB = COEF + 512;          // 128 zeros (GEMM zero-bias)
static const size_t CBAR  = ZEROB + 128;         // [B][NBLK][FSTR] ints = 1024 ints

__device__ __forceinline__ float sigf(float x) { return 1.f/(1.f+expf(-x)); }

// MALL-coherent (L2-bypassing) exchange accessors — no fences needed
__device__ __forceinline__ void gstore(float* p, float v) {
  __hip_atomic_store(p, v, __ATOMIC_RELAXED, __HIP_MEMORY_SCOPE_AGENT);
}
__device__ __forceinline__ float gload(const float* p) {
  return __hip_atomic_load(p, __ATOMIC_RELAXED, __HIP_MEMORY_SCOPE_AGENT);
}

// ---------------- generic tiled fp32 GEMM (64x64) ----------------
template<int BT, int SILU>
__global__ __launch_bounds__(256) void k_gemm(
    const float* __restrict__ A, const float* __restrict__ Bm,
    const float* __restrict__ bias, float* __restrict__ C,
    int M, int N, int K, long sA, long sB, long sC, long sBias)
{
  __shared__ float As[16][68];
  __shared__ float Bs[16][68];
  int bz = blockIdx.z;
  A += bz*sA; Bm += bz*sB; C += bz*sC; bias += bz*sBias;
  int n0 = blockIdx.x*64, m0 = blockIdx.y*64;
  int tid = threadIdx.x;
  int tx = tid & 15, ty = tid >> 4;
  int r  = tid >> 2;
  int kq = (tid & 3) * 4;
  float acc[4][4] = {};
  for (int k0 = 0; k0 < K; k0 += 16) {
    {
      int row = m0 + r;
      float4 v = make_float4(0.f,0.f,0.f,0.f);
      if (row < M) v = *(const float4*)(A + (long)row*K + k0 + kq);
      As[kq+0][r]=v.x; As[kq+1][r]=v.y; As[kq+2][r]=v.z; As[kq+3][r]=v.w;
    }
    if (BT) {
      int row = n0 + r;
      float4 v = *(const float4*)(Bm + (long)row*K + k0 + kq);
      Bs[kq+0][r]=v.x; Bs[kq+1][r]=v.y; Bs[kq+2][r]=v.z; Bs[kq+3][r]=v.w;
    } else {
      int c = tid & 63, r4 = tid >> 6;
      #pragma unroll
      for (int p = 0; p < 4; p++) {
        int kk = r4 + p*4;
        Bs[kk][c] = Bm[(long)(k0+kk)*N + n0 + c];
      }
    }
    __syncthreads();
    #pragma unroll
    for (int kk = 0; kk < 16; kk++) {
      float av[4], bv[4];
      #pragma unroll
      for (int i=0;i<4;i++) av[i] = As[kk][ty*4+i];
      #pragma unroll
      for (int j=0;j<4;j++) bv[j] = Bs[kk][tx*4+j];
      #pragma unroll
      for (int i=0;i<4;i++)
        #pragma unroll
        for (int j=0;j<4;j++)
          acc[i][j] = fmaf(av[i], bv[j], acc[i][j]);
    }
    __syncthreads();
  }
  #pragma unroll
  for (int i=0;i<4;i++) {
    int row = m0 + ty*4 + i;
    if (row >= M) continue;
    #pragma unroll
    for (int j=0;j<4;j++) {
      int col = n0 + tx*4 + j;
      float v = acc[i][j] + bias[col];
      if (SILU) v = v * sigf(v);
      C[(long)row*N + col] = v;
    }
  }
}

// ------- 128x128 tile fp32 GEMM (M-guarded; N,K multiples of 128/16) -------
__global__ __launch_bounds__(256) void k_gemm128(
    const float* __restrict__ A, const float* __restrict__ Bm,
    const float* __restrict__ bias, float* __restrict__ C,
    int M, int N, int K)
{
  __shared__ float As[16][132];
  __shared__ float Bs[16][132];
  int n0 = blockIdx.x*128, m0 = blockIdx.y*128;
  int tid = threadIdx.x;
  int tx = tid & 15, ty = tid >> 4;
  int ar = tid >> 1, ak = (tid & 1) * 8;
  int bk = tid >> 4, bn = (tid & 15) * 8;
  int arow = min(m0 + ar, M-1);    // clamp for OOB tail rows (dup loads harmless)
  float acc[8][8] = {};
  for (int k0 = 0; k0 < K; k0 += 16) {
    {
      const float* ap = A + (long)arow*K + k0 + ak;
      float4 v0 = *(const float4*)(ap);
      float4 v1 = *(const float4*)(ap+4);
      As[ak+0][ar]=v0.x; As[ak+1][ar]=v0.y; As[ak+2][ar]=v0.z; As[ak+3][ar]=v0.w;
      As[ak+4][ar]=v1.x; As[ak+5][ar]=v1.y; As[ak+6][ar]=v1.z; As[ak+7][ar]=v1.w;
      const float* bp = Bm + (long)(k0+bk)*N + n0 + bn;
      float4 w0 = *(const float4*)(bp);
      float4 w1 = *(const float4*)(bp+4);
      *(float4*)(&Bs[bk][bn])   = w0;
      *(float4*)(&Bs[bk][bn+4]) = w1;
    }
    __syncthreads();
    #pragma unroll
    for (int kk = 0; kk < 16; kk++) {
      float av[8], bv[8];
      #pragma unroll
      for (int i=0;i<8;i++) av[i] = As[kk][ty*8+i];
      #pragma unroll
      for (int j=0;j<8;j++) bv[j] = Bs[kk][tx*8+j];
      #pragma unroll
      for (int i=0;i<8;i++)
        #pragma unroll
        for (int j=0;j<8;j++)
          acc[i][j] = fmaf(av[i], bv[j], acc[i][j]);
    }
    __syncthreads();
  }
  #pragma unroll
  for (int i=0;i<8;i++) {
    int row = m0 + ty*8 + i;
    if (row >= M) continue;
    #pragma unroll
    for (int j=0;j<8;j++) acc[i][j] += bias[n0 + tx*8 + j];
    *(float4*)(C + (long)row*N + n0 + tx*8)     = make_float4(acc[i][0],acc[i][1],acc[i][2],acc[i][3]);
    *(float4*)(C + (long)row*N + n0 + tx*8 + 4) = make_float4(acc[i][4],acc[i][5],acc[i][6],acc[i][7]);
  }
}

// ---------------- small kernels ----------------
__global__ void k_embed(const int* __restrict__ x, const float* __restrict__ emb,
                        float* __restrict__ xe)
{
  int row = blockIdx.x, tid = threadIdx.x;
  int idx = x[row];
  float4 v = *(const float4*)(emb + (long)idx*D_ + tid*4);
  *(float4*)(xe + (long)row*D_ + tid*4) = v;
}

#define PER_ 263296L
__global__ void k_init(const float* __restrict__ mW1in, const float* __restrict__ mb1in,
                       const float* __restrict__ mW2in, const float* __restrict__ mb2in,
                       float* __restrict__ pW1, float* __restrict__ pb1,
                       float* __restrict__ pW2T, float* __restrict__ pb2)
{
  long g = (long)blockIdx.x*256 + threadIdx.x;
  if (g >= 2*PER_) return;
  int b = (int)(g / PER_);
  long rr = g % PER_;
  if (rr < 131072)       pW1[(long)b*131072 + rr] = mW1in[rr];
  else if (rr < 131200)  pb1[b*W_ + (rr-131072)] = mb1in[rr-131072];
  else if (rr < 262272) { long l = rr-131200; int j=(int)(l>>7), h=(int)(l&127);
                          pW2T[(long)b*131072 + l] = mW2in[(long)h*D_ + j]; }
  else                   pb2[b*D_ + (rr-262272)] = mb2in[rr-262272];
}

__global__ void k_coef(float* __restrict__ c)
{
  if (blockIdx.x == 0 && threadIdx.x == 0) {
    c[0] = 1.f; c[128] = 1.f;
    float A = 1.f, eta_d = 1.f;
    for (int d = 1; d < 128; d++) {
      eta_d *= ETA_;
      A = PDEC_*A + eta_d;
      c[d] = A;
      c[128 + d] = eta_d;
    }
    c[256] = 1.f;
    float bp = 1.f;
    for (int t = 1; t <= 128; t++) { bp *= PDEC_; c[256 + t] = bp; }
  }
}

__global__ __launch_bounds__(256) void k_l2n(float* __restrict__ X)
{
  long row = blockIdx.x;
  float* p = X + row*D_;
  int tid = threadIdx.x;
  float4 v = *(float4*)(p + tid*4);
  float ss = v.x*v.x + v.y*v.y + v.z*v.z + v.w*v.w;
  for (int o=32;o;o>>=1) ss += __shfl_xor(ss,o);
  __shared__ float wsum[4];
  if ((tid&63)==0) wsum[tid>>6] = ss;
  __syncthreads();
  float tot = wsum[0]+wsum[1]+wsum[2]+wsum[3];
  float sc = 1.f/(sqrtf(tot)+EPSN_);
  v.x*=sc; v.y*=sc; v.z*=sc; v.w*=sc;
  *(float4*)(p + tid*4) = v;
}

__global__ void k_concat(const float* __restrict__ pers, const float* __restrict__ h,
                         const float* __restrict__ xemb, int s, float* __restrict__ comb)
{
  int row = blockIdx.x, b = blockIdx.y, tid = threadIdx.x;
  const float* src;
  if (row < NPT_)            src = pers + (long)row*D_;
  else if (row < NPT_+SEG_)  src = h    + ((long)b*SEG_ + (row-NPT_))*D_;
  else                       src = xemb + ((long)b*N_ + s*SEG_ + (row-NPT_-SEG_))*D_;
  float4 v = *(const float4*)(src + tid*4);
  *(float4*)(comb + ((long)b*T_ + row)*D_ + tid*4) = v;
}

__global__ __launch_bounds__(256) void k_attn(const float* __restrict__ qkv,
                                              float* __restrict__ outp)
{
  __shared__ float sQ[16][68];
  __shared__ float sKV[64][68];
  __shared__ float sS[16][273];
  int qt = blockIdx.x, head = blockIdx.y, b = blockIdx.z;
  int tid = threadIdx.x;
  const float* base = qkv + (long)b*T_*3*D_;
  int qoff = head*HD_, koff = D_ + head*HD_, voff = 2*D_ + head*HD_;
  int qrow0 = NPT_ + SEG_ + qt*16;
  {
    int rr = tid>>4, c4 = (tid&15)*4;
    float4 v = *(const float4*)(base + (long)(qrow0+rr)*3*D_ + qoff + c4);
    sQ[rr][c4]=v.x; sQ[rr][c4+1]=v.y; sQ[rr][c4+2]=v.z; sQ[rr][c4+3]=v.w;
  }
  __syncthreads();
  for (int j0 = 0; j0 < T_; j0 += 64) {
    int chunk = min(64, T_ - j0);
    {
      int jj = tid>>2, cq = (tid&3)*16;
      if (jj < chunk) {
        #pragma unroll
        for (int q4=0;q4<4;q4++) {
          float4 v = *(const float4*)(base + (long)(j0+jj)*3*D_ + koff + cq + q4*4);
          sKV[jj][cq+q4*4]=v.x; sKV[jj][cq+q4*4+1]=v.y; sKV[jj][cq+q4*4+2]=v.z; sKV[jj][cq+q4*4+3]=v.w;
        }
      }
    }
    __syncthreads();
    int rr = tid>>4, jj0 = tid&15;
    #pragma unroll
    for (int p=0;p<4;p++) {
      int jj = jj0 + p*16;
      if (jj < chunk) {
        float s = 0.f;
        #pragma unroll 8
        for (int c=0;c<HD_;c++) s = fmaf(sQ[rr][c], sKV[jj][c], s);
        s *= 0.125f;
        int jg = j0 + jj, qg = qrow0 + rr;
        if (jg > qg) s = -3.0e38f;
        sS[rr][jg] = s;
      }
    }
    __syncthreads();
  }
  {
    int rr = tid>>4, l16 = tid&15;
    float m = -3.4e38f;
    for (int j=l16; j<T_; j+=16) m = fmaxf(m, sS[rr][j]);
    for (int o=8;o;o>>=1) m = fmaxf(m, __shfl_xor(m,o));
    float sum = 0.f;
    for (int j=l16; j<T_; j+=16) { float e = expf(sS[rr][j]-m); sS[rr][j] = e; sum += e; }
    for (int o=8;o;o>>=1) sum += __shfl_xor(sum,o);
    float inv = 1.f/sum;
    for (int j=l16; j<T_; j+=16) sS[rr][j] *= inv;
  }
  __syncthreads();
  float acc[4] = {0.f,0.f,0.f,0.f};
  int rr = tid>>4, c4 = (tid&15)*4;
  for (int j0 = 0; j0 < T_; j0 += 64) {
    int chunk = min(64, T_ - j0);
    {
      int jj = tid>>2, cq = (tid&3)*16;
      if (jj < chunk) {
        #pragma unroll
        for (int q4=0;q4<4;q4++) {
          float4 v = *(const float4*)(base + (long)(j0+jj)*3*D_ + voff + cq + q4*4);
          sKV[jj][cq+q4*4]=v.x; sKV[jj][cq+q4*4+1]=v.y; sKV[jj][cq+q4*4+2]=v.z; sKV[jj][cq+q4*4+3]=v.w;
        }
      }
    }
    __syncthreads();
    for (int jj=0; jj<chunk; jj++) {
      float p = sS[rr][j0+jj];
      #pragma unroll
      for (int i=0;i<4;i++) acc[i] = fmaf(p, sKV[jj][c4+i], acc[i]);
    }
    __syncthreads();
  }
  float4 o4 = make_float4(acc[0],acc[1],acc[2],acc[3]);
  *(float4*)(outp + ((long)(b*SEG_) + qt*16 + rr)*D_ + head*HD_ + c4) = o4;
}

// ------- fence-free flag barrier (exchange data uses MALL atomics) ---------
// Every wave drains its own stores (vmcnt) BEFORE the block barrier; then one
// relaxed flag store per block; 16 threads poll 16 padded flags in parallel.
// No __threadfence => no L2 writeback/invalidate => L2 stays warm.
__device__ __forceinline__ void gbar(int* flags, int blk, int gen)
{
  asm volatile("s_waitcnt vmcnt(0) lgkmcnt(0)" ::: "memory");
  __syncthreads();
  if (threadIdx.x == 0)
    __hip_atomic_store(flags + blk*FSTR_, gen, __ATOMIC_RELAXED, __HIP_MEMORY_SCOPE_AGENT);
  if (threadIdx.x < NBLK_) {
    while (__hip_atomic_load(flags + threadIdx.x*FSTR_, __ATOMIC_RELAXED,
                             __HIP_MEMORY_SCOPE_AGENT) < gen)
      __builtin_amdgcn_s_sleep(1);
  }
  __syncthreads();
}

// ---------------- persistent token-space scan (one launch per segment) ------
__global__ __launch_bounds__(256) void k_scan(
  const float* __restrict__ pW2T, const float* __restrict__ mW2T,
  float* __restrict__ pb1, float* __restrict__ mb1,
  float* __restrict__ pb2, float* __restrict__ mb2,
  const float* __restrict__ Vm,
  const float* __restrict__ q1k, const float* __restrict__ q1km,
  const float* __restrict__ G,
  float* __restrict__ dz1o, float* __restrict__ a1o, float* __restrict__ eo,
  float* __restrict__ exA1, float* __restrict__ exSP,
  float* __restrict__ exR, float* __restrict__ exEE,
  const float* __restrict__ coef, int* __restrict__ barbase, int seg)
{
  __shared__ float sW[64][132];
  __shared__ float sMW[64][132];
  __shared__ float sEh[128][66];
  __shared__ float sA1h[128][9];
  __shared__ float sDZ[128][9];
  __shared__ float sQ1K[128][8];
  __shared__ float sQ1KM[128][8];
  __shared__ float sAt[128];
  __shared__ float sBp[129];
  __shared__ float sB1[8], sMB1[8], sZ1[8], sR[8];
  __shared__ float sB2[64], sMB2[64], sE[64];
  __shared__ float sA1t[128];
  __shared__ float sS[128];
  __shared__ float sEEc[128];

  int b = blockIdx.y, blk = blockIdx.x, tid = threadIdx.x;
  int j0 = blk*64, h0 = blk*8;
  int* flags = barbase + b*(NBLK_*FSTR_);
  int gbase = seg*1000;

  for (int i = tid; i < 64*128; i += 256) {
    int jj = i >> 7, h = i & 127;
    sW[jj][h]  = pW2T[(long)b*131072 + (long)(j0+jj)*128 + h];
    sMW[jj][h] = mW2T[(long)b*131072 + (long)(j0+jj)*128 + h];
  }
  for (int i = tid; i < 128*8; i += 256) {
    int t2 = i >> 3, hh = i & 7;
    sQ1K[t2][hh]  = q1k [((long)b*SEG_ + t2)*W_ + h0 + hh];
    sQ1KM[t2][hh] = q1km[((long)b*SEG_ + t2)*W_ + h0 + hh];
  }
  if (tid < 128) sAt[tid] = coef[tid];
  for (int i = tid; i < 129; i += 256) sBp[i] = coef[256 + i];
  if (tid < 8)  { sB1[tid] = pb1[b*W_ + h0 + tid]; sMB1[tid] = mb1[b*W_ + h0 + tid]; }
  if (tid >= 64 && tid < 128) {
    int jj = tid - 64;
    sB2[jj] = pb2[b*D_ + j0 + jj]; sMB2[jj] = mb2[b*D_ + j0 + jj];
  }
  __syncthreads();

  for (int t = 0; t < SEG_; ++t) {
    int par = t & 1;
    float bp = sBp[t];
    float ca = (t > 0) ? ETA_*sAt[t-1] : 0.f;

    // ---- phase 1: b1 update, z1/a1 (h slice), sp partials ----
    if (t > 0 && tid < 8) {
      float mm = ETA_*sMB1[tid] - THETA_*sDZ[t-1][tid];
      sMB1[tid] = mm; sB1[tid] = PDEC_*sB1[tid] + mm;
    }
    __syncthreads();
    {
      int hh = tid >> 5, lane = tid & 31;
      float acc = 0.f;
      const float* Grow = G + ((long)b*SEG_ + t)*SEG_;
      for (int u = lane; u < t; u += 32)
        acc += sAt[t-1-u] * Grow[u] * sDZ[u][hh];
      for (int o = 16; o; o >>= 1) acc += __shfl_xor(acc, o);
      if (lane == 0) {
        int h = h0 + hh;
        float z1 = bp*sQ1K[t][hh] + ca*sQ1KM[t][hh] + sB1[hh] - THETA_*acc;
        sZ1[hh] = z1;
        float a1 = z1 * sigf(z1);
        sA1h[t][hh] = a1;
        gstore(&exA1[(long)par*(B_*W_) + b*W_ + h], a1);
        a1o[((long)b*SEG_ + t)*W_ + h] = a1;
      }
    }
    __syncthreads();
    if (tid < t) {
      float acc = 0.f;
      #pragma unroll
      for (int hh2 = 0; hh2 < 8; hh2++) acc += sA1h[tid][hh2]*sA1h[t][hh2];
      gstore(&exSP[(((long)par*B_ + b)*NBLK_ + blk)*W_ + tid], acc);
    }
    gbar(flags, blk, gbase + t*2 + 1);

    // ---- phase 2: gather a1/s, b2 update, z2/e (j slice), r/ee partials ----
    if (tid < 128) {
      sA1t[tid] = gload(&exA1[(long)par*(B_*W_) + b*W_ + tid]);
    } else {
      int u = tid - 128;
      if (u < t) {
        float s = 0.f;
        #pragma unroll 4
        for (int k2 = 0; k2 < NBLK_; k2++)
          s += gload(&exSP[(((long)par*B_ + b)*NBLK_ + k2)*W_ + u]);
        sS[u] = -2.f*THETA_*sAt[t-1-u]*s;
      }
    }
    __syncthreads();
    if (t > 0 && tid < 64) {
      float mm = ETA_*sMB2[tid] - 2.f*THETA_*sEh[t-1][tid];
      sMB2[tid] = mm; sB2[tid] = PDEC_*sB2[tid] + mm;
    }
    __syncthreads();
    {
      int jj = tid >> 2, l4 = tid & 3;
      float g0 = 0.f, gm = 0.f;
      for (int h = l4; h < 128; h += 4) {
        g0 = fmaf(sW[jj][h],  sA1t[h], g0);
        gm = fmaf(sMW[jj][h], sA1t[h], gm);
      }
      float corr = 0.f;
      for (int u = l4; u < t; u += 4) corr = fmaf(sS[u], sEh[u][jj], corr);
      float tot = bp*g0 + ca*gm + corr;
      tot += __shfl_xor(tot, 1); tot += __shfl_xor(tot, 2);
      if (l4 == 0) {
        float e = tot + sB2[jj] - Vm[((long)b*SEG_ + t)*D_ + j0 + jj];
        sEh[t][jj] = e; sE[jj] = e;
        eo[((long)b*SEG_ + t)*D_ + j0 + jj] = e;
      }
    }
    __syncthreads();
    {
      int h = tid >> 1, l = tid & 1;
      float r0 = 0.f, rm = 0.f;
      for (int jj = l*32; jj < l*32+32; jj++) {
        r0 = fmaf(sW[jj][h],  sE[jj], r0);
        rm = fmaf(sMW[jj][h], sE[jj], rm);
      }
      float rc = bp*r0 + ca*rm;
      rc += __shfl_xor(rc, 1);
      if (l == 0) gstore(&exR[(((long)par*B_ + b)*NBLK_ + blk)*W_ + h], rc);
    }
    {
      int u = tid >> 1, l = tid & 1;
      if (u < t) {
        float acc = 0.f;
        for (int jj = l*32; jj < l*32+32; jj++) acc = fmaf(sEh[u][jj], sE[jj], acc);
        acc += __shfl_xor(acc, 1);
        if (l == 0) gstore(&exEE[(((long)par*B_ + b)*NBLK_ + blk)*W_ + u], acc);
      }
    }
    gbar(flags, blk, gbase + t*2 + 2);

    // ---- phase 3: reduce r/ee, dz1 (h slice) ----
    if (tid < t) {
      float s = 0.f;
      #pragma unroll 4
      for (int k2 = 0; k2 < NBLK_; k2++)
        s += gload(&exEE[(((long)par*B_ + b)*NBLK_ + k2)*W_ + tid]);
      sEEc[tid] = -2.f*THETA_*sAt[t-1-tid]*s;
    }
    if (tid >= 128 && tid < 136) {
      int hh = tid - 128;
      float s = 0.f;
      #pragma unroll 4
      for (int k2 = 0; k2 < NBLK_; k2++)
        s += gload(&exR[(((long)par*B_ + b)*NBLK_ + k2)*W_ + h0 + hh]);
      sR[hh] = s;
    }
    __syncthreads();
    {
      int hh = tid >> 5, lane = tid & 31;
      float acc = 0.f;
      for (int u = lane; u < t; u += 32) acc = fmaf(sEEc[u], sA1h[u][hh], acc);
      for (int o = 16; o; o >>= 1) acc += __shfl_xor(acc, o);
      if (lane == 0) {
        float z = sZ1[hh];
        float sg = sigf(z);
        float dz = 2.f*(sR[hh] + acc) * sg*(1.f + z*(1.f - sg));
        sDZ[t][hh] = dz;
        dz1o[((long)b*SEG_ + t)*W_ + h0 + hh] = dz;
      }
    }
    __syncthreads();
  }

  // final bias state (t=128) writeback
  if (tid < 8) {
    float mm = ETA_*sMB1[tid] - THETA_*sDZ[127][tid];
    mb1[b*W_ + h0 + tid] = mm;
    pb1[b*W_ + h0 + tid] = PDEC_*sB1[tid] + mm;
  } else if (tid >= 64 && tid < 128) {
    int jj = tid - 64;
    float mm = ETA_*sMB2[jj] - 2.f*THETA_*sEh[127][jj];
    mb2[b*D_ + j0 + jj] = mm;
    pb2[b*D_ + j0 + jj] = PDEC_*sB2[jj] + mm;
  }
}

// ---------------- weight/momentum reconstruction --------------------------
__global__ __launch_bounds__(256) void k_recon(
  float* __restrict__ pW1, float* __restrict__ mW1,
  float* __restrict__ pW2T, float* __restrict__ mW2T,
  const float* __restrict__ KMp, const float* __restrict__ Eh,
  const float* __restrict__ DZ1, const float* __restrict__ A1h,
  const float* __restrict__ coef)
{
  __shared__ float s1[16][33];
  __shared__ float s2[16][65];
  __shared__ float sCA[128], sCE[128];
  int dt = blockIdx.x, ht = blockIdx.y, kb = blockIdx.z;
  int kind = kb >> 1, b = kb & 1;
  int tid = threadIdx.x;
  int d0 = dt*32, hb = ht*64;
  const float* in1 = (kind ? Eh : KMp) + (long)b*SEG_*D_;
  const float* in2 = (kind ? A1h : DZ1) + (long)b*SEG_*W_;
  float* Pb = (kind ? pW2T : pW1) + (long)b*131072;
  float* Mb = (kind ? mW2T : mW1) + (long)b*131072;
  float f = kind ? -2.f*THETA_ : -THETA_;
  if (tid < 128) {
    sCA[tid] = f*coef[127 - tid];
    sCE[tid] = f*coef[128 + 127 - tid];
  }
  __syncthreads();
  int dd = tid >> 3, le = tid & 7;
  float accP[8] = {}, accM[8] = {};
  for (int u0 = 0; u0 < 128; u0 += 16) {
    for (int i = tid; i < 16*32; i += 256) {
      int uu = i >> 5, d2 = i & 31;
      s1[uu][d2] = in1[(long)(u0+uu)*D_ + d0 + d2];
    }
    for (int i = tid; i < 16*64; i += 256) {
      int uu = i >> 6, hl = i & 63;
      s2[uu][hl] = in2[(long)(u0+uu)*W_ + hb + hl];
    }
    __syncthreads();
    #pragma unroll
    for (int uu = 0; uu < 16; uu++) {
      float a = s1[uu][dd];
      float cAu = sCA[u0+uu], cEu = sCE[u0+uu];
      #pragma unroll
      for (int k = 0; k < 8; k++) {
        float v = a * s2[uu][k*8 + le];
        accP[k] = fmaf(cAu, v, accP[k]);
        accM[k] = fmaf(cEu, v, accM[k]);
      }
    }
    __syncthreads();
  }
  float b128 = coef[256 + 128];
  float eA   = ETA_*coef[127];
  float e128 = ETA_*coef[128 + 127];
  #pragma unroll
  for (int k = 0; k < 8; k++) {
    long idx = (long)(d0+dd)*W_ + hb + k*8 + le;
    float Po = Pb[idx], Mo = Mb[idx];
    Pb[idx] = b128*Po + eA*Mo + accP[k];
    Mb[idx] = e128*Mo + accM[k];
  }
}

__global__ void k_mul(const float* __restrict__ so, const float* __restrict__ mo,
                      float* __restrict__ outs, int s)
{
  int l = blockIdx.x, b = blockIdx.y, tid = threadIdx.x;
  long src = ((long)b*SEG_ + l)*D_ + tid*4;
  float4 a = *(const float4*)(so + src);
  float4 c = *(const float4*)(mo + src);
  a.x*=c.x; a.y*=c.y; a.z*=c.z; a.w*=c.w;
  *(float4*)(outs + ((long)b*N_ + s*SEG_ + l)*D_ + tid*4) = a;
}

// ---------------- host launcher ----------------
static inline void gemm(const float* A, const float* Bm, const float* bias, float* C,
                        int M, int N, int K, long sA, long sB, long sC, long sBias,
                        int batch, int bt, int silu_, hipStream_t st)
{
  dim3 g(N/64, (M+63)/64, batch), blk(256);
  if (!bt && !silu_) k_gemm<0,0><<<g,blk,0,st>>>(A,Bm,bias,C,M,N,K,sA,sB,sC,sBias);
  else if (!bt && silu_) k_gemm<0,1><<<g,blk,0,st>>>(A,Bm,bias,C,M,N,K,sA,sB,sC,sBias);
  else k_gemm<1,0><<<g,blk,0,st>>>(A,Bm,bias,C,M,N,K,sA,sB,sC,sBias);
}

extern "C" void kernel_launch(void* const* d_in, const int* in_sizes, int n_in,
                              void* d_out, int out_size, void* d_ws, size_t ws_size,
                              hipStream_t stream)
{
  (void)in_sizes; (void)n_in; (void)out_size; (void)ws_size;
  const int*   x     = (const int*)  d_in[0];
  const float* emb   = (const float*)d_in[1];
  const float* pers  = (const float*)d_in[2];
  const float* Wq    = (const float*)d_in[3];
  const float* bq    = (const float*)d_in[4];
  const float* Wk    = (const float*)d_in[5];
  const float* bk    = (const float*)d_in[6];
  const float* Wv    = (const float*)d_in[7];
  const float* bv    = (const float*)d_in[8];
  const float* aiw   = (const float*)d_in[9];
  const float* aib   = (const float*)d_in[10];
  const float* aow   = (const float*)d_in[11];
  const float* aob   = (const float*)d_in[12];
  const float* mW1in = (const float*)d_in[13];
  const float* mb1in = (const float*)d_in[14];
  const float* mW2in = (const float*)d_in[15];
  const float* mb2in = (const float*)d_in[16];
  const float* headw = (const float*)d_in[17];
  const float* headb = (const float*)d_in[18];
  float* out = (float*)d_out;
  float* ws  = (float*)d_ws;

  hipMemsetAsync(ws + MOM, 0, MOMSZ*sizeof(float), stream);
  hipMemsetAsync(ws + ZEROB, 0, 128*sizeof(float), stream);
  hipMemsetAsync(ws + CBAR, 0, 1024*sizeof(int), stream);
  k_embed<<<dim3(B_*N_), dim3(256), 0, stream>>>(x, emb, ws+XEMB);
  k_init<<<dim3((2*PER_+255)/256), dim3(256), 0, stream>>>(
      mW1in, mb1in, mW2in, mb2in, ws+PW1, ws+PB1, ws+PW2T, ws+PB2);
  k_coef<<<dim3(1), dim3(64), 0, stream>>>(ws+COEF);

  for (int s = 0; s < NSEG_; s++) {
    const float* segA = ws + XEMB + (size_t)s*SEG_*D_;
    // h = mlp(p, l2n(seg @ Wq + bq))
    gemm(segA, Wq, bq, ws+Q1, SEG_, D_, D_, (long)N_*D_, 0, (long)SEG_*D_, 0, B_, 0, 0, stream);
    k_l2n<<<dim3(B_*SEG_), dim3(256), 0, stream>>>(ws+Q1);
    gemm(ws+Q1, ws+PW1, ws+PB1, ws+AH, SEG_, W_, D_, (long)SEG_*D_, (long)D_*W_, (long)SEG_*W_, W_, B_, 0, 1, stream);
    gemm(ws+AH, ws+PW2T, ws+PB2, ws+HBUF, SEG_, D_, W_, (long)SEG_*W_, (long)D_*W_, (long)SEG_*D_, D_, B_, 1, 0, stream);
    // attention
    k_concat<<<dim3(T_, B_), dim3(256), 0, stream>>>(pers, ws+HBUF, ws+XEMB, s, ws+COMB);
    k_gemm128<<<dim3(3*D_/128, (B_*T_+127)/128), dim3(256), 0, stream>>>(
        ws+COMB, aiw, aib, ws+QKV, B_*T_, 3*D_, D_);
    k_attn<<<dim3(8, NH_, B_), dim3(256), 0, stream>>>(ws+QKV, ws+ATTN);
    gemm(ws+ATTN, aow, aob, ws+SEGO, B_*SEG_, D_, D_, 0, 0, 0, 0, 1, 0, 0, stream);
    // K/V projections
    gemm(ws+SEGO, Wk, bk, ws+KM, B_*SEG_, D_, D_, 0, 0, 0, 0, 1, 0, 0, stream);
    k_l2n<<<dim3(B_*SEG_), dim3(256), 0, stream>>>(ws+KM);
    gemm(ws+SEGO, Wv, bv, ws+VM, B_*SEG_, D_, D_, 0, 0, 0, 0, 1, 0, 0, stream);
    // token-space scan precompute: Q1K = K@W1, Q1Km = K@mW1, G = K@K^T
    gemm(ws+KM, ws+PW1, ws+ZEROB, ws+AQ1K,  SEG_, W_, D_, (long)SEG_*D_, (long)D_*W_, (long)SEG_*W_, 0, B_, 0, 0, stream);
    gemm(ws+KM, ws+MW1, ws+ZEROB, ws+AQ1KM, SEG_, W_, D_, (long)SEG_*D_, (long)D_*W_, (long)SEG_*W_, 0, B_, 0, 0, stream);
    gemm(ws+KM, ws+KM,  ws+ZEROB, ws+AGRAM, SEG_, SEG_, D_, (long)SEG_*D_, (long)SEG_*D_, (long)SEG_*SEG_, 0, B_, 1, 0, stream);
    // the scan itself (one launch)
    k_scan<<<dim3(NBLK_, B_), dim3(256), 0, stream>>>(
        ws+PW2T, ws+MW2T, ws+PB1, ws+MB1, ws+PB2, ws+MB2, ws+VM,
        ws+AQ1K, ws+AQ1KM, ws+AGRAM,
        ws+ADZ1, ws+AA1H, ws+AEH,
        ws+AEXA1, ws+AEXSP, ws+AEXR, ws+AEXEE,
        ws+COEF, (int*)(ws+CBAR), s);
    // reconstruct W1/mW1/W2T/mW2T
    k_recon<<<dim3(32, 2, 4), dim3(256), 0, stream>>>(
        ws+PW1, ws+MW1, ws+PW2T, ws+MW2T,
        ws+KM, ws+AEH, ws+ADZ1, ws+AA1H, ws+COEF);
    // mem_out = mlp(p, l2n(seg_out @ Wq + bq)); outs = seg_out * mem_out
    gemm(ws+SEGO, Wq, bq, ws+Q1, B_*SEG_, D_, D_, 0, 0, 0, 0, 1, 0, 0, stream);
    k_l2n<<<dim3(B_*SEG_), dim3(256), 0, stream>>>(ws+Q1);
    gemm(ws+Q1, ws+PW1, ws+PB1, ws+AH, SEG_, W_, D_, (long)SEG_*D_, (long)D_*W_, (long)SEG_*W_, W_, B_, 0, 1, stream);
    gemm(ws+AH, ws+PW2T, ws+PB2, ws+MEMO, SEG_, D_, W_, (long)SEG_*W_, (long)D_*W_, (long)SEG_*D_, D_, B_, 1, 0, stream);
    k_mul<<<dim3(SEG_, B_), dim3(256), 0, stream>>>(ws+SEGO, ws+MEMO, ws+OUTS, s);
  }
  // head: out = full @ head_w + head_b (128x128-tile GEMM)
  k_gemm128<<<dim3(V_/128, (B_*N_)/128), dim3(256), 0, stream>>>(
      ws+OUTS, headw, headb, out, B_*N_, V_, D_);
}

// Round 7
// 9194.929 us; speedup vs baseline: 1.4142x; 1.0590x over previous
//
#include <hip/hip_runtime.h>
#include <math.h>

#define D_    1024
#define B_    2
#define N_    512
#define SEG_  128
#define NSEG_ 4
#define NPT_  16
#define T_    272
#define NH_   16
#define HD_   64
#define W_    128
#define V_    32000

#define THETA_ 0.1f
#define ETA_   0.9f
#define PDEC_  0.99f
#define EPSN_  1e-6f
#define NBLK_ 16
#define FSTR_ 32   // flag stride in ints (128B = 1 cacheline)

// ---------------- workspace layout (float offsets) ----------------
static const size_t XEMB = 0;                       // [B,N,D]
static const size_t OUTS = XEMB + (size_t)B_*N_*D_; // [B,N,D]
static const size_t PW1  = OUTS + (size_t)B_*N_*D_; // [B,1024,128]
static const size_t PB1  = PW1  + (size_t)B_*D_*W_; // [B,128]
static const size_t PW2T = PB1  + (size_t)B_*W_;    // [B,1024,128]  (W2 transposed: [j][h])
static const size_t PB2  = PW2T + (size_t)B_*D_*W_; // [B,1024]
static const size_t MOM  = PB2  + (size_t)B_*D_;    // momentum block (contiguous, memset 0)
static const size_t MW1  = MOM;
static const size_t MB1  = MW1  + (size_t)B_*D_*W_;
static const size_t MW2T = MB1  + (size_t)B_*W_;
static const size_t MB2  = MW2T + (size_t)B_*D_*W_;
static const size_t MOMSZ = (size_t)B_*(D_*W_ + W_ + D_*W_ + D_);
static const size_t Q1   = MOM  + MOMSZ;            // [B,128,1024]
static const size_t AH   = Q1   + (size_t)B_*SEG_*D_; // [B,128,128]
static const size_t HBUF = AH   + (size_t)B_*SEG_*W_; // [B,128,1024]
static const size_t COMB = HBUF + (size_t)B_*SEG_*D_; // [B,272,1024]
static const size_t QKV  = COMB + (size_t)B_*T_*D_;   // [B,272,3072]
static const size_t ATTN = QKV  + (size_t)B_*T_*3*D_; // [B,128,1024]
static const size_t SEGO = ATTN + (size_t)B_*SEG_*D_; // [B,128,1024]
static const size_t KM   = SEGO + (size_t)B_*SEG_*D_; // [B,128,1024]
static const size_t VM   = KM   + (size_t)B_*SEG_*D_; // [B,128,1024]
static const size_t MEMO = VM   + (size_t)B_*SEG_*D_; // [B,128,1024]
static const size_t WSEND = MEMO + (size_t)B_*SEG_*D_;

// scan-phase buffers ALIAS the QKV region
static const size_t AQ1K  = QKV;                 // [B,128,128]
static const size_t AQ1KM = AQ1K  + 32768;       // [B,128,128]
static const size_t AGRAM = AQ1KM + 32768;       // [B,128,128]
static const size_t ADZ1  = AGRAM + 32768;       // [B,128,128]
static const size_t AA1H  = ADZ1  + 32768;       // [B,128,128]
static const size_t AEH   = AA1H  + 32768;       // [B,128,1024]
static const size_t AEXA1 = AEH + (size_t)B_*SEG_*D_;  // [2][B][128]
static const size_t AEXSP = AEXA1 + 512;         // [2][B][16][128]
static const size_t AEXR  = AEXSP + 8192;
static const size_t AEXEE = AEXR  + 8192;
// persistent tail (must NOT alias QKV)
static const size_t COEF  = WSEND;               // A[128], etaPow[128], betaPow[129]
static const size_t ZEROB = COEF + 512;          // 128 zeros (GEMM zero-bias)
static const size_t CBAR  = ZEROB + 128;         // [B][NBLK][FSTR] ints = 1024 ints

__device__ __forceinline__ float sigf(float x) { return 1.f/(1.f+expf(-x)); }

// MALL-coherent (L2-bypassing) exchange accessors — no fences needed
__device__ __forceinline__ void gstore(float* p, float v) {
  __hip_atomic_store(p, v, __ATOMIC_RELAXED, __HIP_MEMORY_SCOPE_AGENT);
}
__device__ __forceinline__ float gload(const float* p) {
  return __hip_atomic_load(p, __ATOMIC_RELAXED, __HIP_MEMORY_SCOPE_AGENT);
}

// ---------------- generic tiled fp32 GEMM (64x64) ----------------
template<int BT, int SILU>
__global__ __launch_bounds__(256) void k_gemm(
    const float* __restrict__ A, const float* __restrict__ Bm,
    const float* __restrict__ bias, float* __restrict__ C,
    int M, int N, int K, long sA, long sB, long sC, long sBias)
{
  __shared__ float As[16][68];
  __shared__ float Bs[16][68];
  int bz = blockIdx.z;
  A += bz*sA; Bm += bz*sB; C += bz*sC; bias += bz*sBias;
  int n0 = blockIdx.x*64, m0 = blockIdx.y*64;
  int tid = threadIdx.x;
  int tx = tid & 15, ty = tid >> 4;
  int r  = tid >> 2;
  int kq = (tid & 3) * 4;
  float acc[4][4] = {};
  for (int k0 = 0; k0 < K; k0 += 16) {
    {
      int row = m0 + r;
      float4 v = make_float4(0.f,0.f,0.f,0.f);
      if (row < M) v = *(const float4*)(A + (long)row*K + k0 + kq);
      As[kq+0][r]=v.x; As[kq+1][r]=v.y; As[kq+2][r]=v.z; As[kq+3][r]=v.w;
    }
    if (BT) {
      int row = n0 + r;
      float4 v = *(const float4*)(Bm + (long)row*K + k0 + kq);
      Bs[kq+0][r]=v.x; Bs[kq+1][r]=v.y; Bs[kq+2][r]=v.z; Bs[kq+3][r]=v.w;
    } else {
      int c = tid & 63, r4 = tid >> 6;
      #pragma unroll
      for (int p = 0; p < 4; p++) {
        int kk = r4 + p*4;
        Bs[kk][c] = Bm[(long)(k0+kk)*N + n0 + c];
      }
    }
    __syncthreads();
    #pragma unroll
    for (int kk = 0; kk < 16; kk++) {
      float av[4], bv[4];
      #pragma unroll
      for (int i=0;i<4;i++) av[i] = As[kk][ty*4+i];
      #pragma unroll
      for (int j=0;j<4;j++) bv[j] = Bs[kk][tx*4+j];
      #pragma unroll
      for (int i=0;i<4;i++)
        #pragma unroll
        for (int j=0;j<4;j++)
          acc[i][j] = fmaf(av[i], bv[j], acc[i][j]);
    }
    __syncthreads();
  }
  #pragma unroll
  for (int i=0;i<4;i++) {
    int row = m0 + ty*4 + i;
    if (row >= M) continue;
    #pragma unroll
    for (int j=0;j<4;j++) {
      int col = n0 + tx*4 + j;
      float v = acc[i][j] + bias[col];
      if (SILU) v = v * sigf(v);
      C[(long)row*N + col] = v;
    }
  }
}

// ------- 128x128 tile fp32 GEMM (M-guarded; N,K multiples of 128/16) -------
__global__ __launch_bounds__(256) void k_gemm128(
    const float* __restrict__ A, const float* __restrict__ Bm,
    const float* __restrict__ bias, float* __restrict__ C,
    int M, int N, int K)
{
  __shared__ float As[16][132];
  __shared__ float Bs[16][132];
  int n0 = blockIdx.x*128, m0 = blockIdx.y*128;
  int tid = threadIdx.x;
  int tx = tid & 15, ty = tid >> 4;
  int ar = tid >> 1, ak = (tid & 1) * 8;
  int bk = tid >> 4, bn = (tid & 15) * 8;
  int arow = min(m0 + ar, M-1);    // clamp for OOB tail rows (dup loads harmless)
  float acc[8][8] = {};
  for (int k0 = 0; k0 < K; k0 += 16) {
    {
      const float* ap = A + (long)arow*K + k0 + ak;
      float4 v0 = *(const float4*)(ap);
      float4 v1 = *(const float4*)(ap+4);
      As[ak+0][ar]=v0.x; As[ak+1][ar]=v0.y; As[ak+2][ar]=v0.z; As[ak+3][ar]=v0.w;
      As[ak+4][ar]=v1.x; As[ak+5][ar]=v1.y; As[ak+6][ar]=v1.z; As[ak+7][ar]=v1.w;
      const float* bp = Bm + (long)(k0+bk)*N + n0 + bn;
      float4 w0 = *(const float4*)(bp);
      float4 w1 = *(const float4*)(bp+4);
      *(float4*)(&Bs[bk][bn])   = w0;
      *(float4*)(&Bs[bk][bn+4]) = w1;
    }
    __syncthreads();
    #pragma unroll
    for (int kk = 0; kk < 16; kk++) {
      float av[8], bv[8];
      #pragma unroll
      for (int i=0;i<8;i++) av[i] = As[kk][ty*8+i];
      #pragma unroll
      for (int j=0;j<8;j++) bv[j] = Bs[kk][tx*8+j];
      #pragma unroll
      for (int i=0;i<8;i++)
        #pragma unroll
        for (int j=0;j<8;j++)
          acc[i][j] = fmaf(av[i], bv[j], acc[i][j]);
    }
    __syncthreads();
  }
  #pragma unroll
  for (int i=0;i<8;i++) {
    int row = m0 + ty*8 + i;
    if (row >= M) continue;
    #pragma unroll
    for (int j=0;j<8;j++) acc[i][j] += bias[n0 + tx*8 + j];
    *(float4*)(C + (long)row*N + n0 + tx*8)     = make_float4(acc[i][0],acc[i][1],acc[i][2],acc[i][3]);
    *(float4*)(C + (long)row*N + n0 + tx*8 + 4) = make_float4(acc[i][4],acc[i][5],acc[i][6],acc[i][7]);
  }
}

// ------- fused K/V/Q projection: SEGO[256,1024] x {Wk,Wv,Wq} -> KM,VM,Q1 ----
// grid (24, 2): bx selects which weight matrix (bx/8) and its column tile.
__global__ __launch_bounds__(256) void k_gemmkvq(
    const float* __restrict__ A,
    const float* __restrict__ Wk, const float* __restrict__ bk,
    const float* __restrict__ Wv, const float* __restrict__ bv,
    const float* __restrict__ Wq, const float* __restrict__ bq,
    float* __restrict__ KMo, float* __restrict__ VMo, float* __restrict__ Q1o)
{
  __shared__ float As[16][132];
  __shared__ float Bs[16][132];
  int bx = blockIdx.x;
  int sel = bx >> 3;
  int c0 = (bx & 7) * 128;        // column within the selected 1024-wide matrix
  int m0 = blockIdx.y * 128;
  const float* Bm   = sel == 0 ? Wk : sel == 1 ? Wv : Wq;
  const float* bias = sel == 0 ? bk : sel == 1 ? bv : bq;
  float* C          = sel == 0 ? KMo : sel == 1 ? VMo : Q1o;
  int tid = threadIdx.x;
  int tx = tid & 15, ty = tid >> 4;
  int ar = tid >> 1, ak = (tid & 1) * 8;
  int bkr = tid >> 4, bn = (tid & 15) * 8;
  float acc[8][8] = {};
  for (int k0 = 0; k0 < D_; k0 += 16) {
    {
      const float* ap = A + (long)(m0+ar)*D_ + k0 + ak;
      float4 v0 = *(const float4*)(ap);
      float4 v1 = *(const float4*)(ap+4);
      As[ak+0][ar]=v0.x; As[ak+1][ar]=v0.y; As[ak+2][ar]=v0.z; As[ak+3][ar]=v0.w;
      As[ak+4][ar]=v1.x; As[ak+5][ar]=v1.y; As[ak+6][ar]=v1.z; As[ak+7][ar]=v1.w;
      const float* bp = Bm + (long)(k0+bkr)*D_ + c0 + bn;
      *(float4*)(&Bs[bkr][bn])   = *(const float4*)(bp);
      *(float4*)(&Bs[bkr][bn+4]) = *(const float4*)(bp+4);
    }
    __syncthreads();
    #pragma unroll
    for (int kk = 0; kk < 16; kk++) {
      float av[8], bv8[8];
      #pragma unroll
      for (int i=0;i<8;i++) av[i] = As[kk][ty*8+i];
      #pragma unroll
      for (int j=0;j<8;j++) bv8[j] = Bs[kk][tx*8+j];
      #pragma unroll
      for (int i=0;i<8;i++)
        #pragma unroll
        for (int j=0;j<8;j++)
          acc[i][j] = fmaf(av[i], bv8[j], acc[i][j]);
    }
    __syncthreads();
  }
  #pragma unroll
  for (int i=0;i<8;i++) {
    int row = m0 + ty*8 + i;
    #pragma unroll
    for (int j=0;j<8;j++) acc[i][j] += bias[c0 + tx*8 + j];
    *(float4*)(C + (long)row*D_ + c0 + tx*8)     = make_float4(acc[i][0],acc[i][1],acc[i][2],acc[i][3]);
    *(float4*)(C + (long)row*D_ + c0 + tx*8 + 4) = make_float4(acc[i][4],acc[i][5],acc[i][6],acc[i][7]);
  }
}

// ---------------- small kernels ----------------
__global__ void k_embed(const int* __restrict__ x, const float* __restrict__ emb,
                        float* __restrict__ xe)
{
  int row = blockIdx.x, tid = threadIdx.x;
  int idx = x[row];
  float4 v = *(const float4*)(emb + (long)idx*D_ + tid*4);
  *(float4*)(xe + (long)row*D_ + tid*4) = v;
}

#define PER_ 263296L
__global__ void k_init(const float* __restrict__ mW1in, const float* __restrict__ mb1in,
                       const float* __restrict__ mW2in, const float* __restrict__ mb2in,
                       float* __restrict__ pW1, float* __restrict__ pb1,
                       float* __restrict__ pW2T, float* __restrict__ pb2)
{
  long g = (long)blockIdx.x*256 + threadIdx.x;
  if (g >= 2*PER_) return;
  int b = (int)(g / PER_);
  long rr = g % PER_;
  if (rr < 131072)       pW1[(long)b*131072 + rr] = mW1in[rr];
  else if (rr < 131200)  pb1[b*W_ + (rr-131072)] = mb1in[rr-131072];
  else if (rr < 262272) { long l = rr-131200; int j=(int)(l>>7), h=(int)(l&127);
                          pW2T[(long)b*131072 + l] = mW2in[(long)h*D_ + j]; }
  else                   pb2[b*D_ + (rr-262272)] = mb2in[rr-262272];
}

__global__ void k_coef(float* __restrict__ c)
{
  if (blockIdx.x == 0 && threadIdx.x == 0) {
    c[0] = 1.f; c[128] = 1.f;
    float A = 1.f, eta_d = 1.f;
    for (int d = 1; d < 128; d++) {
      eta_d *= ETA_;
      A = PDEC_*A + eta_d;
      c[d] = A;
      c[128 + d] = eta_d;
    }
    c[256] = 1.f;
    float bp = 1.f;
    for (int t = 1; t <= 128; t++) { bp *= PDEC_; c[256 + t] = bp; }
  }
}

__global__ __launch_bounds__(256) void k_l2n(float* __restrict__ X)
{
  long row = blockIdx.x;
  float* p = X + row*D_;
  int tid = threadIdx.x;
  float4 v = *(float4*)(p + tid*4);
  float ss = v.x*v.x + v.y*v.y + v.z*v.z + v.w*v.w;
  for (int o=32;o;o>>=1) ss += __shfl_xor(ss,o);
  __shared__ float wsum[4];
  if ((tid&63)==0) wsum[tid>>6] = ss;
  __syncthreads();
  float tot = wsum[0]+wsum[1]+wsum[2]+wsum[3];
  float sc = 1.f/(sqrtf(tot)+EPSN_);
  v.x*=sc; v.y*=sc; v.z*=sc; v.w*=sc;
  *(float4*)(p + tid*4) = v;
}

__global__ void k_concat(const float* __restrict__ pers, const float* __restrict__ h,
                         const float* __restrict__ xemb, int s, float* __restrict__ comb)
{
  int row = blockIdx.x, b = blockIdx.y, tid = threadIdx.x;
  const float* src;
  if (row < NPT_)            src = pers + (long)row*D_;
  else if (row < NPT_+SEG_)  src = h    + ((long)b*SEG_ + (row-NPT_))*D_;
  else                       src = xemb + ((long)b*N_ + s*SEG_ + (row-NPT_-SEG_))*D_;
  float4 v = *(const float4*)(src + tid*4);
  *(float4*)(comb + ((long)b*T_ + row)*D_ + tid*4) = v;
}

__global__ __launch_bounds__(256) void k_attn(const float* __restrict__ qkv,
                                              float* __restrict__ outp)
{
  __shared__ float sQ[16][68];
  __shared__ float sKV[64][68];
  __shared__ float sS[16][273];
  int qt = blockIdx.x, head = blockIdx.y, b = blockIdx.z;
  int tid = threadIdx.x;
  const float* base = qkv + (long)b*T_*3*D_;
  int qoff = head*HD_, koff = D_ + head*HD_, voff = 2*D_ + head*HD_;
  int qrow0 = NPT_ + SEG_ + qt*16;
  {
    int rr = tid>>4, c4 = (tid&15)*4;
    float4 v = *(const float4*)(base + (long)(qrow0+rr)*3*D_ + qoff + c4);
    sQ[rr][c4]=v.x; sQ[rr][c4+1]=v.y; sQ[rr][c4+2]=v.z; sQ[rr][c4+3]=v.w;
  }
  __syncthreads();
  for (int j0 = 0; j0 < T_; j0 += 64) {
    int chunk = min(64, T_ - j0);
    {
      int jj = tid>>2, cq = (tid&3)*16;
      if (jj < chunk) {
        #pragma unroll
        for (int q4=0;q4<4;q4++) {
          float4 v = *(const float4*)(base + (long)(j0+jj)*3*D_ + koff + cq + q4*4);
          sKV[jj][cq+q4*4]=v.x; sKV[jj][cq+q4*4+1]=v.y; sKV[jj][cq+q4*4+2]=v.z; sKV[jj][cq+q4*4+3]=v.w;
        }
      }
    }
    __syncthreads();
    int rr = tid>>4, jj0 = tid&15;
    #pragma unroll
    for (int p=0;p<4;p++) {
      int jj = jj0 + p*16;
      if (jj < chunk) {
        float s = 0.f;
        #pragma unroll 8
        for (int c=0;c<HD_;c++) s = fmaf(sQ[rr][c], sKV[jj][c], s);
        s *= 0.125f;
        int jg = j0 + jj, qg = qrow0 + rr;
        if (jg > qg) s = -3.0e38f;
        sS[rr][jg] = s;
      }
    }
    __syncthreads();
  }
  {
    int rr = tid>>4, l16 = tid&15;
    float m = -3.4e38f;
    for (int j=l16; j<T_; j+=16) m = fmaxf(m, sS[rr][j]);
    for (int o=8;o;o>>=1) m = fmaxf(m, __shfl_xor(m,o));
    float sum = 0.f;
    for (int j=l16; j<T_; j+=16) { float e = expf(sS[rr][j]-m); sS[rr][j] = e; sum += e; }
    for (int o=8;o;o>>=1) sum += __shfl_xor(sum,o);
    float inv = 1.f/sum;
    for (int j=l16; j<T_; j+=16) sS[rr][j] *= inv;
  }
  __syncthreads();
  float acc[4] = {0.f,0.f,0.f,0.f};
  int rr = tid>>4, c4 = (tid&15)*4;
  for (int j0 = 0; j0 < T_; j0 += 64) {
    int chunk = min(64, T_ - j0);
    {
      int jj = tid>>2, cq = (tid&3)*16;
      if (jj < chunk) {
        #pragma unroll
        for (int q4=0;q4<4;q4++) {
          float4 v = *(const float4*)(base + (long)(j0+jj)*3*D_ + voff + cq + q4*4);
          sKV[jj][cq+q4*4]=v.x; sKV[jj][cq+q4*4+1]=v.y; sKV[jj][cq+q4*4+2]=v.z; sKV[jj][cq+q4*4+3]=v.w;
        }
      }
    }
    __syncthreads();
    for (int jj=0; jj<chunk; jj++) {
      float p = sS[rr][j0+jj];
      #pragma unroll
      for (int i=0;i<4;i++) acc[i] = fmaf(p, sKV[jj][c4+i], acc[i]);
    }
    __syncthreads();
  }
  float4 o4 = make_float4(acc[0],acc[1],acc[2],acc[3]);
  *(float4*)(outp + ((long)(b*SEG_) + qt*16 + rr)*D_ + head*HD_ + c4) = o4;
}

// ------- fence-free flag barrier (exchange data uses MALL atomics) ---------
__device__ __forceinline__ void gbar(int* flags, int blk, int gen)
{
  asm volatile("s_waitcnt vmcnt(0) lgkmcnt(0)" ::: "memory");
  __syncthreads();
  if (threadIdx.x == 0)
    __hip_atomic_store(flags + blk*FSTR_, gen, __ATOMIC_RELAXED, __HIP_MEMORY_SCOPE_AGENT);
  if (threadIdx.x < NBLK_) {
    while (__hip_atomic_load(flags + threadIdx.x*FSTR_, __ATOMIC_RELAXED,
                             __HIP_MEMORY_SCOPE_AGENT) < gen)
      __builtin_amdgcn_s_sleep(1);
  }
  __syncthreads();
}

// ---------------- persistent token-space scan (one launch per segment) ------
__global__ __launch_bounds__(256) void k_scan(
  const float* __restrict__ pW2T, const float* __restrict__ mW2T,
  float* __restrict__ pb1, float* __restrict__ mb1,
  float* __restrict__ pb2, float* __restrict__ mb2,
  const float* __restrict__ Vm,
  const float* __restrict__ q1k, const float* __restrict__ q1km,
  const float* __restrict__ G,
  float* __restrict__ dz1o, float* __restrict__ a1o, float* __restrict__ eo,
  float* __restrict__ exA1, float* __restrict__ exSP,
  float* __restrict__ exR, float* __restrict__ exEE,
  const float* __restrict__ coef, int* __restrict__ barbase, int seg)
{
  __shared__ float sW[64][132];
  __shared__ float sMW[64][132];
  __shared__ float sEh[128][66];
  __shared__ float sA1h[128][9];
  __shared__ float sDZ[128][9];
  __shared__ float sQ1K[128][8];
  __shared__ float sQ1KM[128][8];
  __shared__ float sAt[128];
  __shared__ float sBp[129];
  __shared__ float sB1[8], sMB1[8], sZ1[8], sR[8];
  __shared__ float sB2[64], sMB2[64], sE[64];
  __shared__ float sA1t[128];
  __shared__ float sS[128];
  __shared__ float sEEc[128];

  int b = blockIdx.y, blk = blockIdx.x, tid = threadIdx.x;
  int j0 = blk*64, h0 = blk*8;
  int* flags = barbase + b*(NBLK_*FSTR_);
  int gbase = seg*1000;

  for (int i = tid; i < 64*128; i += 256) {
    int jj = i >> 7, h = i & 127;
    sW[jj][h]  = pW2T[(long)b*131072 + (long)(j0+jj)*128 + h];
    sMW[jj][h] = mW2T[(long)b*131072 + (long)(j0+jj)*128 + h];
  }
  for (int i = tid; i < 128*8; i += 256) {
    int t2 = i >> 3, hh = i & 7;
    sQ1K[t2][hh]  = q1k [((long)b*SEG_ + t2)*W_ + h0 + hh];
    sQ1KM[t2][hh] = q1km[((long)b*SEG_ + t2)*W_ + h0 + hh];
  }
  if (tid < 128) sAt[tid] = coef[tid];
  for (int i = tid; i < 129; i += 256) sBp[i] = coef[256 + i];
  if (tid < 8)  { sB1[tid] = pb1[b*W_ + h0 + tid]; sMB1[tid] = mb1[b*W_ + h0 + tid]; }
  if (tid >= 64 && tid < 128) {
    int jj = tid - 64;
    sB2[jj] = pb2[b*D_ + j0 + jj]; sMB2[jj] = mb2[b*D_ + j0 + jj];
  }
  __syncthreads();

  for (int t = 0; t < SEG_; ++t) {
    int par = t & 1;
    float bp = sBp[t];
    float ca = (t > 0) ? ETA_*sAt[t-1] : 0.f;

    // ---- phase 1: b1 update, z1/a1 (h slice), sp partials ----
    if (t > 0 && tid < 8) {
      float mm = ETA_*sMB1[tid] - THETA_*sDZ[t-1][tid];
      sMB1[tid] = mm; sB1[tid] = PDEC_*sB1[tid] + mm;
    }
    __syncthreads();
    {
      int hh = tid >> 5, lane = tid & 31;
      float acc = 0.f;
      const float* Grow = G + ((long)b*SEG_ + t)*SEG_;
      for (int u = lane; u < t; u += 32)
        acc += sAt[t-1-u] * Grow[u] * sDZ[u][hh];
      for (int o = 16; o; o >>= 1) acc += __shfl_xor(acc, o);
      if (lane == 0) {
        int h = h0 + hh;
        float z1 = bp*sQ1K[t][hh] + ca*sQ1KM[t][hh] + sB1[hh] - THETA_*acc;
        sZ1[hh] = z1;
        float a1 = z1 * sigf(z1);
        sA1h[t][hh] = a1;
        gstore(&exA1[(long)par*(B_*W_) + b*W_ + h], a1);
      }
    }
    __syncthreads();
    if (tid < t) {
      float acc = 0.f;
      #pragma unroll
      for (int hh2 = 0; hh2 < 8; hh2++) acc += sA1h[tid][hh2]*sA1h[t][hh2];
      gstore(&exSP[(((long)par*B_ + b)*NBLK_ + blk)*W_ + tid], acc);
    }
    gbar(flags, blk, gbase + t*2 + 1);

    // ---- phase 2: gather a1/s, b2 update, z2/e (j slice), r/ee partials ----
    if (tid < 128) {
      sA1t[tid] = gload(&exA1[(long)par*(B_*W_) + b*W_ + tid]);
    } else {
      int u = tid - 128;
      if (u < t) {
        float s = 0.f;
        #pragma unroll
        for (int k2 = 0; k2 < NBLK_; k2++)
          s += gload(&exSP[(((long)par*B_ + b)*NBLK_ + k2)*W_ + u]);
        sS[u] = -2.f*THETA_*sAt[t-1-u]*s;
      }
    }
    __syncthreads();
    if (t > 0 && tid < 64) {
      float mm = ETA_*sMB2[tid] - 2.f*THETA_*sEh[t-1][tid];
      sMB2[tid] = mm; sB2[tid] = PDEC_*sB2[tid] + mm;
    }
    __syncthreads();
    {
      int jj = tid >> 2, l4 = tid & 3;
      float g0 = 0.f, gm = 0.f;
      for (int h = l4; h < 128; h += 4) {
        g0 = fmaf(sW[jj][h],  sA1t[h], g0);
        gm = fmaf(sMW[jj][h], sA1t[h], gm);
      }
      float corr = 0.f;
      for (int u = l4; u < t; u += 4) corr = fmaf(sS[u], sEh[u][jj], corr);
      float tot = bp*g0 + ca*gm + corr;
      tot += __shfl_xor(tot, 1); tot += __shfl_xor(tot, 2);
      if (l4 == 0) {
        float e = tot + sB2[jj] - Vm[((long)b*SEG_ + t)*D_ + j0 + jj];
        sEh[t][jj] = e; sE[jj] = e;
      }
    }
    __syncthreads();
    {
      int h = tid >> 1, l = tid & 1;
      float r0 = 0.f, rm = 0.f;
      for (int jj = l*32; jj < l*32+32; jj++) {
        r0 = fmaf(sW[jj][h],  sE[jj], r0);
        rm = fmaf(sMW[jj][h], sE[jj], rm);
      }
      float rc = bp*r0 + ca*rm;
      rc += __shfl_xor(rc, 1);
      if (l == 0) gstore(&exR[(((long)par*B_ + b)*NBLK_ + blk)*W_ + h], rc);
    }
    {
      int u = tid >> 1, l = tid & 1;
      if (u < t) {
        float acc = 0.f;
        for (int jj = l*32; jj < l*32+32; jj++) acc = fmaf(sEh[u][jj], sE[jj], acc);
        acc += __shfl_xor(acc, 1);
        if (l == 0) gstore(&exEE[(((long)par*B_ + b)*NBLK_ + blk)*W_ + u], acc);
      }
    }
    gbar(flags, blk, gbase + t*2 + 2);

    // ---- phase 3: reduce r/ee, dz1 (h slice) ----
    if (tid < t) {
      float s = 0.f;
      #pragma unroll
      for (int k2 = 0; k2 < NBLK_; k2++)
        s += gload(&exEE[(((long)par*B_ + b)*NBLK_ + k2)*W_ + tid]);
      sEEc[tid] = -2.f*THETA_*sAt[t-1-tid]*s;
    }
    if (tid >= 128 && tid < 136) {
      int hh = tid - 128;
      float s = 0.f;
      #pragma unroll
      for (int k2 = 0; k2 < NBLK_; k2++)
        s += gload(&exR[(((long)par*B_ + b)*NBLK_ + k2)*W_ + h0 + hh]);
      sR[hh] = s;
    }
    __syncthreads();
    {
      int hh = tid >> 5, lane = tid & 31;
      float acc = 0.f;
      for (int u = lane; u < t; u += 32) acc = fmaf(sEEc[u], sA1h[u][hh], acc);
      for (int o = 16; o; o >>= 1) acc += __shfl_xor(acc, o);
      if (lane == 0) {
        float z = sZ1[hh];
        float sg = sigf(z);
        float dz = 2.f*(sR[hh] + acc) * sg*(1.f + z*(1.f - sg));
        sDZ[t][hh] = dz;
      }
    }
    __syncthreads();
  }

  // ---- bulk history writeback from LDS (off the per-token critical path) ----
  for (int i = tid; i < 128*8; i += 256) {
    int t2 = i >> 3, hh = i & 7;
    dz1o[((long)b*SEG_ + t2)*W_ + h0 + hh] = sDZ[t2][hh];
    a1o [((long)b*SEG_ + t2)*W_ + h0 + hh] = sA1h[t2][hh];
  }
  for (int i = tid; i < 128*64; i += 256) {
    int t2 = i >> 6, jj = i & 63;
    eo[((long)b*SEG_ + t2)*D_ + j0 + jj] = sEh[t2][jj];
  }
  // final bias state (t=128) writeback
  if (tid < 8) {
    float mm = ETA_*sMB1[tid] - THETA_*sDZ[127][tid];
    mb1[b*W_ + h0 + tid] = mm;
    pb1[b*W_ + h0 + tid] = PDEC_*sB1[tid] + mm;
  } else if (tid >= 64 && tid < 128) {
    int jj = tid - 64;
    float mm = ETA_*sMB2[jj] - 2.f*THETA_*sEh[127][jj];
    mb2[b*D_ + j0 + jj] = mm;
    pb2[b*D_ + j0 + jj] = PDEC_*sB2[jj] + mm;
  }
}

// ---------------- weight/momentum reconstruction --------------------------
__global__ __launch_bounds__(256) void k_recon(
  float* __restrict__ pW1, float* __restrict__ mW1,
  float* __restrict__ pW2T, float* __restrict__ mW2T,
  const float* __restrict__ KMp, const float* __restrict__ Eh,
  const float* __restrict__ DZ1, const float* __restrict__ A1h,
  const float* __restrict__ coef)
{
  __shared__ float s1[16][33];
  __shared__ float s2[16][65];
  __shared__ float sCA[128], sCE[128];
  int dt = blockIdx.x, ht = blockIdx.y, kb = blockIdx.z;
  int kind = kb >> 1, b = kb & 1;
  int tid = threadIdx.x;
  int d0 = dt*32, hb = ht*64;
  const float* in1 = (kind ? Eh : KMp) + (long)b*SEG_*D_;
  const float* in2 = (kind ? A1h : DZ1) + (long)b*SEG_*W_;
  float* Pb = (kind ? pW2T : pW1) + (long)b*131072;
  float* Mb = (kind ? mW2T : mW1) + (long)b*131072;
  float f = kind ? -2.f*THETA_ : -THETA_;
  if (tid < 128) {
    sCA[tid] = f*coef[127 - tid];
    sCE[tid] = f*coef[128 + 127 - tid];
  }
  __syncthreads();
  int dd = tid >> 3, le = tid & 7;
  float accP[8] = {}, accM[8] = {};
  for (int u0 = 0; u0 < 128; u0 += 16) {
    for (int i = tid; i < 16*32; i += 256) {
      int uu = i >> 5, d2 = i & 31;
      s1[uu][d2] = in1[(long)(u0+uu)*D_ + d0 + d2];
    }
    for (int i = tid; i < 16*64; i += 256) {
      int uu = i >> 6, hl = i & 63;
      s2[uu][hl] = in2[(long)(u0+uu)*W_ + hb + hl];
    }
    __syncthreads();
    #pragma unroll
    for (int uu = 0; uu < 16; uu++) {
      float a = s1[uu][dd];
      float cAu = sCA[u0+uu], cEu = sCE[u0+uu];
      #pragma unroll
      for (int k = 0; k < 8; k++) {
        float v = a * s2[uu][k*8 + le];
        accP[k] = fmaf(cAu, v, accP[k]);
        accM[k] = fmaf(cEu, v, accM[k]);
      }
    }
    __syncthreads();
  }
  float b128 = coef[256 + 128];
  float eA   = ETA_*coef[127];
  float e128 = ETA_*coef[128 + 127];
  #pragma unroll
  for (int k = 0; k < 8; k++) {
    long idx = (long)(d0+dd)*W_ + hb + k*8 + le;
    float Po = Pb[idx], Mo = Mb[idx];
    Pb[idx] = b128*Po + eA*Mo + accP[k];
    Mb[idx] = e128*Mo + accM[k];
  }
}

__global__ void k_mul(const float* __restrict__ so, const float* __restrict__ mo,
                      float* __restrict__ outs, int s)
{
  int l = blockIdx.x, b = blockIdx.y, tid = threadIdx.x;
  long src = ((long)b*SEG_ + l)*D_ + tid*4;
  float4 a = *(const float4*)(so + src);
  float4 c = *(const float4*)(mo + src);
  a.x*=c.x; a.y*=c.y; a.z*=c.z; a.w*=c.w;
  *(float4*)(outs + ((long)b*N_ + s*SEG_ + l)*D_ + tid*4) = a;
}

// ---------------- host launcher ----------------
static inline void gemm(const float* A, const float* Bm, const float* bias, float* C,
                        int M, int N, int K, long sA, long sB, long sC, long sBias,
                        int batch, int bt, int silu_, hipStream_t st)
{
  dim3 g(N/64, (M+63)/64, batch), blk(256);
  if (!bt && !silu_) k_gemm<0,0><<<g,blk,0,st>>>(A,Bm,bias,C,M,N,K,sA,sB,sC,sBias);
  else if (!bt && silu_) k_gemm<0,1><<<g,blk,0,st>>>(A,Bm,bias,C,M,N,K,sA,sB,sC,sBias);
  else k_gemm<1,0><<<g,blk,0,st>>>(A,Bm,bias,C,M,N,K,sA,sB,sC,sBias);
}

extern "C" void kernel_launch(void* const* d_in, const int* in_sizes, int n_in,
                              void* d_out, int out_size, void* d_ws, size_t ws_size,
                              hipStream_t stream)
{
  (void)in_sizes; (void)n_in; (void)out_size; (void)ws_size;
  const int*   x     = (const int*)  d_in[0];
  const float* emb   = (const float*)d_in[1];
  const float* pers  = (const float*)d_in[2];
  const float* Wq    = (const float*)d_in[3];
  const float* bq    = (const float*)d_in[4];
  const float* Wk    = (const float*)d_in[5];
  const float* bk    = (const float*)d_in[6];
  const float* Wv    = (const float*)d_in[7];
  const float* bv    = (const float*)d_in[8];
  const float* aiw   = (const float*)d_in[9];
  const float* aib   = (const float*)d_in[10];
  const float* aow   = (const float*)d_in[11];
  const float* aob   = (const float*)d_in[12];
  const float* mW1in = (const float*)d_in[13];
  const float* mb1in = (const float*)d_in[14];
  const float* mW2in = (const float*)d_in[15];
  const float* mb2in = (const float*)d_in[16];
  const float* headw = (const float*)d_in[17];
  const float* headb = (const float*)d_in[18];
  float* out = (float*)d_out;
  float* ws  = (float*)d_ws;

  hipMemsetAsync(ws + MOM, 0, MOMSZ*sizeof(float), stream);
  hipMemsetAsync(ws + ZEROB, 0, 128*sizeof(float), stream);
  hipMemsetAsync(ws + CBAR, 0, 1024*sizeof(int), stream);
  k_embed<<<dim3(B_*N_), dim3(256), 0, stream>>>(x, emb, ws+XEMB);
  k_init<<<dim3((2*PER_+255)/256), dim3(256), 0, stream>>>(
      mW1in, mb1in, mW2in, mb2in, ws+PW1, ws+PB1, ws+PW2T, ws+PB2);
  k_coef<<<dim3(1), dim3(64), 0, stream>>>(ws+COEF);

  for (int s = 0; s < NSEG_; s++) {
    const float* segA = ws + XEMB + (size_t)s*SEG_*D_;
    // h = mlp(p, l2n(seg @ Wq + bq))
    gemm(segA, Wq, bq, ws+Q1, SEG_, D_, D_, (long)N_*D_, 0, (long)SEG_*D_, 0, B_, 0, 0, stream);
    k_l2n<<<dim3(B_*SEG_), dim3(256), 0, stream>>>(ws+Q1);
    gemm(ws+Q1, ws+PW1, ws+PB1, ws+AH, SEG_, W_, D_, (long)SEG_*D_, (long)D_*W_, (long)SEG_*W_, W_, B_, 0, 1, stream);
    gemm(ws+AH, ws+PW2T, ws+PB2, ws+HBUF, SEG_, D_, W_, (long)SEG_*W_, (long)D_*W_, (long)SEG_*D_, D_, B_, 1, 0, stream);
    // attention
    k_concat<<<dim3(T_, B_), dim3(256), 0, stream>>>(pers, ws+HBUF, ws+XEMB, s, ws+COMB);
    k_gemm128<<<dim3(3*D_/128, (B_*T_+127)/128), dim3(256), 0, stream>>>(
        ws+COMB, aiw, aib, ws+QKV, B_*T_, 3*D_, D_);
    k_attn<<<dim3(8, NH_, B_), dim3(256), 0, stream>>>(ws+QKV, ws+ATTN);
    gemm(ws+ATTN, aow, aob, ws+SEGO, B_*SEG_, D_, D_, 0, 0, 0, 0, 1, 0, 0, stream);
    // fused K/V/Q projections of seg_out (Q reused after the scan for mem_out)
    k_gemmkvq<<<dim3(24, 2), dim3(256), 0, stream>>>(
        ws+SEGO, Wk, bk, Wv, bv, Wq, bq, ws+KM, ws+VM, ws+Q1);
    k_l2n<<<dim3(B_*SEG_), dim3(256), 0, stream>>>(ws+KM);
    k_l2n<<<dim3(B_*SEG_), dim3(256), 0, stream>>>(ws+Q1);
    // token-space scan precompute: Q1K = K@W1, Q1Km = K@mW1, G = K@K^T
    gemm(ws+KM, ws+PW1, ws+ZEROB, ws+AQ1K,  SEG_, W_, D_, (long)SEG_*D_, (long)D_*W_, (long)SEG_*W_, 0, B_, 0, 0, stream);
    gemm(ws+KM, ws+MW1, ws+ZEROB, ws+AQ1KM, SEG_, W_, D_, (long)SEG_*D_, (long)D_*W_, (long)SEG_*W_, 0, B_, 0, 0, stream);
    gemm(ws+KM, ws+KM,  ws+ZEROB, ws+AGRAM, SEG_, SEG_, D_, (long)SEG_*D_, (long)SEG_*D_, (long)SEG_*SEG_, 0, B_, 1, 0, stream);
    // the scan itself (one launch)
    k_scan<<<dim3(NBLK_, B_), dim3(256), 0, stream>>>(
        ws+PW2T, ws+MW2T, ws+PB1, ws+MB1, ws+PB2, ws+MB2, ws+VM,
        ws+AQ1K, ws+AQ1KM, ws+AGRAM,
        ws+ADZ1, ws+AA1H, ws+AEH,
        ws+AEXA1, ws+AEXSP, ws+AEXR, ws+AEXEE,
        ws+COEF, (int*)(ws+CBAR), s);
    // reconstruct W1/mW1/W2T/mW2T
    k_recon<<<dim3(32, 2, 4), dim3(256), 0, stream>>>(
        ws+PW1, ws+MW1, ws+PW2T, ws+MW2T,
        ws+KM, ws+AEH, ws+ADZ1, ws+AA1H, ws+COEF);
    // mem_out = mlp(p_new, l2n(seg_out @ Wq + bq));  (Q1 already projected+l2n'd)
    gemm(ws+Q1, ws+PW1, ws+PB1, ws+AH, SEG_, W_, D_, (long)SEG_*D_, (long)D_*W_, (long)SEG_*W_, W_, B_, 0, 1, stream);
    gemm(ws+AH, ws+PW2T, ws+PB2, ws+MEMO, SEG_, D_, W_, (long)SEG_*W_, (long)D_*W_, (long)SEG_*D_, D_, B_, 1, 0, stream);
    k_mul<<<dim3(SEG_, B_), dim3(256), 0, stream>>>(ws+SEGO, ws+MEMO, ws+OUTS, s);
  }
  // head: out = full @ head_w + head_b (128x128-tile GEMM)
  k_gemm128<<<dim3(V_/128, (B_*N_)/128), dim3(256), 0, stream>>>(
      ws+OUTS, headw, headb, out, B_*N_, V_, D_);
}

// Round 8
// 8680.712 us; speedup vs baseline: 1.4979x; 1.0592x over previous
//
#include <hip/hip_runtime.h>
#include <math.h>

#define D_    1024
#define B_    2
#define N_    512
#define SEG_  128
#define NSEG_ 4
#define NPT_  16
#define T_    272
#define NH_   16
#define HD_   64
#define W_    128
#define V_    32000

#define THETA_ 0.1f
#define ETA_   0.9f
#define PDEC_  0.99f
#define EPSN_  1e-6f
#define NBLK_ 16
#define FSTR_ 32   // flag stride in ints (128B)

typedef __bf16 bf16x8 __attribute__((ext_vector_type(8)));
typedef float  f32x4  __attribute__((ext_vector_type(4)));

// ---------------- workspace layout (float offsets) ----------------
static const size_t XEMB = 0;                       // [B,N,D]
static const size_t OUTS = XEMB + (size_t)B_*N_*D_; // [B,N,D]
static const size_t PW1  = OUTS + (size_t)B_*N_*D_; // [B,1024,128]
static const size_t PB1  = PW1  + (size_t)B_*D_*W_; // [B,128]
static const size_t PW2T = PB1  + (size_t)B_*W_;    // [B,1024,128]  (W2 transposed)
static const size_t PB2  = PW2T + (size_t)B_*D_*W_; // [B,1024]
static const size_t MOM  = PB2  + (size_t)B_*D_;
static const size_t MW1  = MOM;
static const size_t MB1  = MW1  + (size_t)B_*D_*W_;
static const size_t MW2T = MB1  + (size_t)B_*W_;
static const size_t MB2  = MW2T + (size_t)B_*D_*W_;
static const size_t MOMSZ = (size_t)B_*(D_*W_ + W_ + D_*W_ + D_);
static const size_t Q1   = MOM  + MOMSZ;              // [B,128,1024]
static const size_t AH   = Q1   + (size_t)B_*SEG_*D_; // [B,128,128]
static const size_t HBUF = AH   + (size_t)B_*SEG_*W_; // [B,128,1024]
static const size_t COMB = HBUF + (size_t)B_*SEG_*D_; // [B,272,1024]
static const size_t QKV  = COMB + (size_t)B_*T_*D_;   // [B,272,3072]
static const size_t ATTN = QKV  + (size_t)B_*T_*3*D_; // [B,128,1024]
static const size_t SEGO = ATTN + (size_t)B_*SEG_*D_; // [B,128,1024]
static const size_t KM   = SEGO + (size_t)B_*SEG_*D_; // [B,128,1024]
static const size_t VM   = KM   + (size_t)B_*SEG_*D_; // [B,128,1024]
static const size_t MEMO = VM   + (size_t)B_*SEG_*D_; // [B,128,1024]
static const size_t WSEND = MEMO + (size_t)B_*SEG_*D_;

// scan-phase buffers ALIAS the QKV region
static const size_t AQ1K  = QKV;
static const size_t AQ1KM = AQ1K  + 32768;
static const size_t AGRAM = AQ1KM + 32768;
static const size_t ADZ1  = AGRAM + 32768;
static const size_t AA1H  = ADZ1  + 32768;
static const size_t AEH   = AA1H  + 32768;
static const size_t AEXA1 = AEH + (size_t)B_*SEG_*D_;
static const size_t AEXSP = AEXA1 + 512;
static const size_t AEXR  = AEXSP + 8192;
static const size_t AEXEE = AEXR  + 8192;
// persistent tail
static const size_t COEF  = WSEND;
static const size_t ZEROB = COEF + 512;
static const size_t CBAR  = ZEROB + 128;

__device__ __forceinline__ float sigf(float x) { return 1.f/(1.f+expf(-x)); }

__device__ __forceinline__ void gstore(float* p, float v) {
  __hip_atomic_store(p, v, __ATOMIC_RELAXED, __HIP_MEMORY_SCOPE_AGENT);
}
__device__ __forceinline__ float gload(const float* p) {
  return __hip_atomic_load(p, __ATOMIC_RELAXED, __HIP_MEMORY_SCOPE_AGENT);
}

// RNE bf16 split: a ≈ float(h) + float(l), residual ≤ 2^-18 |a|
__device__ __forceinline__ void bsplit(float a, short& h, short& l) {
  unsigned u = __builtin_bit_cast(unsigned, a);
  unsigned hb = (u + 0x7fffu + ((u >> 16) & 1u)) >> 16;
  h = (short)hb;
  float hf = __builtin_bit_cast(float, hb << 16);
  float r = a - hf;
  unsigned ur = __builtin_bit_cast(unsigned, r);
  unsigned lb = (ur + 0x7fffu + ((ur >> 16) & 1u)) >> 16;
  l = (short)lb;
}

// ---------------- generic tiled fp32 GEMM (64x64) ----------------
template<int BT, int SILU>
__global__ __launch_bounds__(256) void k_gemm(
    const float* __restrict__ A, const float* __restrict__ Bm,
    const float* __restrict__ bias, float* __restrict__ C,
    int M, int N, int K, long sA, long sB, long sC, long sBias)
{
  __shared__ float As[16][68];
  __shared__ float Bs[16][68];
  int bz = blockIdx.z;
  A += bz*sA; Bm += bz*sB; C += bz*sC; bias += bz*sBias;
  int n0 = blockIdx.x*64, m0 = blockIdx.y*64;
  int tid = threadIdx.x;
  int tx = tid & 15, ty = tid >> 4;
  int r  = tid >> 2;
  int kq = (tid & 3) * 4;
  float acc[4][4] = {};
  for (int k0 = 0; k0 < K; k0 += 16) {
    {
      int row = m0 + r;
      float4 v = make_float4(0.f,0.f,0.f,0.f);
      if (row < M) v = *(const float4*)(A + (long)row*K + k0 + kq);
      As[kq+0][r]=v.x; As[kq+1][r]=v.y; As[kq+2][r]=v.z; As[kq+3][r]=v.w;
    }
    if (BT) {
      int row = n0 + r;
      float4 v = *(const float4*)(Bm + (long)row*K + k0 + kq);
      Bs[kq+0][r]=v.x; Bs[kq+1][r]=v.y; Bs[kq+2][r]=v.z; Bs[kq+3][r]=v.w;
    } else {
      int c = tid & 63, r4 = tid >> 6;
      #pragma unroll
      for (int p = 0; p < 4; p++) {
        int kk = r4 + p*4;
        Bs[kk][c] = Bm[(long)(k0+kk)*N + n0 + c];
      }
    }
    __syncthreads();
    #pragma unroll
    for (int kk = 0; kk < 16; kk++) {
      float av[4], bv[4];
      #pragma unroll
      for (int i=0;i<4;i++) av[i] = As[kk][ty*4+i];
      #pragma unroll
      for (int j=0;j<4;j++) bv[j] = Bs[kk][tx*4+j];
      #pragma unroll
      for (int i=0;i<4;i++)
        #pragma unroll
        for (int j=0;j<4;j++)
          acc[i][j] = fmaf(av[i], bv[j], acc[i][j]);
    }
    __syncthreads();
  }
  #pragma unroll
  for (int i=0;i<4;i++) {
    int row = m0 + ty*4 + i;
    if (row >= M) continue;
    #pragma unroll
    for (int j=0;j<4;j++) {
      int col = n0 + tx*4 + j;
      float v = acc[i][j] + bias[col];
      if (SILU) v = v * sigf(v);
      C[(long)row*N + col] = v;
    }
  }
}

// ------- dual-output 64x64 GEMM: C1=A@B1, C2=A@B2 (no bias). M=128,N=128 ----
__global__ __launch_bounds__(256) void k_gemm2(
    const float* __restrict__ A, const float* __restrict__ B1,
    const float* __restrict__ B2, float* __restrict__ C1, float* __restrict__ C2,
    int K, long sA, long sB, long sC)
{
  __shared__ float As[16][68];
  __shared__ float B1s[16][68];
  __shared__ float B2s[16][68];
  int bz = blockIdx.z;
  A += bz*sA; B1 += bz*sB; B2 += bz*sB; C1 += bz*sC; C2 += bz*sC;
  int n0 = blockIdx.x*64, m0 = blockIdx.y*64;
  int tid = threadIdx.x;
  int tx = tid & 15, ty = tid >> 4;
  int r  = tid >> 2;
  int kq = (tid & 3) * 4;
  float acc1[4][4] = {}, acc2[4][4] = {};
  for (int k0 = 0; k0 < K; k0 += 16) {
    {
      float4 v = *(const float4*)(A + (long)(m0+r)*K + k0 + kq);
      As[kq+0][r]=v.x; As[kq+1][r]=v.y; As[kq+2][r]=v.z; As[kq+3][r]=v.w;
    }
    {
      int c = tid & 63, r4 = tid >> 6;
      #pragma unroll
      for (int p = 0; p < 4; p++) {
        int kk = r4 + p*4;
        B1s[kk][c] = B1[(long)(k0+kk)*W_ + n0 + c];
        B2s[kk][c] = B2[(long)(k0+kk)*W_ + n0 + c];
      }
    }
    __syncthreads();
    #pragma unroll
    for (int kk = 0; kk < 16; kk++) {
      float av[4], b1v[4], b2v[4];
      #pragma unroll
      for (int i=0;i<4;i++) av[i] = As[kk][ty*4+i];
      #pragma unroll
      for (int j=0;j<4;j++) { b1v[j] = B1s[kk][tx*4+j]; b2v[j] = B2s[kk][tx*4+j]; }
      #pragma unroll
      for (int i=0;i<4;i++)
        #pragma unroll
        for (int j=0;j<4;j++) {
          acc1[i][j] = fmaf(av[i], b1v[j], acc1[i][j]);
          acc2[i][j] = fmaf(av[i], b2v[j], acc2[i][j]);
        }
    }
    __syncthreads();
  }
  #pragma unroll
  for (int i=0;i<4;i++) {
    int row = m0 + ty*4 + i;
    #pragma unroll
    for (int j=0;j<4;j++) {
      int col = n0 + tx*4 + j;
      C1[(long)row*W_ + col] = acc1[i][j];
      C2[(long)row*W_ + col] = acc2[i][j];
    }
  }
}

// ------- 128x128 tile fp32 GEMM (M-guarded) -------
__global__ __launch_bounds__(256) void k_gemm128(
    const float* __restrict__ A, const float* __restrict__ Bm,
    const float* __restrict__ bias, float* __restrict__ C,
    int M, int N, int K)
{
  __shared__ float As[16][132];
  __shared__ float Bs[16][132];
  int n0 = blockIdx.x*128, m0 = blockIdx.y*128;
  int tid = threadIdx.x;
  int tx = tid & 15, ty = tid >> 4;
  int ar = tid >> 1, ak = (tid & 1) * 8;
  int bk = tid >> 4, bn = (tid & 15) * 8;
  int arow = min(m0 + ar, M-1);
  float acc[8][8] = {};
  for (int k0 = 0; k0 < K; k0 += 16) {
    {
      const float* ap = A + (long)arow*K + k0 + ak;
      float4 v0 = *(const float4*)(ap);
      float4 v1 = *(const float4*)(ap+4);
      As[ak+0][ar]=v0.x; As[ak+1][ar]=v0.y; As[ak+2][ar]=v0.z; As[ak+3][ar]=v0.w;
      As[ak+4][ar]=v1.x; As[ak+5][ar]=v1.y; As[ak+6][ar]=v1.z; As[ak+7][ar]=v1.w;
      const float* bp = Bm + (long)(k0+bk)*N + n0 + bn;
      *(float4*)(&Bs[bk][bn])   = *(const float4*)(bp);
      *(float4*)(&Bs[bk][bn+4]) = *(const float4*)(bp+4);
    }
    __syncthreads();
    #pragma unroll
    for (int kk = 0; kk < 16; kk++) {
      float av[8], bv[8];
      #pragma unroll
      for (int i=0;i<8;i++) av[i] = As[kk][ty*8+i];
      #pragma unroll
      for (int j=0;j<8;j++) bv[j] = Bs[kk][tx*8+j];
      #pragma unroll
      for (int i=0;i<8;i++)
        #pragma unroll
        for (int j=0;j<8;j++)
          acc[i][j] = fmaf(av[i], bv[j], acc[i][j]);
    }
    __syncthreads();
  }
  #pragma unroll
  for (int i=0;i<8;i++) {
    int row = m0 + ty*8 + i;
    if (row >= M) continue;
    #pragma unroll
    for (int j=0;j<8;j++) acc[i][j] += bias[n0 + tx*8 + j];
    *(float4*)(C + (long)row*N + n0 + tx*8)     = make_float4(acc[i][0],acc[i][1],acc[i][2],acc[i][3]);
    *(float4*)(C + (long)row*N + n0 + tx*8 + 4) = make_float4(acc[i][4],acc[i][5],acc[i][6],acc[i][7]);
  }
}

// ------- head GEMM via bf16-split MFMA: C = A@B + bias (fp32 in/out) -------
// M=1024, N=32000, K=1024. C ≈ Ah·Bh + Ah·Bl + Al·Bh (fp32 accum).
__global__ __launch_bounds__(256) void k_head_mfma(
    const float* __restrict__ A, const float* __restrict__ Bm,
    const float* __restrict__ bias, float* __restrict__ C,
    int M, int N, int K)
{
  __shared__ short Ah[128][48];   // [m][k], 32 k + pad (96B rows)
  __shared__ short Al[128][48];
  __shared__ short Bh[32][132];   // [k][n], 128 n + pad (264B rows)
  __shared__ short Bl[32][132];
  int n0 = blockIdx.x*128, m0 = blockIdx.y*128;
  int tid = threadIdx.x;
  int wave = tid >> 6, lane = tid & 63;
  int wm = (wave >> 1) * 64, wn = (wave & 1) * 64;
  int lrow = lane & 15, lk = (lane >> 4) * 8;
  f32x4 acc[4][4] = {};
  for (int k0 = 0; k0 < K; k0 += 32) {
    __syncthreads();
    { // stage A: row = tid>>1, 16 k-values
      int r = tid >> 1, kq = (tid & 1) * 16;
      const float* ap = A + (long)(m0 + r)*K + k0 + kq;
      #pragma unroll
      for (int q = 0; q < 16; q += 4) {
        float4 v = *(const float4*)(ap + q);
        short h0,l0,h1,l1,h2,l2,h3,l3;
        bsplit(v.x,h0,l0); bsplit(v.y,h1,l1); bsplit(v.z,h2,l2); bsplit(v.w,h3,l3);
        short4 hh = make_short4(h0,h1,h2,h3), ll = make_short4(l0,l1,l2,l3);
        *(short4*)&Ah[r][kq+q] = hh;
        *(short4*)&Al[r][kq+q] = ll;
      }
    }
    { // stage B: k-row = tid>>3, 16 n-values
      int kr = tid >> 3, nq = (tid & 7) * 16;
      const float* bp = Bm + (long)(k0 + kr)*N + n0 + nq;
      #pragma unroll
      for (int q = 0; q < 16; q += 4) {
        float4 v = *(const float4*)(bp + q);
        short h0,l0,h1,l1,h2,l2,h3,l3;
        bsplit(v.x,h0,l0); bsplit(v.y,h1,l1); bsplit(v.z,h2,l2); bsplit(v.w,h3,l3);
        *(short4*)&Bh[kr][nq+q] = make_short4(h0,h1,h2,h3);
        *(short4*)&Bl[kr][nq+q] = make_short4(l0,l1,l2,l3);
      }
    }
    __syncthreads();
    // b-fragments: lane holds B[k=lk+j][col=wn+nf*16+lrow]
    bf16x8 bh[4], bl[4];
    #pragma unroll
    for (int nf = 0; nf < 4; nf++) {
      int col = wn + nf*16 + lrow;
      #pragma unroll
      for (int j = 0; j < 8; j++) {
        bh[nf][j] = __builtin_bit_cast(__bf16, Bh[lk+j][col]);
        bl[nf][j] = __builtin_bit_cast(__bf16, Bl[lk+j][col]);
      }
    }
    #pragma unroll
    for (int mf = 0; mf < 4; mf++) {
      int arow2 = wm + mf*16 + lrow;
      bf16x8 ah = *(const bf16x8*)&Ah[arow2][lk];
      bf16x8 al = *(const bf16x8*)&Al[arow2][lk];
      #pragma unroll
      for (int nf = 0; nf < 4; nf++) {
        acc[mf][nf] = __builtin_amdgcn_mfma_f32_16x16x32_bf16(ah, bh[nf], acc[mf][nf], 0, 0, 0);
        acc[mf][nf] = __builtin_amdgcn_mfma_f32_16x16x32_bf16(ah, bl[nf], acc[mf][nf], 0, 0, 0);
        acc[mf][nf] = __builtin_amdgcn_mfma_f32_16x16x32_bf16(al, bh[nf], acc[mf][nf], 0, 0, 0);
      }
    }
  }
  // epilogue: D[row=(lane>>4)*4+j][col=lane&15] per 16x16 fragment
  #pragma unroll
  for (int mf = 0; mf < 4; mf++) {
    #pragma unroll
    for (int nf = 0; nf < 4; nf++) {
      int col = n0 + wn + nf*16 + lrow;
      float bv = bias[col];
      #pragma unroll
      for (int j = 0; j < 4; j++) {
        int row = m0 + wm + mf*16 + (lane >> 4)*4 + j;
        C[(long)row*N + col] = acc[mf][nf][j] + bv;
      }
    }
  }
}

// ---------------- small kernels ----------------
__global__ void k_embed(const int* __restrict__ x, const float* __restrict__ emb,
                        float* __restrict__ xe)
{
  int row = blockIdx.x, tid = threadIdx.x;
  int idx = x[row];
  float4 v = *(const float4*)(emb + (long)idx*D_ + tid*4);
  *(float4*)(xe + (long)row*D_ + tid*4) = v;
}

#define PER_ 263296L
__global__ void k_init(const float* __restrict__ mW1in, const float* __restrict__ mb1in,
                       const float* __restrict__ mW2in, const float* __restrict__ mb2in,
                       float* __restrict__ pW1, float* __restrict__ pb1,
                       float* __restrict__ pW2T, float* __restrict__ pb2)
{
  long g = (long)blockIdx.x*256 + threadIdx.x;
  if (g >= 2*PER_) return;
  int b = (int)(g / PER_);
  long rr = g % PER_;
  if (rr < 131072)       pW1[(long)b*131072 + rr] = mW1in[rr];
  else if (rr < 131200)  pb1[b*W_ + (rr-131072)] = mb1in[rr-131072];
  else if (rr < 262272) { long l = rr-131200; int j=(int)(l>>7), h=(int)(l&127);
                          pW2T[(long)b*131072 + l] = mW2in[(long)h*D_ + j]; }
  else                   pb2[b*D_ + (rr-262272)] = mb2in[rr-262272];
}

__global__ void k_coef(float* __restrict__ c)
{
  if (blockIdx.x == 0 && threadIdx.x == 0) {
    c[0] = 1.f; c[128] = 1.f;
    float A = 1.f, eta_d = 1.f;
    for (int d = 1; d < 128; d++) {
      eta_d *= ETA_;
      A = PDEC_*A + eta_d;
      c[d] = A;
      c[128 + d] = eta_d;
    }
    c[256] = 1.f;
    float bp = 1.f;
    for (int t = 1; t <= 128; t++) { bp *= PDEC_; c[256 + t] = bp; }
  }
}

__global__ __launch_bounds__(256) void k_l2n(float* __restrict__ X)
{
  long row = blockIdx.x;
  float* p = X + row*D_;
  int tid = threadIdx.x;
  float4 v = *(float4*)(p + tid*4);
  float ss = v.x*v.x + v.y*v.y + v.z*v.z + v.w*v.w;
  for (int o=32;o;o>>=1) ss += __shfl_xor(ss,o);
  __shared__ float wsum[4];
  if ((tid&63)==0) wsum[tid>>6] = ss;
  __syncthreads();
  float tot = wsum[0]+wsum[1]+wsum[2]+wsum[3];
  float sc = 1.f/(sqrtf(tot)+EPSN_);
  v.x*=sc; v.y*=sc; v.z*=sc; v.w*=sc;
  *(float4*)(p + tid*4) = v;
}

__global__ void k_concat(const float* __restrict__ pers, const float* __restrict__ h,
                         const float* __restrict__ xemb, int s, float* __restrict__ comb)
{
  int row = blockIdx.x, b = blockIdx.y, tid = threadIdx.x;
  const float* src;
  if (row < NPT_)            src = pers + (long)row*D_;
  else if (row < NPT_+SEG_)  src = h    + ((long)b*SEG_ + (row-NPT_))*D_;
  else                       src = xemb + ((long)b*N_ + s*SEG_ + (row-NPT_-SEG_))*D_;
  float4 v = *(const float4*)(src + tid*4);
  *(float4*)(comb + ((long)b*T_ + row)*D_ + tid*4) = v;
}

__global__ __launch_bounds__(256) void k_attn(const float* __restrict__ qkv,
                                              float* __restrict__ outp)
{
  __shared__ float sQ[16][68];
  __shared__ float sKV[64][68];
  __shared__ float sS[16][273];
  int qt = blockIdx.x, head = blockIdx.y, b = blockIdx.z;
  int tid = threadIdx.x;
  const float* base = qkv + (long)b*T_*3*D_;
  int qoff = head*HD_, koff = D_ + head*HD_, voff = 2*D_ + head*HD_;
  int qrow0 = NPT_ + SEG_ + qt*16;
  {
    int rr = tid>>4, c4 = (tid&15)*4;
    float4 v = *(const float4*)(base + (long)(qrow0+rr)*3*D_ + qoff + c4);
    sQ[rr][c4]=v.x; sQ[rr][c4+1]=v.y; sQ[rr][c4+2]=v.z; sQ[rr][c4+3]=v.w;
  }
  __syncthreads();
  for (int j0 = 0; j0 < T_; j0 += 64) {
    int chunk = min(64, T_ - j0);
    {
      int jj = tid>>2, cq = (tid&3)*16;
      if (jj < chunk) {
        #pragma unroll
        for (int q4=0;q4<4;q4++) {
          float4 v = *(const float4*)(base + (long)(j0+jj)*3*D_ + koff + cq + q4*4);
          sKV[jj][cq+q4*4]=v.x; sKV[jj][cq+q4*4+1]=v.y; sKV[jj][cq+q4*4+2]=v.z; sKV[jj][cq+q4*4+3]=v.w;
        }
      }
    }
    __syncthreads();
    int rr = tid>>4, jj0 = tid&15;
    #pragma unroll
    for (int p=0;p<4;p++) {
      int jj = jj0 + p*16;
      if (jj < chunk) {
        float s = 0.f;
        #pragma unroll 8
        for (int c=0;c<HD_;c++) s = fmaf(sQ[rr][c], sKV[jj][c], s);
        s *= 0.125f;
        int jg = j0 + jj, qg = qrow0 + rr;
        if (jg > qg) s = -3.0e38f;
        sS[rr][jg] = s;
      }
    }
    __syncthreads();
  }
  {
    int rr = tid>>4, l16 = tid&15;
    float m = -3.4e38f;
    for (int j=l16; j<T_; j+=16) m = fmaxf(m, sS[rr][j]);
    for (int o=8;o;o>>=1) m = fmaxf(m, __shfl_xor(m,o));
    float sum = 0.f;
    for (int j=l16; j<T_; j+=16) { float e = expf(sS[rr][j]-m); sS[rr][j] = e; sum += e; }
    for (int o=8;o;o>>=1) sum += __shfl_xor(sum,o);
    float inv = 1.f/sum;
    for (int j=l16; j<T_; j+=16) sS[rr][j] *= inv;
  }
  __syncthreads();
  float acc[4] = {0.f,0.f,0.f,0.f};
  int rr = tid>>4, c4 = (tid&15)*4;
  for (int j0 = 0; j0 < T_; j0 += 64) {
    int chunk = min(64, T_ - j0);
    {
      int jj = tid>>2, cq = (tid&3)*16;
      if (jj < chunk) {
        #pragma unroll
        for (int q4=0;q4<4;q4++) {
          float4 v = *(const float4*)(base + (long)(j0+jj)*3*D_ + voff + cq + q4*4);
          sKV[jj][cq+q4*4]=v.x; sKV[jj][cq+q4*4+1]=v.y; sKV[jj][cq+q4*4+2]=v.z; sKV[jj][cq+q4*4+3]=v.w;
        }
      }
    }
    __syncthreads();
    for (int jj=0; jj<chunk; jj++) {
      float p = sS[rr][j0+jj];
      #pragma unroll
      for (int i=0;i<4;i++) acc[i] = fmaf(p, sKV[jj][c4+i], acc[i]);
    }
    __syncthreads();
  }
  float4 o4 = make_float4(acc[0],acc[1],acc[2],acc[3]);
  *(float4*)(outp + ((long)(b*SEG_) + qt*16 + rr)*D_ + head*HD_ + c4) = o4;
}

// ------- fence-free flag barrier ---------
__device__ __forceinline__ void gbar(int* flags, int blk, int gen)
{
  asm volatile("s_waitcnt vmcnt(0) lgkmcnt(0)" ::: "memory");
  __syncthreads();
  if (threadIdx.x == 0)
    __hip_atomic_store(flags + blk*FSTR_, gen, __ATOMIC_RELAXED, __HIP_MEMORY_SCOPE_AGENT);
  if (threadIdx.x < NBLK_) {
    while (__hip_atomic_load(flags + threadIdx.x*FSTR_, __ATOMIC_RELAXED,
                             __HIP_MEMORY_SCOPE_AGENT) < gen)
      __builtin_amdgcn_s_sleep(1);
  }
  __syncthreads();
}

// ---------------- persistent token-space scan ------
__global__ __launch_bounds__(256) void k_scan(
  const float* __restrict__ pW2T, const float* __restrict__ mW2T,
  float* __restrict__ pb1, float* __restrict__ mb1,
  float* __restrict__ pb2, float* __restrict__ mb2,
  const float* __restrict__ Vm,
  const float* __restrict__ q1k, const float* __restrict__ q1km,
  const float* __restrict__ G,
  float* __restrict__ dz1o, float* __restrict__ a1o, float* __restrict__ eo,
  float* __restrict__ exA1, float* __restrict__ exSP,
  float* __restrict__ exR, float* __restrict__ exEE,
  const float* __restrict__ coef, int* __restrict__ barbase, int seg)
{
  __shared__ float sW[64][132];
  __shared__ float sMW[64][132];
  __shared__ float sEh[128][66];
  __shared__ float sA1h[128][9];
  __shared__ float sDZ[128][9];
  __shared__ float sQ1K[128][8];
  __shared__ float sQ1KM[128][8];
  __shared__ float sAt[128];
  __shared__ float sBp[129];
  __shared__ float sB1[8], sMB1[8], sZ1[8], sR[8];
  __shared__ float sB2[64], sMB2[64], sE[64];
  __shared__ float sA1t[128];
  __shared__ float sS[128];
  __shared__ float sEEc[128];

  int b = blockIdx.y, blk = blockIdx.x, tid = threadIdx.x;
  int j0 = blk*64, h0 = blk*8;
  int* flags = barbase + b*(NBLK_*FSTR_);
  int gbase = seg*1000;

  for (int i = tid; i < 64*128; i += 256) {
    int jj = i >> 7, h = i & 127;
    sW[jj][h]  = pW2T[(long)b*131072 + (long)(j0+jj)*128 + h];
    sMW[jj][h] = mW2T[(long)b*131072 + (long)(j0+jj)*128 + h];
  }
  for (int i = tid; i < 128*8; i += 256) {
    int t2 = i >> 3, hh = i & 7;
    sQ1K[t2][hh]  = q1k [((long)b*SEG_ + t2)*W_ + h0 + hh];
    sQ1KM[t2][hh] = q1km[((long)b*SEG_ + t2)*W_ + h0 + hh];
  }
  if (tid < 128) sAt[tid] = coef[tid];
  for (int i = tid; i < 129; i += 256) sBp[i] = coef[256 + i];
  if (tid < 8)  { sB1[tid] = pb1[b*W_ + h0 + tid]; sMB1[tid] = mb1[b*W_ + h0 + tid]; }
  if (tid >= 64 && tid < 128) {
    int jj = tid - 64;
    sB2[jj] = pb2[b*D_ + j0 + jj]; sMB2[jj] = mb2[b*D_ + j0 + jj];
  }
  __syncthreads();

  for (int t = 0; t < SEG_; ++t) {
    int par = t & 1;
    float bp = sBp[t];
    float ca = (t > 0) ? ETA_*sAt[t-1] : 0.f;

    // ---- phase 1 ----
    if (t > 0 && tid < 8) {
      float mm = ETA_*sMB1[tid] - THETA_*sDZ[t-1][tid];
      sMB1[tid] = mm; sB1[tid] = PDEC_*sB1[tid] + mm;
    }
    __syncthreads();
    {
      int hh = tid >> 5, lane = tid & 31;
      float acc = 0.f;
      const float* Grow = G + ((long)b*SEG_ + t)*SEG_;
      for (int u = lane; u < t; u += 32)
        acc += sAt[t-1-u] * Grow[u] * sDZ[u][hh];
      for (int o = 16; o; o >>= 1) acc += __shfl_xor(acc, o);
      if (lane == 0) {
        int h = h0 + hh;
        float z1 = bp*sQ1K[t][hh] + ca*sQ1KM[t][hh] + sB1[hh] - THETA_*acc;
        sZ1[hh] = z1;
        float a1 = z1 * sigf(z1);
        sA1h[t][hh] = a1;
        gstore(&exA1[(long)par*(B_*W_) + b*W_ + h], a1);
      }
    }
    __syncthreads();
    if (tid < t) {
      float acc = 0.f;
      #pragma unroll
      for (int hh2 = 0; hh2 < 8; hh2++) acc += sA1h[tid][hh2]*sA1h[t][hh2];
      gstore(&exSP[(((long)par*B_ + b)*NBLK_ + blk)*W_ + tid], acc);
    }
    gbar(flags, blk, gbase + t*2 + 1);

    // ---- phase 2: issue MALL gathers into regs, overlap b2 update ----
    float rA1 = 0.f, rSP = 0.f;
    if (tid < 128) {
      rA1 = gload(&exA1[(long)par*(B_*W_) + b*W_ + tid]);
    } else {
      int u = tid - 128;
      if (u < t) {
        #pragma unroll
        for (int k2 = 0; k2 < NBLK_; k2++)
          rSP += gload(&exSP[(((long)par*B_ + b)*NBLK_ + k2)*W_ + u]);
      }
    }
    if (t > 0 && tid < 64) {
      float mm = ETA_*sMB2[tid] - 2.f*THETA_*sEh[t-1][tid];
      sMB2[tid] = mm; sB2[tid] = PDEC_*sB2[tid] + mm;
    }
    if (tid < 128) {
      sA1t[tid] = rA1;
    } else {
      int u = tid - 128;
      if (u < t) sS[u] = -2.f*THETA_*sAt[t-1-u]*rSP;
    }
    __syncthreads();
    {
      int jj = tid >> 2, l4 = tid & 3;
      float g0 = 0.f, gm = 0.f;
      for (int h = l4; h < 128; h += 4) {
        g0 = fmaf(sW[jj][h],  sA1t[h], g0);
        gm = fmaf(sMW[jj][h], sA1t[h], gm);
      }
      float corr = 0.f;
      for (int u = l4; u < t; u += 4) corr = fmaf(sS[u], sEh[u][jj], corr);
      float tot = bp*g0 + ca*gm + corr;
      tot += __shfl_xor(tot, 1); tot += __shfl_xor(tot, 2);
      if (l4 == 0) {
        float e = tot + sB2[jj] - Vm[((long)b*SEG_ + t)*D_ + j0 + jj];
        sEh[t][jj] = e; sE[jj] = e;
      }
    }
    __syncthreads();
    {
      int h = tid >> 1, l = tid & 1;
      float r0 = 0.f, rm = 0.f;
      for (int jj = l*32; jj < l*32+32; jj++) {
        r0 = fmaf(sW[jj][h],  sE[jj], r0);
        rm = fmaf(sMW[jj][h], sE[jj], rm);
      }
      float rc = bp*r0 + ca*rm;
      rc += __shfl_xor(rc, 1);
      if (l == 0) gstore(&exR[(((long)par*B_ + b)*NBLK_ + blk)*W_ + h], rc);
    }
    {
      int u = tid >> 1, l = tid & 1;
      if (u < t) {
        float acc = 0.f;
        for (int jj = l*32; jj < l*32+32; jj++) acc = fmaf(sEh[u][jj], sE[jj], acc);
        acc += __shfl_xor(acc, 1);
        if (l == 0) gstore(&exEE[(((long)par*B_ + b)*NBLK_ + blk)*W_ + u], acc);
      }
    }
    gbar(flags, blk, gbase + t*2 + 2);

    // ---- phase 3 ----
    if (tid < t) {
      float s = 0.f;
      #pragma unroll
      for (int k2 = 0; k2 < NBLK_; k2++)
        s += gload(&exEE[(((long)par*B_ + b)*NBLK_ + k2)*W_ + tid]);
      sEEc[tid] = -2.f*THETA_*sAt[t-1-tid]*s;
    }
    if (tid >= 128 && tid < 136) {
      int hh = tid - 128;
      float s = 0.f;
      #pragma unroll
      for (int k2 = 0; k2 < NBLK_; k2++)
        s += gload(&exR[(((long)par*B_ + b)*NBLK_ + k2)*W_ + h0 + hh]);
      sR[hh] = s;
    }
    __syncthreads();
    {
      int hh = tid >> 5, lane = tid & 31;
      float acc = 0.f;
      for (int u = lane; u < t; u += 32) acc = fmaf(sEEc[u], sA1h[u][hh], acc);
      for (int o = 16; o; o >>= 1) acc += __shfl_xor(acc, o);
      if (lane == 0) {
        float z = sZ1[hh];
        float sg = sigf(z);
        float dz = 2.f*(sR[hh] + acc) * sg*(1.f + z*(1.f - sg));
        sDZ[t][hh] = dz;
      }
    }
    __syncthreads();
  }

  // ---- bulk history writeback ----
  for (int i = tid; i < 128*8; i += 256) {
    int t2 = i >> 3, hh = i & 7;
    dz1o[((long)b*SEG_ + t2)*W_ + h0 + hh] = sDZ[t2][hh];
    a1o [((long)b*SEG_ + t2)*W_ + h0 + hh] = sA1h[t2][hh];
  }
  for (int i = tid; i < 128*64; i += 256) {
    int t2 = i >> 6, jj = i & 63;
    eo[((long)b*SEG_ + t2)*D_ + j0 + jj] = sEh[t2][jj];
  }
  if (tid < 8) {
    float mm = ETA_*sMB1[tid] - THETA_*sDZ[127][tid];
    mb1[b*W_ + h0 + tid] = mm;
    pb1[b*W_ + h0 + tid] = PDEC_*sB1[tid] + mm;
  } else if (tid >= 64 && tid < 128) {
    int jj = tid - 64;
    float mm = ETA_*sMB2[jj] - 2.f*THETA_*sEh[127][jj];
    mb2[b*D_ + j0 + jj] = mm;
    pb2[b*D_ + j0 + jj] = PDEC_*sB2[jj] + mm;
  }
}

// ---------------- weight/momentum reconstruction --------------------------
__global__ __launch_bounds__(256) void k_recon(
  float* __restrict__ pW1, float* __restrict__ mW1,
  float* __restrict__ pW2T, float* __restrict__ mW2T,
  const float* __restrict__ KMp, const float* __restrict__ Eh,
  const float* __restrict__ DZ1, const float* __restrict__ A1h,
  const float* __restrict__ coef)
{
  __shared__ float s1[16][33];
  __shared__ float s2[16][65];
  __shared__ float sCA[128], sCE[128];
  int dt = blockIdx.x, ht = blockIdx.y, kb = blockIdx.z;
  int kind = kb >> 1, b = kb & 1;
  int tid = threadIdx.x;
  int d0 = dt*32, hb = ht*64;
  const float* in1 = (kind ? Eh : KMp) + (long)b*SEG_*D_;
  const float* in2 = (kind ? A1h : DZ1) + (long)b*SEG_*W_;
  float* Pb = (kind ? pW2T : pW1) + (long)b*131072;
  float* Mb = (kind ? mW2T : mW1) + (long)b*131072;
  float f = kind ? -2.f*THETA_ : -THETA_;
  if (tid < 128) {
    sCA[tid] = f*coef[127 - tid];
    sCE[tid] = f*coef[128 + 127 - tid];
  }
  __syncthreads();
  int dd = tid >> 3, le = tid & 7;
  float accP[8] = {}, accM[8] = {};
  for (int u0 = 0; u0 < 128; u0 += 16) {
    for (int i = tid; i < 16*32; i += 256) {
      int uu = i >> 5, d2 = i & 31;
      s1[uu][d2] = in1[(long)(u0+uu)*D_ + d0 + d2];
    }
    for (int i = tid; i < 16*64; i += 256) {
      int uu = i >> 6, hl = i & 63;
      s2[uu][hl] = in2[(long)(u0+uu)*W_ + hb + hl];
    }
    __syncthreads();
    #pragma unroll
    for (int uu = 0; uu < 16; uu++) {
      float a = s1[uu][dd];
      float cAu = sCA[u0+uu], cEu = sCE[u0+uu];
      #pragma unroll
      for (int k = 0; k < 8; k++) {
        float v = a * s2[uu][k*8 + le];
        accP[k] = fmaf(cAu, v, accP[k]);
        accM[k] = fmaf(cEu, v, accM[k]);
      }
    }
    __syncthreads();
  }
  float b128 = coef[256 + 128];
  float eA   = ETA_*coef[127];
  float e128 = ETA_*coef[128 + 127];
  #pragma unroll
  for (int k = 0; k < 8; k++) {
    long idx = (long)(d0+dd)*W_ + hb + k*8 + le;
    float Po = Pb[idx], Mo = Mb[idx];
    Pb[idx] = b128*Po + eA*Mo + accP[k];
    Mb[idx] = e128*Mo + accM[k];
  }
}

// ------- fused K/V/Q projection -------
__global__ __launch_bounds__(256) void k_gemmkvq(
    const float* __restrict__ A,
    const float* __restrict__ Wk, const float* __restrict__ bk,
    const float* __restrict__ Wv, const float* __restrict__ bv,
    const float* __restrict__ Wq, const float* __restrict__ bq,
    float* __restrict__ KMo, float* __restrict__ VMo, float* __restrict__ Q1o)
{
  __shared__ float As[16][132];
  __shared__ float Bs[16][132];
  int bx = blockIdx.x;
  int sel = bx >> 3;
  int c0 = (bx & 7) * 128;
  int m0 = blockIdx.y * 128;
  const float* Bm   = sel == 0 ? Wk : sel == 1 ? Wv : Wq;
  const float* bias = sel == 0 ? bk : sel == 1 ? bv : bq;
  float* C          = sel == 0 ? KMo : sel == 1 ? VMo : Q1o;
  int tid = threadIdx.x;
  int tx = tid & 15, ty = tid >> 4;
  int ar = tid >> 1, ak = (tid & 1) * 8;
  int bkr = tid >> 4, bn = (tid & 15) * 8;
  float acc[8][8] = {};
  for (int k0 = 0; k0 < D_; k0 += 16) {
    {
      const float* ap = A + (long)(m0+ar)*D_ + k0 + ak;
      float4 v0 = *(const float4*)(ap);
      float4 v1 = *(const float4*)(ap+4);
      As[ak+0][ar]=v0.x; As[ak+1][ar]=v0.y; As[ak+2][ar]=v0.z; As[ak+3][ar]=v0.w;
      As[ak+4][ar]=v1.x; As[ak+5][ar]=v1.y; As[ak+6][ar]=v1.z; As[ak+7][ar]=v1.w;
      const float* bp = Bm + (long)(k0+bkr)*D_ + c0 + bn;
      *(float4*)(&Bs[bkr][bn])   = *(const float4*)(bp);
      *(float4*)(&Bs[bkr][bn+4]) = *(const float4*)(bp+4);
    }
    __syncthreads();
    #pragma unroll
    for (int kk = 0; kk < 16; kk++) {
      float av[8], bv8[8];
      #pragma unroll
      for (int i=0;i<8;i++) av[i] = As[kk][ty*8+i];
      #pragma unroll
      for (int j=0;j<8;j++) bv8[j] = Bs[kk][tx*8+j];
      #pragma unroll
      for (int i=0;i<8;i++)
        #pragma unroll
        for (int j=0;j<8;j++)
          acc[i][j] = fmaf(av[i], bv8[j], acc[i][j]);
    }
    __syncthreads();
  }
  #pragma unroll
  for (int i=0;i<8;i++) {
    int row = m0 + ty*8 + i;
    #pragma unroll
    for (int j=0;j<8;j++) acc[i][j] += bias[c0 + tx*8 + j];
    *(float4*)(C + (long)row*D_ + c0 + tx*8)     = make_float4(acc[i][0],acc[i][1],acc[i][2],acc[i][3]);
    *(float4*)(C + (long)row*D_ + c0 + tx*8 + 4) = make_float4(acc[i][4],acc[i][5],acc[i][6],acc[i][7]);
  }
}

__global__ void k_mul(const float* __restrict__ so, const float* __restrict__ mo,
                      float* __restrict__ outs, int s)
{
  int l = blockIdx.x, b = blockIdx.y, tid = threadIdx.x;
  long src = ((long)b*SEG_ + l)*D_ + tid*4;
  float4 a = *(const float4*)(so + src);
  float4 c = *(const float4*)(mo + src);
  a.x*=c.x; a.y*=c.y; a.z*=c.z; a.w*=c.w;
  *(float4*)(outs + ((long)b*N_ + s*SEG_ + l)*D_ + tid*4) = a;
}

// ---------------- host launcher ----------------
static inline void gemm(const float* A, const float* Bm, const float* bias, float* C,
                        int M, int N, int K, long sA, long sB, long sC, long sBias,
                        int batch, int bt, int silu_, hipStream_t st)
{
  dim3 g(N/64, (M+63)/64, batch), blk(256);
  if (!bt && !silu_) k_gemm<0,0><<<g,blk,0,st>>>(A,Bm,bias,C,M,N,K,sA,sB,sC,sBias);
  else if (!bt && silu_) k_gemm<0,1><<<g,blk,0,st>>>(A,Bm,bias,C,M,N,K,sA,sB,sC,sBias);
  else k_gemm<1,0><<<g,blk,0,st>>>(A,Bm,bias,C,M,N,K,sA,sB,sC,sBias);
}

extern "C" void kernel_launch(void* const* d_in, const int* in_sizes, int n_in,
                              void* d_out, int out_size, void* d_ws, size_t ws_size,
                              hipStream_t stream)
{
  (void)in_sizes; (void)n_in; (void)out_size; (void)ws_size;
  const int*   x     = (const int*)  d_in[0];
  const float* emb   = (const float*)d_in[1];
  const float* pers  = (const float*)d_in[2];
  const float* Wq    = (const float*)d_in[3];
  const float* bq    = (const float*)d_in[4];
  const float* Wk    = (const float*)d_in[5];
  const float* bk    = (const float*)d_in[6];
  const float* Wv    = (const float*)d_in[7];
  const float* bv    = (const float*)d_in[8];
  const float* aiw   = (const float*)d_in[9];
  const float* aib   = (const float*)d_in[10];
  const float* aow   = (const float*)d_in[11];
  const float* aob   = (const float*)d_in[12];
  const float* mW1in = (const float*)d_in[13];
  const float* mb1in = (const float*)d_in[14];
  const float* mW2in = (const float*)d_in[15];
  const float* mb2in = (const float*)d_in[16];
  const float* headw = (const float*)d_in[17];
  const float* headb = (const float*)d_in[18];
  float* out = (float*)d_out;
  float* ws  = (float*)d_ws;

  hipMemsetAsync(ws + MOM, 0, MOMSZ*sizeof(float), stream);
  hipMemsetAsync(ws + ZEROB, 0, 128*sizeof(float), stream);
  hipMemsetAsync(ws + CBAR, 0, 1024*sizeof(int), stream);
  k_embed<<<dim3(B_*N_), dim3(256), 0, stream>>>(x, emb, ws+XEMB);
  k_init<<<dim3((2*PER_+255)/256), dim3(256), 0, stream>>>(
      mW1in, mb1in, mW2in, mb2in, ws+PW1, ws+PB1, ws+PW2T, ws+PB2);
  k_coef<<<dim3(1), dim3(64), 0, stream>>>(ws+COEF);

  for (int s = 0; s < NSEG_; s++) {
    const float* segA = ws + XEMB + (size_t)s*SEG_*D_;
    // h = mlp(p, l2n(seg @ Wq + bq))
    gemm(segA, Wq, bq, ws+Q1, SEG_, D_, D_, (long)N_*D_, 0, (long)SEG_*D_, 0, B_, 0, 0, stream);
    k_l2n<<<dim3(B_*SEG_), dim3(256), 0, stream>>>(ws+Q1);
    gemm(ws+Q1, ws+PW1, ws+PB1, ws+AH, SEG_, W_, D_, (long)SEG_*D_, (long)D_*W_, (long)SEG_*W_, W_, B_, 0, 1, stream);
    gemm(ws+AH, ws+PW2T, ws+PB2, ws+HBUF, SEG_, D_, W_, (long)SEG_*W_, (long)D_*W_, (long)SEG_*D_, D_, B_, 1, 0, stream);
    // attention
    k_concat<<<dim3(T_, B_), dim3(256), 0, stream>>>(pers, ws+HBUF, ws+XEMB, s, ws+COMB);
    k_gemm128<<<dim3(3*D_/128, (B_*T_+127)/128), dim3(256), 0, stream>>>(
        ws+COMB, aiw, aib, ws+QKV, B_*T_, 3*D_, D_);
    k_attn<<<dim3(8, NH_, B_), dim3(256), 0, stream>>>(ws+QKV, ws+ATTN);
    gemm(ws+ATTN, aow, aob, ws+SEGO, B_*SEG_, D_, D_, 0, 0, 0, 0, 1, 0, 0, stream);
    // fused K/V/Q projections of seg_out
    k_gemmkvq<<<dim3(24, 2), dim3(256), 0, stream>>>(
        ws+SEGO, Wk, bk, Wv, bv, Wq, bq, ws+KM, ws+VM, ws+Q1);
    k_l2n<<<dim3(B_*SEG_), dim3(256), 0, stream>>>(ws+KM);
    k_l2n<<<dim3(B_*SEG_), dim3(256), 0, stream>>>(ws+Q1);
    // scan precompute: {Q1K, Q1Km} fused; G = K@K^T
    k_gemm2<<<dim3(2, 2, B_), dim3(256), 0, stream>>>(
        ws+KM, ws+PW1, ws+MW1, ws+AQ1K, ws+AQ1KM,
        D_, (long)SEG_*D_, (long)D_*W_, (long)SEG_*W_);
    gemm(ws+KM, ws+KM,  ws+ZEROB, ws+AGRAM, SEG_, SEG_, D_, (long)SEG_*D_, (long)SEG_*D_, (long)SEG_*SEG_, 0, B_, 1, 0, stream);
    // the scan
    k_scan<<<dim3(NBLK_, B_), dim3(256), 0, stream>>>(
        ws+PW2T, ws+MW2T, ws+PB1, ws+MB1, ws+PB2, ws+MB2, ws+VM,
        ws+AQ1K, ws+AQ1KM, ws+AGRAM,
        ws+ADZ1, ws+AA1H, ws+AEH,
        ws+AEXA1, ws+AEXSP, ws+AEXR, ws+AEXEE,
        ws+COEF, (int*)(ws+CBAR), s);
    // reconstruct weights/momenta
    k_recon<<<dim3(32, 2, 4), dim3(256), 0, stream>>>(
        ws+PW1, ws+MW1, ws+PW2T, ws+MW2T,
        ws+KM, ws+AEH, ws+ADZ1, ws+AA1H, ws+COEF);
    // mem_out = mlp(p_new, Q1)
    gemm(ws+Q1, ws+PW1, ws+PB1, ws+AH, SEG_, W_, D_, (long)SEG_*D_, (long)D_*W_, (long)SEG_*W_, W_, B_, 0, 1, stream);
    gemm(ws+AH, ws+PW2T, ws+PB2, ws+MEMO, SEG_, D_, W_, (long)SEG_*W_, (long)D_*W_, (long)SEG_*D_, D_, B_, 1, 0, stream);
    k_mul<<<dim3(SEG_, B_), dim3(256), 0, stream>>>(ws+SEGO, ws+MEMO, ws+OUTS, s);
  }
  // head via bf16-split MFMA
  k_head_mfma<<<dim3(V_/128, (B_*N_)/128), dim3(256), 0, stream>>>(
      ws+OUTS, headw, headb, out, B_*N_, V_, D_);
}

// Round 9
// 8502.934 us; speedup vs baseline: 1.5292x; 1.0209x over previous
//
#include <hip/hip_runtime.h>
#include <math.h>

#define D_    1024
#define B_    2
#define N_    512
#define SEG_  128
#define NSEG_ 4
#define NPT_  16
#define T_    272
#define NH_   16
#define HD_   64
#define W_    128
#define V_    32000

#define THETA_ 0.1f
#define ETA_   0.9f
#define PDEC_  0.99f
#define EPSN_  1e-6f
#define NB2_  32   // blocks per sample in the scan (j-slice = 32)
#define FSTR_ 32   // flag stride in ints (128B)

typedef __bf16 bf16x8 __attribute__((ext_vector_type(8)));
typedef float  f32x4  __attribute__((ext_vector_type(4)));

// ---------------- workspace layout (float offsets) ----------------
static const size_t XEMB = 0;                       // [B,N,D]
static const size_t OUTS = XEMB + (size_t)B_*N_*D_; // [B,N,D]
static const size_t PW1  = OUTS + (size_t)B_*N_*D_; // [B,1024,128]
static const size_t PB1  = PW1  + (size_t)B_*D_*W_; // [B,128]
static const size_t PW2T = PB1  + (size_t)B_*W_;    // [B,1024,128]  (W2 transposed)
static const size_t PB2  = PW2T + (size_t)B_*D_*W_; // [B,1024]
static const size_t MOM  = PB2  + (size_t)B_*D_;
static const size_t MW1  = MOM;
static const size_t MB1  = MW1  + (size_t)B_*D_*W_;
static const size_t MW2T = MB1  + (size_t)B_*W_;
static const size_t MB2  = MW2T + (size_t)B_*D_*W_;
static const size_t MOMSZ = (size_t)B_*(D_*W_ + W_ + D_*W_ + D_);
static const size_t Q1   = MOM  + MOMSZ;              // [B,128,1024]
static const size_t AH   = Q1   + (size_t)B_*SEG_*D_; // [B,128,128]
static const size_t HBUF = AH   + (size_t)B_*SEG_*W_; // [B,128,1024]
static const size_t COMB = HBUF + (size_t)B_*SEG_*D_; // [B,272,1024]
static const size_t QKV  = COMB + (size_t)B_*T_*D_;   // [B,272,3072]
static const size_t ATTN = QKV  + (size_t)B_*T_*3*D_; // [B,128,1024]
static const size_t SEGO = ATTN + (size_t)B_*SEG_*D_; // [B,128,1024]
static const size_t KM   = SEGO + (size_t)B_*SEG_*D_; // [B,128,1024]
static const size_t VM   = KM   + (size_t)B_*SEG_*D_; // [B,128,1024]
static const size_t MEMO = VM   + (size_t)B_*SEG_*D_; // [B,128,1024]
static const size_t WSEND = MEMO + (size_t)B_*SEG_*D_;

// scan-phase buffers ALIAS the QKV region
static const size_t AQ1K  = QKV;
static const size_t AQ1KM = AQ1K  + 32768;
static const size_t AGRAM = AQ1KM + 32768;
static const size_t ADZ1  = AGRAM + 32768;
static const size_t AA1H  = ADZ1  + 32768;
static const size_t AEH   = AA1H  + 32768;
static const size_t AEXR  = AEH + (size_t)B_*SEG_*D_;  // [2][B][32][128]
static const size_t AEXEE = AEXR + 16384;              // [2][B][32][128]
// persistent tail
static const size_t COEF  = WSEND;
static const size_t ZEROB = COEF + 512;
static const size_t CBAR  = ZEROB + 128;               // [B][NB2][FSTR] = 2048 ints

__device__ __forceinline__ float sigf(float x) { return 1.f/(1.f+expf(-x)); }

__device__ __forceinline__ void gstore(float* p, float v) {
  __hip_atomic_store(p, v, __ATOMIC_RELAXED, __HIP_MEMORY_SCOPE_AGENT);
}
__device__ __forceinline__ float gload(const float* p) {
  return __hip_atomic_load(p, __ATOMIC_RELAXED, __HIP_MEMORY_SCOPE_AGENT);
}

// RNE bf16 split: a ≈ float(h) + float(l), residual ≤ 2^-18 |a|
__device__ __forceinline__ void bsplit(float a, short& h, short& l) {
  unsigned u = __builtin_bit_cast(unsigned, a);
  unsigned hb = (u + 0x7fffu + ((u >> 16) & 1u)) >> 16;
  h = (short)hb;
  float hf = __builtin_bit_cast(float, hb << 16);
  float r = a - hf;
  unsigned ur = __builtin_bit_cast(unsigned, r);
  unsigned lb = (ur + 0x7fffu + ((ur >> 16) & 1u)) >> 16;
  l = (short)lb;
}

// ---------------- generic tiled fp32 GEMM (64x64) ----------------
template<int BT, int SILU>
__global__ __launch_bounds__(256) void k_gemm(
    const float* __restrict__ A, const float* __restrict__ Bm,
    const float* __restrict__ bias, float* __restrict__ C,
    int M, int N, int K, long sA, long sB, long sC, long sBias)
{
  __shared__ float As[16][68];
  __shared__ float Bs[16][68];
  int bz = blockIdx.z;
  A += bz*sA; Bm += bz*sB; C += bz*sC; bias += bz*sBias;
  int n0 = blockIdx.x*64, m0 = blockIdx.y*64;
  int tid = threadIdx.x;
  int tx = tid & 15, ty = tid >> 4;
  int r  = tid >> 2;
  int kq = (tid & 3) * 4;
  float acc[4][4] = {};
  for (int k0 = 0; k0 < K; k0 += 16) {
    {
      int row = m0 + r;
      float4 v = make_float4(0.f,0.f,0.f,0.f);
      if (row < M) v = *(const float4*)(A + (long)row*K + k0 + kq);
      As[kq+0][r]=v.x; As[kq+1][r]=v.y; As[kq+2][r]=v.z; As[kq+3][r]=v.w;
    }
    if (BT) {
      int row = n0 + r;
      float4 v = *(const float4*)(Bm + (long)row*K + k0 + kq);
      Bs[kq+0][r]=v.x; Bs[kq+1][r]=v.y; Bs[kq+2][r]=v.z; Bs[kq+3][r]=v.w;
    } else {
      int c = tid & 63, r4 = tid >> 6;
      #pragma unroll
      for (int p = 0; p < 4; p++) {
        int kk = r4 + p*4;
        Bs[kk][c] = Bm[(long)(k0+kk)*N + n0 + c];
      }
    }
    __syncthreads();
    #pragma unroll
    for (int kk = 0; kk < 16; kk++) {
      float av[4], bv[4];
      #pragma unroll
      for (int i=0;i<4;i++) av[i] = As[kk][ty*4+i];
      #pragma unroll
      for (int j=0;j<4;j++) bv[j] = Bs[kk][tx*4+j];
      #pragma unroll
      for (int i=0;i<4;i++)
        #pragma unroll
        for (int j=0;j<4;j++)
          acc[i][j] = fmaf(av[i], bv[j], acc[i][j]);
    }
    __syncthreads();
  }
  #pragma unroll
  for (int i=0;i<4;i++) {
    int row = m0 + ty*4 + i;
    if (row >= M) continue;
    #pragma unroll
    for (int j=0;j<4;j++) {
      int col = n0 + tx*4 + j;
      float v = acc[i][j] + bias[col];
      if (SILU) v = v * sigf(v);
      C[(long)row*N + col] = v;
    }
  }
}

// ------- dual-output 64x64 GEMM: C1=A@B1, C2=A@B2 (no bias) ----
__global__ __launch_bounds__(256) void k_gemm2(
    const float* __restrict__ A, const float* __restrict__ B1,
    const float* __restrict__ B2, float* __restrict__ C1, float* __restrict__ C2,
    int K, long sA, long sB, long sC)
{
  __shared__ float As[16][68];
  __shared__ float B1s[16][68];
  __shared__ float B2s[16][68];
  int bz = blockIdx.z;
  A += bz*sA; B1 += bz*sB; B2 += bz*sB; C1 += bz*sC; C2 += bz*sC;
  int n0 = blockIdx.x*64, m0 = blockIdx.y*64;
  int tid = threadIdx.x;
  int tx = tid & 15, ty = tid >> 4;
  int r  = tid >> 2;
  int kq = (tid & 3) * 4;
  float acc1[4][4] = {}, acc2[4][4] = {};
  for (int k0 = 0; k0 < K; k0 += 16) {
    {
      float4 v = *(const float4*)(A + (long)(m0+r)*K + k0 + kq);
      As[kq+0][r]=v.x; As[kq+1][r]=v.y; As[kq+2][r]=v.z; As[kq+3][r]=v.w;
    }
    {
      int c = tid & 63, r4 = tid >> 6;
      #pragma unroll
      for (int p = 0; p < 4; p++) {
        int kk = r4 + p*4;
        B1s[kk][c] = B1[(long)(k0+kk)*W_ + n0 + c];
        B2s[kk][c] = B2[(long)(k0+kk)*W_ + n0 + c];
      }
    }
    __syncthreads();
    #pragma unroll
    for (int kk = 0; kk < 16; kk++) {
      float av[4], b1v[4], b2v[4];
      #pragma unroll
      for (int i=0;i<4;i++) av[i] = As[kk][ty*4+i];
      #pragma unroll
      for (int j=0;j<4;j++) { b1v[j] = B1s[kk][tx*4+j]; b2v[j] = B2s[kk][tx*4+j]; }
      #pragma unroll
      for (int i=0;i<4;i++)
        #pragma unroll
        for (int j=0;j<4;j++) {
          acc1[i][j] = fmaf(av[i], b1v[j], acc1[i][j]);
          acc2[i][j] = fmaf(av[i], b2v[j], acc2[i][j]);
        }
    }
    __syncthreads();
  }
  #pragma unroll
  for (int i=0;i<4;i++) {
    int row = m0 + ty*4 + i;
    #pragma unroll
    for (int j=0;j<4;j++) {
      int col = n0 + tx*4 + j;
      C1[(long)row*W_ + col] = acc1[i][j];
      C2[(long)row*W_ + col] = acc2[i][j];
    }
  }
}

// ------- 128x128 tile fp32 GEMM (M-guarded) -------
__global__ __launch_bounds__(256) void k_gemm128(
    const float* __restrict__ A, const float* __restrict__ Bm,
    const float* __restrict__ bias, float* __restrict__ C,
    int M, int N, int K)
{
  __shared__ float As[16][132];
  __shared__ float Bs[16][132];
  int n0 = blockIdx.x*128, m0 = blockIdx.y*128;
  int tid = threadIdx.x;
  int tx = tid & 15, ty = tid >> 4;
  int ar = tid >> 1, ak = (tid & 1) * 8;
  int bk = tid >> 4, bn = (tid & 15) * 8;
  int arow = min(m0 + ar, M-1);
  float acc[8][8] = {};
  for (int k0 = 0; k0 < K; k0 += 16) {
    {
      const float* ap = A + (long)arow*K + k0 + ak;
      float4 v0 = *(const float4*)(ap);
      float4 v1 = *(const float4*)(ap+4);
      As[ak+0][ar]=v0.x; As[ak+1][ar]=v0.y; As[ak+2][ar]=v0.z; As[ak+3][ar]=v0.w;
      As[ak+4][ar]=v1.x; As[ak+5][ar]=v1.y; As[ak+6][ar]=v1.z; As[ak+7][ar]=v1.w;
      const float* bp = Bm + (long)(k0+bk)*N + n0 + bn;
      *(float4*)(&Bs[bk][bn])   = *(const float4*)(bp);
      *(float4*)(&Bs[bk][bn+4]) = *(const float4*)(bp+4);
    }
    __syncthreads();
    #pragma unroll
    for (int kk = 0; kk < 16; kk++) {
      float av[8], bv[8];
      #pragma unroll
      for (int i=0;i<8;i++) av[i] = As[kk][ty*8+i];
      #pragma unroll
      for (int j=0;j<8;j++) bv[j] = Bs[kk][tx*8+j];
      #pragma unroll
      for (int i=0;i<8;i++)
        #pragma unroll
        for (int j=0;j<8;j++)
          acc[i][j] = fmaf(av[i], bv[j], acc[i][j]);
    }
    __syncthreads();
  }
  #pragma unroll
  for (int i=0;i<8;i++) {
    int row = m0 + ty*8 + i;
    if (row >= M) continue;
    #pragma unroll
    for (int j=0;j<8;j++) acc[i][j] += bias[n0 + tx*8 + j];
    *(float4*)(C + (long)row*N + n0 + tx*8)     = make_float4(acc[i][0],acc[i][1],acc[i][2],acc[i][3]);
    *(float4*)(C + (long)row*N + n0 + tx*8 + 4) = make_float4(acc[i][4],acc[i][5],acc[i][6],acc[i][7]);
  }
}

// ------- head GEMM via bf16-split MFMA -------
__global__ __launch_bounds__(256) void k_head_mfma(
    const float* __restrict__ A, const float* __restrict__ Bm,
    const float* __restrict__ bias, float* __restrict__ C,
    int M, int N, int K)
{
  __shared__ short Ah[128][48];
  __shared__ short Al[128][48];
  __shared__ short Bh[32][132];
  __shared__ short Bl[32][132];
  int n0 = blockIdx.x*128, m0 = blockIdx.y*128;
  int tid = threadIdx.x;
  int wave = tid >> 6, lane = tid & 63;
  int wm = (wave >> 1) * 64, wn = (wave & 1) * 64;
  int lrow = lane & 15, lk = (lane >> 4) * 8;
  f32x4 acc[4][4] = {};
  for (int k0 = 0; k0 < K; k0 += 32) {
    __syncthreads();
    {
      int r = tid >> 1, kq = (tid & 1) * 16;
      const float* ap = A + (long)(m0 + r)*K + k0 + kq;
      #pragma unroll
      for (int q = 0; q < 16; q += 4) {
        float4 v = *(const float4*)(ap + q);
        short h0,l0,h1,l1,h2,l2,h3,l3;
        bsplit(v.x,h0,l0); bsplit(v.y,h1,l1); bsplit(v.z,h2,l2); bsplit(v.w,h3,l3);
        *(short4*)&Ah[r][kq+q] = make_short4(h0,h1,h2,h3);
        *(short4*)&Al[r][kq+q] = make_short4(l0,l1,l2,l3);
      }
    }
    {
      int kr = tid >> 3, nq = (tid & 7) * 16;
      const float* bp = Bm + (long)(k0 + kr)*N + n0 + nq;
      #pragma unroll
      for (int q = 0; q < 16; q += 4) {
        float4 v = *(const float4*)(bp + q);
        short h0,l0,h1,l1,h2,l2,h3,l3;
        bsplit(v.x,h0,l0); bsplit(v.y,h1,l1); bsplit(v.z,h2,l2); bsplit(v.w,h3,l3);
        *(short4*)&Bh[kr][nq+q] = make_short4(h0,h1,h2,h3);
        *(short4*)&Bl[kr][nq+q] = make_short4(l0,l1,l2,l3);
      }
    }
    __syncthreads();
    bf16x8 bh[4], bl[4];
    #pragma unroll
    for (int nf = 0; nf < 4; nf++) {
      int col = wn + nf*16 + lrow;
      #pragma unroll
      for (int j = 0; j < 8; j++) {
        bh[nf][j] = __builtin_bit_cast(__bf16, Bh[lk+j][col]);
        bl[nf][j] = __builtin_bit_cast(__bf16, Bl[lk+j][col]);
      }
    }
    #pragma unroll
    for (int mf = 0; mf < 4; mf++) {
      int arow2 = wm + mf*16 + lrow;
      bf16x8 ah = *(const bf16x8*)&Ah[arow2][lk];
      bf16x8 al = *(const bf16x8*)&Al[arow2][lk];
      #pragma unroll
      for (int nf = 0; nf < 4; nf++) {
        acc[mf][nf] = __builtin_amdgcn_mfma_f32_16x16x32_bf16(ah, bh[nf], acc[mf][nf], 0, 0, 0);
        acc[mf][nf] = __builtin_amdgcn_mfma_f32_16x16x32_bf16(ah, bl[nf], acc[mf][nf], 0, 0, 0);
        acc[mf][nf] = __builtin_amdgcn_mfma_f32_16x16x32_bf16(al, bh[nf], acc[mf][nf], 0, 0, 0);
      }
    }
  }
  #pragma unroll
  for (int mf = 0; mf < 4; mf++) {
    #pragma unroll
    for (int nf = 0; nf < 4; nf++) {
      int col = n0 + wn + nf*16 + lrow;
      float bv = bias[col];
      #pragma unroll
      for (int j = 0; j < 4; j++) {
        int row = m0 + wm + mf*16 + (lane >> 4)*4 + j;
        C[(long)row*N + col] = acc[mf][nf][j] + bv;
      }
    }
  }
}

// ---------------- small kernels ----------------
__global__ void k_embed(const int* __restrict__ x, const float* __restrict__ emb,
                        float* __restrict__ xe)
{
  int row = blockIdx.x, tid = threadIdx.x;
  int idx = x[row];
  float4 v = *(const float4*)(emb + (long)idx*D_ + tid*4);
  *(float4*)(xe + (long)row*D_ + tid*4) = v;
}

#define PER_ 263296L
__global__ void k_init(const float* __restrict__ mW1in, const float* __restrict__ mb1in,
                       const float* __restrict__ mW2in, const float* __restrict__ mb2in,
                       float* __restrict__ pW1, float* __restrict__ pb1,
                       float* __restrict__ pW2T, float* __restrict__ pb2)
{
  long g = (long)blockIdx.x*256 + threadIdx.x;
  if (g >= 2*PER_) return;
  int b = (int)(g / PER_);
  long rr = g % PER_;
  if (rr < 131072)       pW1[(long)b*131072 + rr] = mW1in[rr];
  else if (rr < 131200)  pb1[b*W_ + (rr-131072)] = mb1in[rr-131072];
  else if (rr < 262272) { long l = rr-131200; int j=(int)(l>>7), h=(int)(l&127);
                          pW2T[(long)b*131072 + l] = mW2in[(long)h*D_ + j]; }
  else                   pb2[b*D_ + (rr-262272)] = mb2in[rr-262272];
}

__global__ void k_coef(float* __restrict__ c)
{
  if (blockIdx.x == 0 && threadIdx.x == 0) {
    c[0] = 1.f; c[128] = 1.f;
    float A = 1.f, eta_d = 1.f;
    for (int d = 1; d < 128; d++) {
      eta_d *= ETA_;
      A = PDEC_*A + eta_d;
      c[d] = A;
      c[128 + d] = eta_d;
    }
    c[256] = 1.f;
    float bp = 1.f;
    for (int t = 1; t <= 128; t++) { bp *= PDEC_; c[256 + t] = bp; }
  }
}

__global__ __launch_bounds__(256) void k_l2n(float* __restrict__ X)
{
  long row = blockIdx.x;
  float* p = X + row*D_;
  int tid = threadIdx.x;
  float4 v = *(float4*)(p + tid*4);
  float ss = v.x*v.x + v.y*v.y + v.z*v.z + v.w*v.w;
  for (int o=32;o;o>>=1) ss += __shfl_xor(ss,o);
  __shared__ float wsum[4];
  if ((tid&63)==0) wsum[tid>>6] = ss;
  __syncthreads();
  float tot = wsum[0]+wsum[1]+wsum[2]+wsum[3];
  float sc = 1.f/(sqrtf(tot)+EPSN_);
  v.x*=sc; v.y*=sc; v.z*=sc; v.w*=sc;
  *(float4*)(p + tid*4) = v;
}

__global__ void k_concat(const float* __restrict__ pers, const float* __restrict__ h,
                         const float* __restrict__ xemb, int s, float* __restrict__ comb)
{
  int row = blockIdx.x, b = blockIdx.y, tid = threadIdx.x;
  const float* src;
  if (row < NPT_)            src = pers + (long)row*D_;
  else if (row < NPT_+SEG_)  src = h    + ((long)b*SEG_ + (row-NPT_))*D_;
  else                       src = xemb + ((long)b*N_ + s*SEG_ + (row-NPT_-SEG_))*D_;
  float4 v = *(const float4*)(src + tid*4);
  *(float4*)(comb + ((long)b*T_ + row)*D_ + tid*4) = v;
}

__global__ __launch_bounds__(256) void k_attn(const float* __restrict__ qkv,
                                              float* __restrict__ outp)
{
  __shared__ float sQ[16][68];
  __shared__ float sKV[64][68];
  __shared__ float sS[16][273];
  int qt = blockIdx.x, head = blockIdx.y, b = blockIdx.z;
  int tid = threadIdx.x;
  const float* base = qkv + (long)b*T_*3*D_;
  int qoff = head*HD_, koff = D_ + head*HD_, voff = 2*D_ + head*HD_;
  int qrow0 = NPT_ + SEG_ + qt*16;
  {
    int rr = tid>>4, c4 = (tid&15)*4;
    float4 v = *(const float4*)(base + (long)(qrow0+rr)*3*D_ + qoff + c4);
    sQ[rr][c4]=v.x; sQ[rr][c4+1]=v.y; sQ[rr][c4+2]=v.z; sQ[rr][c4+3]=v.w;
  }
  __syncthreads();
  for (int j0 = 0; j0 < T_; j0 += 64) {
    int chunk = min(64, T_ - j0);
    {
      int jj = tid>>2, cq = (tid&3)*16;
      if (jj < chunk) {
        #pragma unroll
        for (int q4=0;q4<4;q4++) {
          float4 v = *(const float4*)(base + (long)(j0+jj)*3*D_ + koff + cq + q4*4);
          sKV[jj][cq+q4*4]=v.x; sKV[jj][cq+q4*4+1]=v.y; sKV[jj][cq+q4*4+2]=v.z; sKV[jj][cq+q4*4+3]=v.w;
        }
      }
    }
    __syncthreads();
    int rr = tid>>4, jj0 = tid&15;
    #pragma unroll
    for (int p=0;p<4;p++) {
      int jj = jj0 + p*16;
      if (jj < chunk) {
        float s = 0.f;
        #pragma unroll 8
        for (int c=0;c<HD_;c++) s = fmaf(sQ[rr][c], sKV[jj][c], s);
        s *= 0.125f;
        int jg = j0 + jj, qg = qrow0 + rr;
        if (jg > qg) s = -3.0e38f;
        sS[rr][jg] = s;
      }
    }
    __syncthreads();
  }
  {
    int rr = tid>>4, l16 = tid&15;
    float m = -3.4e38f;
    for (int j=l16; j<T_; j+=16) m = fmaxf(m, sS[rr][j]);
    for (int o=8;o;o>>=1) m = fmaxf(m, __shfl_xor(m,o));
    float sum = 0.f;
    for (int j=l16; j<T_; j+=16) { float e = expf(sS[rr][j]-m); sS[rr][j] = e; sum += e; }
    for (int o=8;o;o>>=1) sum += __shfl_xor(sum,o);
    float inv = 1.f/sum;
    for (int j=l16; j<T_; j+=16) sS[rr][j] *= inv;
  }
  __syncthreads();
  float acc[4] = {0.f,0.f,0.f,0.f};
  int rr = tid>>4, c4 = (tid&15)*4;
  for (int j0 = 0; j0 < T_; j0 += 64) {
    int chunk = min(64, T_ - j0);
    {
      int jj = tid>>2, cq = (tid&3)*16;
      if (jj < chunk) {
        #pragma unroll
        for (int q4=0;q4<4;q4++) {
          float4 v = *(const float4*)(base + (long)(j0+jj)*3*D_ + voff + cq + q4*4);
          sKV[jj][cq+q4*4]=v.x; sKV[jj][cq+q4*4+1]=v.y; sKV[jj][cq+q4*4+2]=v.z; sKV[jj][cq+q4*4+3]=v.w;
        }
      }
    }
    __syncthreads();
    for (int jj=0; jj<chunk; jj++) {
      float p = sS[rr][j0+jj];
      #pragma unroll
      for (int i=0;i<4;i++) acc[i] = fmaf(p, sKV[jj][c4+i], acc[i]);
    }
    __syncthreads();
  }
  float4 o4 = make_float4(acc[0],acc[1],acc[2],acc[3]);
  *(float4*)(outp + ((long)(b*SEG_) + qt*16 + rr)*D_ + head*HD_ + c4) = o4;
}

// ------- fence-free flag barrier (NB2_ participants) ---------
__device__ __forceinline__ void gbar(int* flags, int blk, int gen)
{
  asm volatile("s_waitcnt vmcnt(0) lgkmcnt(0)" ::: "memory");
  __syncthreads();
  if (threadIdx.x == 0)
    __hip_atomic_store(flags + blk*FSTR_, gen, __ATOMIC_RELAXED, __HIP_MEMORY_SCOPE_AGENT);
  if (threadIdx.x < NB2_) {
    while (__hip_atomic_load(flags + threadIdx.x*FSTR_, __ATOMIC_RELAXED,
                             __HIP_MEMORY_SCOPE_AGENT) < gen)
      __builtin_amdgcn_s_sleep(1);
  }
  __syncthreads();
}

// ---- persistent token-space scan: full-h replicated, j 32-sliced, 1 barrier/token ----
__global__ __launch_bounds__(256) void k_scan(
  const float* __restrict__ pW2T, const float* __restrict__ mW2T,
  float* __restrict__ pb1, float* __restrict__ mb1,
  float* __restrict__ pb2, float* __restrict__ mb2,
  const float* __restrict__ Vm,
  const float* __restrict__ q1k, const float* __restrict__ q1km,
  const float* __restrict__ G,
  float* __restrict__ dz1o, float* __restrict__ a1o, float* __restrict__ eo,
  float* __restrict__ exR, float* __restrict__ exEE,
  const float* __restrict__ coef, int* __restrict__ barbase, int seg)
{
  __shared__ float sDZ[128][129];   // full-h dz1 history (replicated)
  __shared__ float sA1[128][129];   // full-h a1 history (replicated)
  __shared__ float sEh[128][33];    // e history, local j-slice (32)
  __shared__ float sB1[128], sMB1[128], sZ1[128], sR[128];
  __shared__ float sB2[32], sMB2[32];
  __shared__ float sAt[128];
  __shared__ float sBp[129];
  __shared__ float sGc[128];
  __shared__ float sS[128];
  __shared__ float sEEc[128];

  int b = blockIdx.y, blk = blockIdx.x, tid = threadIdx.x;
  int j0 = blk*32;
  int* flags = barbase + b*(NB2_*FSTR_);
  int gbase = seg*200;
  const float* W0 = pW2T + (long)b*131072;
  const float* Wm = mW2T + (long)b*131072;

  if (tid < 128) { sAt[tid] = coef[tid]; sB1[tid] = pb1[b*W_+tid]; sMB1[tid] = mb1[b*W_+tid]; }
  else if (tid < 160) { int j = tid-128; sB2[j] = pb2[b*D_+j0+j]; sMB2[j] = mb2[b*D_+j0+j]; }
  for (int i = tid; i < 129; i += 256) sBp[i] = coef[256+i];
  __syncthreads();

  for (int t = 0; t < SEG_; ++t) {
    int par = t & 1;
    float bp = sBp[t];
    float ca = (t>0) ? ETA_*sAt[t-1] : 0.f;

    // ---- A: bias recurrences, G-row prescale, q1k loads ----
    float rq1k = 0.f, rq1km = 0.f;
    if (tid < 128) {
      rq1k  = q1k [((long)b*SEG_+t)*W_ + tid];
      rq1km = q1km[((long)b*SEG_+t)*W_ + tid];
      if (t > 0) {
        float mm = ETA_*sMB1[tid] - THETA_*sDZ[t-1][tid];
        sMB1[tid] = mm; sB1[tid] = PDEC_*sB1[tid] + mm;
      }
      if (tid < t) sGc[tid] = sAt[t-1-tid]*G[((long)b*SEG_+t)*SEG_ + tid];
    } else if (tid < 160) {
      int j = tid-128;
      if (t > 0) {
        float mm = ETA_*sMB2[j] - 2.f*THETA_*sEh[t-1][j];
        sMB2[j] = mm; sB2[j] = PDEC_*sB2[j] + mm;
      }
    }
    __syncthreads();

    // ---- B: z1/a1 for ALL h (replicated) ----
    if (tid < 128) {
      float acc = 0.f;
      for (int u = 0; u < t; ++u) acc = fmaf(sGc[u], sDZ[u][tid], acc);
      float z1 = bp*rq1k + ca*rq1km + sB1[tid] - THETA_*acc;
      sZ1[tid] = z1;
      sA1[t][tid] = z1 * sigf(z1);
    }
    __syncthreads();

    // ---- C: sS scalars from in-block a1 Gram ----
    if (tid < t) {
      float acc = 0.f;
      #pragma unroll 8
      for (int h = 0; h < 128; ++h) acc = fmaf(sA1[tid][h], sA1[t][h], acc);
      sS[tid] = -2.f*THETA_*sAt[t-1-tid]*acc;
    }
    __syncthreads();

    // ---- D: e slice (32 j, 8 lanes each; W from L2) ----
    {
      int j = tid >> 3, l = tid & 7;
      const float* w0r = W0 + (long)(j0+j)*128;
      const float* wmr = Wm + (long)(j0+j)*128;
      float g = 0.f, gm = 0.f;
      for (int h = l; h < 128; h += 8) {
        g  = fmaf(w0r[h], sA1[t][h], g);
        gm = fmaf(wmr[h], sA1[t][h], gm);
      }
      float corr = 0.f;
      for (int u = l; u < t; u += 8) corr = fmaf(sS[u], sEh[u][j], corr);
      float tot = bp*g + ca*gm + corr;
      tot += __shfl_xor(tot,4); tot += __shfl_xor(tot,2); tot += __shfl_xor(tot,1);
      if (l == 0) sEh[t][j] = tot + sB2[j] - Vm[((long)b*SEG_+t)*D_ + j0+j];
    }
    __syncthreads();

    // ---- E: r partials (all h) + ee partials ----
    {
      int h = tid >> 1, half = tid & 1;
      float racc = 0.f;
      for (int jj = half*16; jj < half*16+16; ++jj) {
        float w = bp*W0[(long)(j0+jj)*128 + h] + ca*Wm[(long)(j0+jj)*128 + h];
        racc = fmaf(w, sEh[t][jj], racc);
      }
      racc += __shfl_xor(racc,1);
      if (half == 0) gstore(&exR[(((long)par*B_ + b)*NB2_ + blk)*W_ + h], racc);
      if (h < t) {
        float eacc = 0.f;
        for (int jj = half*16; jj < half*16+16; ++jj)
          eacc = fmaf(sEh[h][jj], sEh[t][jj], eacc);
        eacc += __shfl_xor(eacc,1);
        if (half == 0) gstore(&exEE[(((long)par*B_ + b)*NB2_ + blk)*W_ + h], eacc);
      }
    }
    gbar(flags, blk, gbase + t + 1);

    // ---- F: gather r/ee, dz1 full-h ----
    {
      int h = tid >> 1, half = tid & 1;
      float racc = 0.f;
      #pragma unroll
      for (int k = 0; k < 16; ++k)
        racc += gload(&exR[(((long)par*B_ + b)*NB2_ + half*16 + k)*W_ + h]);
      racc += __shfl_xor(racc,1);
      if (half == 0) sR[h] = racc;
      if (h < t) {
        float eacc = 0.f;
        #pragma unroll
        for (int k = 0; k < 16; ++k)
          eacc += gload(&exEE[(((long)par*B_ + b)*NB2_ + half*16 + k)*W_ + h]);
        eacc += __shfl_xor(eacc,1);
        if (half == 0) sEEc[h] = -2.f*THETA_*sAt[t-1-h]*eacc;
      }
    }
    __syncthreads();
    if (tid < 128) {
      float macc = 0.f;
      for (int u = 0; u < t; ++u) macc = fmaf(sEEc[u], sA1[u][tid], macc);
      float z = sZ1[tid], sg = sigf(z);
      sDZ[t][tid] = 2.f*(sR[tid] + macc)*sg*(1.f + z*(1.f - sg));
    }
    __syncthreads();
  }

  // ---- epilogue ----
  if (tid < 128) {
    if (blk == 0) {
      float mm = ETA_*sMB1[tid] - THETA_*sDZ[127][tid];
      mb1[b*W_ + tid] = mm;
      pb1[b*W_ + tid] = PDEC_*sB1[tid] + mm;
    }
  } else if (tid < 160) {
    int j = tid-128;
    float mm = ETA_*sMB2[j] - 2.f*THETA_*sEh[127][j];
    mb2[b*D_ + j0+j] = mm;
    pb2[b*D_ + j0+j] = PDEC_*sB2[j] + mm;
  }
  for (int i = tid; i < 128*4; i += 256) {
    int t2 = i >> 2, hh = (i & 3) + blk*4;
    dz1o[((long)b*SEG_+t2)*W_ + hh] = sDZ[t2][hh];
    a1o [((long)b*SEG_+t2)*W_ + hh] = sA1[t2][hh];
  }
  for (int i = tid; i < 128*32; i += 256) {
    int t2 = i >> 5, jj = i & 31;
    eo[((long)b*SEG_+t2)*D_ + j0+jj] = sEh[t2][jj];
  }
}

// ---------------- weight/momentum reconstruction --------------------------
__global__ __launch_bounds__(256) void k_recon(
  float* __restrict__ pW1, float* __restrict__ mW1,
  float* __restrict__ pW2T, float* __restrict__ mW2T,
  const float* __restrict__ KMp, const float* __restrict__ Eh,
  const float* __restrict__ DZ1, const float* __restrict__ A1h,
  const float* __restrict__ coef)
{
  __shared__ float s1[16][33];
  __shared__ float s2[16][65];
  __shared__ float sCA[128], sCE[128];
  int dt = blockIdx.x, ht = blockIdx.y, kb = blockIdx.z;
  int kind = kb >> 1, b = kb & 1;
  int tid = threadIdx.x;
  int d0 = dt*32, hb = ht*64;
  const float* in1 = (kind ? Eh : KMp) + (long)b*SEG_*D_;
  const float* in2 = (kind ? A1h : DZ1) + (long)b*SEG_*W_;
  float* Pb = (kind ? pW2T : pW1) + (long)b*131072;
  float* Mb = (kind ? mW2T : mW1) + (long)b*131072;
  float f = kind ? -2.f*THETA_ : -THETA_;
  if (tid < 128) {
    sCA[tid] = f*coef[127 - tid];
    sCE[tid] = f*coef[128 + 127 - tid];
  }
  __syncthreads();
  int dd = tid >> 3, le = tid & 7;
  float accP[8] = {}, accM[8] = {};
  for (int u0 = 0; u0 < 128; u0 += 16) {
    for (int i = tid; i < 16*32; i += 256) {
      int uu = i >> 5, d2 = i & 31;
      s1[uu][d2] = in1[(long)(u0+uu)*D_ + d0 + d2];
    }
    for (int i = tid; i < 16*64; i += 256) {
      int uu = i >> 6, hl = i & 63;
      s2[uu][hl] = in2[(long)(u0+uu)*W_ + hb + hl];
    }
    __syncthreads();
    #pragma unroll
    for (int uu = 0; uu < 16; uu++) {
      float a = s1[uu][dd];
      float cAu = sCA[u0+uu], cEu = sCE[u0+uu];
      #pragma unroll
      for (int k = 0; k < 8; k++) {
        float v = a * s2[uu][k*8 + le];
        accP[k] = fmaf(cAu, v, accP[k]);
        accM[k] = fmaf(cEu, v, accM[k]);
      }
    }
    __syncthreads();
  }
  float b128 = coef[256 + 128];
  float eA   = ETA_*coef[127];
  float e128 = ETA_*coef[128 + 127];
  #pragma unroll
  for (int k = 0; k < 8; k++) {
    long idx = (long)(d0+dd)*W_ + hb + k*8 + le;
    float Po = Pb[idx], Mo = Mb[idx];
    Pb[idx] = b128*Po + eA*Mo + accP[k];
    Mb[idx] = e128*Mo + accM[k];
  }
}

// ------- fused K/V/Q projection -------
__global__ __launch_bounds__(256) void k_gemmkvq(
    const float* __restrict__ A,
    const float* __restrict__ Wk, const float* __restrict__ bk,
    const float* __restrict__ Wv, const float* __restrict__ bv,
    const float* __restrict__ Wq, const float* __restrict__ bq,
    float* __restrict__ KMo, float* __restrict__ VMo, float* __restrict__ Q1o)
{
  __shared__ float As[16][132];
  __shared__ float Bs[16][132];
  int bx = blockIdx.x;
  int sel = bx >> 3;
  int c0 = (bx & 7) * 128;
  int m0 = blockIdx.y * 128;
  const float* Bm   = sel == 0 ? Wk : sel == 1 ? Wv : Wq;
  const float* bias = sel == 0 ? bk : sel == 1 ? bv : bq;
  float* C          = sel == 0 ? KMo : sel == 1 ? VMo : Q1o;
  int tid = threadIdx.x;
  int tx = tid & 15, ty = tid >> 4;
  int ar = tid >> 1, ak = (tid & 1) * 8;
  int bkr = tid >> 4, bn = (tid & 15) * 8;
  float acc[8][8] = {};
  for (int k0 = 0; k0 < D_; k0 += 16) {
    {
      const float* ap = A + (long)(m0+ar)*D_ + k0 + ak;
      float4 v0 = *(const float4*)(ap);
      float4 v1 = *(const float4*)(ap+4);
      As[ak+0][ar]=v0.x; As[ak+1][ar]=v0.y; As[ak+2][ar]=v0.z; As[ak+3][ar]=v0.w;
      As[ak+4][ar]=v1.x; As[ak+5][ar]=v1.y; As[ak+6][ar]=v1.z; As[ak+7][ar]=v1.w;
      const float* bp = Bm + (long)(k0+bkr)*D_ + c0 + bn;
      *(float4*)(&Bs[bkr][bn])   = *(const float4*)(bp);
      *(float4*)(&Bs[bkr][bn+4]) = *(const float4*)(bp+4);
    }
    __syncthreads();
    #pragma unroll
    for (int kk = 0; kk < 16; kk++) {
      float av[8], bv8[8];
      #pragma unroll
      for (int i=0;i<8;i++) av[i] = As[kk][ty*8+i];
      #pragma unroll
      for (int j=0;j<8;j++) bv8[j] = Bs[kk][tx*8+j];
      #pragma unroll
      for (int i=0;i<8;i++)
        #pragma unroll
        for (int j=0;j<8;j++)
          acc[i][j] = fmaf(av[i], bv8[j], acc[i][j]);
    }
    __syncthreads();
  }
  #pragma unroll
  for (int i=0;i<8;i++) {
    int row = m0 + ty*8 + i;
    #pragma unroll
    for (int j=0;j<8;j++) acc[i][j] += bias[c0 + tx*8 + j];
    *(float4*)(C + (long)row*D_ + c0 + tx*8)     = make_float4(acc[i][0],acc[i][1],acc[i][2],acc[i][3]);
    *(float4*)(C + (long)row*D_ + c0 + tx*8 + 4) = make_float4(acc[i][4],acc[i][5],acc[i][6],acc[i][7]);
  }
}

__global__ void k_mul(const float* __restrict__ so, const float* __restrict__ mo,
                      float* __restrict__ outs, int s)
{
  int l = blockIdx.x, b = blockIdx.y, tid = threadIdx.x;
  long src = ((long)b*SEG_ + l)*D_ + tid*4;
  float4 a = *(const float4*)(so + src);
  float4 c = *(const float4*)(mo + src);
  a.x*=c.x; a.y*=c.y; a.z*=c.z; a.w*=c.w;
  *(float4*)(outs + ((long)b*N_ + s*SEG_ + l)*D_ + tid*4) = a;
}

// ---------------- host launcher ----------------
static inline void gemm(const float* A, const float* Bm, const float* bias, float* C,
                        int M, int N, int K, long sA, long sB, long sC, long sBias,
                        int batch, int bt, int silu_, hipStream_t st)
{
  dim3 g(N/64, (M+63)/64, batch), blk(256);
  if (!bt && !silu_) k_gemm<0,0><<<g,blk,0,st>>>(A,Bm,bias,C,M,N,K,sA,sB,sC,sBias);
  else if (!bt && silu_) k_gemm<0,1><<<g,blk,0,st>>>(A,Bm,bias,C,M,N,K,sA,sB,sC,sBias);
  else k_gemm<1,0><<<g,blk,0,st>>>(A,Bm,bias,C,M,N,K,sA,sB,sC,sBias);
}

extern "C" void kernel_launch(void* const* d_in, const int* in_sizes, int n_in,
                              void* d_out, int out_size, void* d_ws, size_t ws_size,
                              hipStream_t stream)
{
  (void)in_sizes; (void)n_in; (void)out_size; (void)ws_size;
  const int*   x     = (const int*)  d_in[0];
  const float* emb   = (const float*)d_in[1];
  const float* pers  = (const float*)d_in[2];
  const float* Wq    = (const float*)d_in[3];
  const float* bq    = (const float*)d_in[4];
  const float* Wk    = (const float*)d_in[5];
  const float* bk    = (const float*)d_in[6];
  const float* Wv    = (const float*)d_in[7];
  const float* bv    = (const float*)d_in[8];
  const float* aiw   = (const float*)d_in[9];
  const float* aib   = (const float*)d_in[10];
  const float* aow   = (const float*)d_in[11];
  const float* aob   = (const float*)d_in[12];
  const float* mW1in = (const float*)d_in[13];
  const float* mb1in = (const float*)d_in[14];
  const float* mW2in = (const float*)d_in[15];
  const float* mb2in = (const float*)d_in[16];
  const float* headw = (const float*)d_in[17];
  const float* headb = (const float*)d_in[18];
  float* out = (float*)d_out;
  float* ws  = (float*)d_ws;

  hipMemsetAsync(ws + MOM, 0, MOMSZ*sizeof(float), stream);
  hipMemsetAsync(ws + ZEROB, 0, 128*sizeof(float), stream);
  hipMemsetAsync(ws + CBAR, 0, (size_t)B_*NB2_*FSTR_*sizeof(int), stream);
  k_embed<<<dim3(B_*N_), dim3(256), 0, stream>>>(x, emb, ws+XEMB);
  k_init<<<dim3((2*PER_+255)/256), dim3(256), 0, stream>>>(
      mW1in, mb1in, mW2in, mb2in, ws+PW1, ws+PB1, ws+PW2T, ws+PB2);
  k_coef<<<dim3(1), dim3(64), 0, stream>>>(ws+COEF);

  for (int s = 0; s < NSEG_; s++) {
    const float* segA = ws + XEMB + (size_t)s*SEG_*D_;
    // h = mlp(p, l2n(seg @ Wq + bq))
    gemm(segA, Wq, bq, ws+Q1, SEG_, D_, D_, (long)N_*D_, 0, (long)SEG_*D_, 0, B_, 0, 0, stream);
    k_l2n<<<dim3(B_*SEG_), dim3(256), 0, stream>>>(ws+Q1);
    gemm(ws+Q1, ws+PW1, ws+PB1, ws+AH, SEG_, W_, D_, (long)SEG_*D_, (long)D_*W_, (long)SEG_*W_, W_, B_, 0, 1, stream);
    gemm(ws+AH, ws+PW2T, ws+PB2, ws+HBUF, SEG_, D_, W_, (long)SEG_*W_, (long)D_*W_, (long)SEG_*D_, D_, B_, 1, 0, stream);
    // attention
    k_concat<<<dim3(T_, B_), dim3(256), 0, stream>>>(pers, ws+HBUF, ws+XEMB, s, ws+COMB);
    k_gemm128<<<dim3(3*D_/128, (B_*T_+127)/128), dim3(256), 0, stream>>>(
        ws+COMB, aiw, aib, ws+QKV, B_*T_, 3*D_, D_);
    k_attn<<<dim3(8, NH_, B_), dim3(256), 0, stream>>>(ws+QKV, ws+ATTN);
    gemm(ws+ATTN, aow, aob, ws+SEGO, B_*SEG_, D_, D_, 0, 0, 0, 0, 1, 0, 0, stream);
    // fused K/V/Q projections of seg_out
    k_gemmkvq<<<dim3(24, 2), dim3(256), 0, stream>>>(
        ws+SEGO, Wk, bk, Wv, bv, Wq, bq, ws+KM, ws+VM, ws+Q1);
    k_l2n<<<dim3(B_*SEG_), dim3(256), 0, stream>>>(ws+KM);
    k_l2n<<<dim3(B_*SEG_), dim3(256), 0, stream>>>(ws+Q1);
    // scan precompute: {Q1K, Q1Km} fused; G = K@K^T
    k_gemm2<<<dim3(2, 2, B_), dim3(256), 0, stream>>>(
        ws+KM, ws+PW1, ws+MW1, ws+AQ1K, ws+AQ1KM,
        D_, (long)SEG_*D_, (long)D_*W_, (long)SEG_*W_);
    gemm(ws+KM, ws+KM,  ws+ZEROB, ws+AGRAM, SEG_, SEG_, D_, (long)SEG_*D_, (long)SEG_*D_, (long)SEG_*SEG_, 0, B_, 1, 0, stream);
    // the scan (one barrier per token)
    k_scan<<<dim3(NB2_, B_), dim3(256), 0, stream>>>(
        ws+PW2T, ws+MW2T, ws+PB1, ws+MB1, ws+PB2, ws+MB2, ws+VM,
        ws+AQ1K, ws+AQ1KM, ws+AGRAM,
        ws+ADZ1, ws+AA1H, ws+AEH,
        ws+AEXR, ws+AEXEE,
        ws+COEF, (int*)(ws+CBAR), s);
    // reconstruct weights/momenta
    k_recon<<<dim3(32, 2, 4), dim3(256), 0, stream>>>(
        ws+PW1, ws+MW1, ws+PW2T, ws+MW2T,
        ws+KM, ws+AEH, ws+ADZ1, ws+AA1H, ws+COEF);
    // mem_out = mlp(p_new, Q1)
    gemm(ws+Q1, ws+PW1, ws+PB1, ws+AH, SEG_, W_, D_, (long)SEG_*D_, (long)D_*W_, (long)SEG_*W_, W_, B_, 0, 1, stream);
    gemm(ws+AH, ws+PW2T, ws+PB2, ws+MEMO, SEG_, D_, W_, (long)SEG_*W_, (long)D_*W_, (long)SEG_*D_, D_, B_, 1, 0, stream);
    k_mul<<<dim3(SEG_, B_), dim3(256), 0, stream>>>(ws+SEGO, ws+MEMO, ws+OUTS, s);
  }
  // head via bf16-split MFMA
  k_head_mfma<<<dim3(V_/128, (B_*N_)/128), dim3(256), 0, stream>>>(
      ws+OUTS, headw, headb, out, B_*N_, V_, D_);
}

// Round 10
// 7426.102 us; speedup vs baseline: 1.7510x; 1.1450x over previous
//
#include <hip/hip_runtime.h>
#include <math.h>

#define D_    1024
#define B_    2
#define N_    512
#define SEG_  128
#define NSEG_ 4
#define NPT_  16
#define T_    272
#define NH_   16
#define HD_   64
#define W_    128
#define V_    32000

#define THETA_ 0.1f
#define ETA_   0.9f
#define PDEC_  0.99f
#define EPSN_  1e-6f
#define NB2_  32
#define FSTR_ 32

typedef __bf16 bf16x8 __attribute__((ext_vector_type(8)));
typedef float  f32x4  __attribute__((ext_vector_type(4)));

// ---------------- workspace layout (float offsets) ----------------
static const size_t XEMB = 0;
static const size_t OUTS = XEMB + (size_t)B_*N_*D_;
static const size_t PW1  = OUTS + (size_t)B_*N_*D_;
static const size_t PB1  = PW1  + (size_t)B_*D_*W_;
static const size_t PW2T = PB1  + (size_t)B_*W_;
static const size_t PB2  = PW2T + (size_t)B_*D_*W_;
static const size_t MOM  = PB2  + (size_t)B_*D_;
static const size_t MW1  = MOM;
static const size_t MB1  = MW1  + (size_t)B_*D_*W_;
static const size_t MW2T = MB1  + (size_t)B_*W_;
static const size_t MB2  = MW2T + (size_t)B_*D_*W_;
static const size_t MOMSZ = (size_t)B_*(D_*W_ + W_ + D_*W_ + D_);
static const size_t Q1   = MOM  + MOMSZ;
static const size_t AH   = Q1   + (size_t)B_*SEG_*D_;
static const size_t HBUF = AH   + (size_t)B_*SEG_*W_;
static const size_t COMB = HBUF + (size_t)B_*SEG_*D_;
static const size_t QKV  = COMB + (size_t)B_*T_*D_;
static const size_t ATTN = QKV  + (size_t)B_*T_*3*D_;
static const size_t SEGO = ATTN + (size_t)B_*SEG_*D_;
static const size_t KM   = SEGO + (size_t)B_*SEG_*D_;
static const size_t VM   = KM   + (size_t)B_*SEG_*D_;
static const size_t MEMO = VM   + (size_t)B_*SEG_*D_;
static const size_t WSEND = MEMO + (size_t)B_*SEG_*D_;

// scan-phase buffers ALIAS the QKV region
static const size_t AQ1K  = QKV;
static const size_t AQ1KM = AQ1K  + 32768;
static const size_t AGRAM = AQ1KM + 32768;
static const size_t ADZ1  = AGRAM + 32768;
static const size_t AA1H  = ADZ1  + 32768;
static const size_t AEH   = AA1H  + 32768;
static const size_t AEXR  = AEH + (size_t)B_*SEG_*D_;
static const size_t AEXEE = AEXR + 16384;
// persistent tail
static const size_t COEF  = WSEND;
static const size_t ZEROB = COEF + 512;
static const size_t CBAR  = ZEROB + 128;

__device__ __forceinline__ float sigf(float x) { return 1.f/(1.f+expf(-x)); }

__device__ __forceinline__ void gstore(float* p, float v) {
  __hip_atomic_store(p, v, __ATOMIC_RELAXED, __HIP_MEMORY_SCOPE_AGENT);
}
__device__ __forceinline__ float gload(const float* p) {
  return __hip_atomic_load(p, __ATOMIC_RELAXED, __HIP_MEMORY_SCOPE_AGENT);
}

// RNE bf16 split: a ≈ float(h) + float(l)
__device__ __forceinline__ void bsplit(float a, short& h, short& l) {
  unsigned u = __builtin_bit_cast(unsigned, a);
  unsigned hb = (u + 0x7fffu + ((u >> 16) & 1u)) >> 16;
  h = (short)hb;
  float hf = __builtin_bit_cast(float, hb << 16);
  float r = a - hf;
  unsigned ur = __builtin_bit_cast(unsigned, r);
  unsigned lb = (ur + 0x7fffu + ((ur >> 16) & 1u)) >> 16;
  l = (short)lb;
}

// ---------------- generic tiled fp32 GEMM (64x64) ----------------
template<int BT, int SILU>
__global__ __launch_bounds__(256) void k_gemm(
    const float* __restrict__ A, const float* __restrict__ Bm,
    const float* __restrict__ bias, float* __restrict__ C,
    int M, int N, int K, long sA, long sB, long sC, long sBias)
{
  __shared__ float As[16][68];
  __shared__ float Bs[16][68];
  int bz = blockIdx.z;
  A += bz*sA; Bm += bz*sB; C += bz*sC; bias += bz*sBias;
  int n0 = blockIdx.x*64, m0 = blockIdx.y*64;
  int tid = threadIdx.x;
  int tx = tid & 15, ty = tid >> 4;
  int r  = tid >> 2;
  int kq = (tid & 3) * 4;
  float acc[4][4] = {};
  for (int k0 = 0; k0 < K; k0 += 16) {
    {
      int row = m0 + r;
      float4 v = make_float4(0.f,0.f,0.f,0.f);
      if (row < M) v = *(const float4*)(A + (long)row*K + k0 + kq);
      As[kq+0][r]=v.x; As[kq+1][r]=v.y; As[kq+2][r]=v.z; As[kq+3][r]=v.w;
    }
    if (BT) {
      int row = n0 + r;
      float4 v = *(const float4*)(Bm + (long)row*K + k0 + kq);
      Bs[kq+0][r]=v.x; Bs[kq+1][r]=v.y; Bs[kq+2][r]=v.z; Bs[kq+3][r]=v.w;
    } else {
      int c = tid & 63, r4 = tid >> 6;
      #pragma unroll
      for (int p = 0; p < 4; p++) {
        int kk = r4 + p*4;
        Bs[kk][c] = Bm[(long)(k0+kk)*N + n0 + c];
      }
    }
    __syncthreads();
    #pragma unroll
    for (int kk = 0; kk < 16; kk++) {
      float av[4], bv[4];
      #pragma unroll
      for (int i=0;i<4;i++) av[i] = As[kk][ty*4+i];
      #pragma unroll
      for (int j=0;j<4;j++) bv[j] = Bs[kk][tx*4+j];
      #pragma unroll
      for (int i=0;i<4;i++)
        #pragma unroll
        for (int j=0;j<4;j++)
          acc[i][j] = fmaf(av[i], bv[j], acc[i][j]);
    }
    __syncthreads();
  }
  #pragma unroll
  for (int i=0;i<4;i++) {
    int row = m0 + ty*4 + i;
    if (row >= M) continue;
    #pragma unroll
    for (int j=0;j<4;j++) {
      int col = n0 + tx*4 + j;
      float v = acc[i][j] + bias[col];
      if (SILU) v = v * sigf(v);
      C[(long)row*N + col] = v;
    }
  }
}

// ------- dual-output 64x64 GEMM: C1=A@B1, C2=A@B2 (no bias) ----
__global__ __launch_bounds__(256) void k_gemm2(
    const float* __restrict__ A, const float* __restrict__ B1,
    const float* __restrict__ B2, float* __restrict__ C1, float* __restrict__ C2,
    int K, long sA, long sB, long sC)
{
  __shared__ float As[16][68];
  __shared__ float B1s[16][68];
  __shared__ float B2s[16][68];
  int bz = blockIdx.z;
  A += bz*sA; B1 += bz*sB; B2 += bz*sB; C1 += bz*sC; C2 += bz*sC;
  int n0 = blockIdx.x*64, m0 = blockIdx.y*64;
  int tid = threadIdx.x;
  int tx = tid & 15, ty = tid >> 4;
  int r  = tid >> 2;
  int kq = (tid & 3) * 4;
  float acc1[4][4] = {}, acc2[4][4] = {};
  for (int k0 = 0; k0 < K; k0 += 16) {
    {
      float4 v = *(const float4*)(A + (long)(m0+r)*K + k0 + kq);
      As[kq+0][r]=v.x; As[kq+1][r]=v.y; As[kq+2][r]=v.z; As[kq+3][r]=v.w;
    }
    {
      int c = tid & 63, r4 = tid >> 6;
      #pragma unroll
      for (int p = 0; p < 4; p++) {
        int kk = r4 + p*4;
        B1s[kk][c] = B1[(long)(k0+kk)*W_ + n0 + c];
        B2s[kk][c] = B2[(long)(k0+kk)*W_ + n0 + c];
      }
    }
    __syncthreads();
    #pragma unroll
    for (int kk = 0; kk < 16; kk++) {
      float av[4], b1v[4], b2v[4];
      #pragma unroll
      for (int i=0;i<4;i++) av[i] = As[kk][ty*4+i];
      #pragma unroll
      for (int j=0;j<4;j++) { b1v[j] = B1s[kk][tx*4+j]; b2v[j] = B2s[kk][tx*4+j]; }
      #pragma unroll
      for (int i=0;i<4;i++)
        #pragma unroll
        for (int j=0;j<4;j++) {
          acc1[i][j] = fmaf(av[i], b1v[j], acc1[i][j]);
          acc2[i][j] = fmaf(av[i], b2v[j], acc2[i][j]);
        }
    }
    __syncthreads();
  }
  #pragma unroll
  for (int i=0;i<4;i++) {
    int row = m0 + ty*4 + i;
    #pragma unroll
    for (int j=0;j<4;j++) {
      int col = n0 + tx*4 + j;
      C1[(long)row*W_ + col] = acc1[i][j];
      C2[(long)row*W_ + col] = acc2[i][j];
    }
  }
}

// ------- generic bf16-split MFMA GEMM: C = A@B + bias (fp32 in/out) -------
// 128x128 tiles; M guarded; N mult of 128; K mult of 32; batch via grid.z.
__global__ __launch_bounds__(256) void k_gemm_mfma(
    const float* __restrict__ A, const float* __restrict__ Bm,
    const float* __restrict__ bias, float* __restrict__ C,
    int M, int N, int K, long sA, long sB, long sC, long sBias)
{
  __shared__ short Ah[128][48];
  __shared__ short Al[128][48];
  __shared__ short Bh[32][132];
  __shared__ short Bl[32][132];
  int bz = blockIdx.z;
  A += bz*sA; Bm += bz*sB; C += bz*sC; bias += bz*sBias;
  int n0 = blockIdx.x*128, m0 = blockIdx.y*128;
  int tid = threadIdx.x;
  int wave = tid >> 6, lane = tid & 63;
  int wm = (wave >> 1) * 64, wn = (wave & 1) * 64;
  int lrow = lane & 15, lk = (lane >> 4) * 8;
  int arow0 = min(m0 + (tid >> 1), M-1);
  f32x4 acc[4][4] = {};
  for (int k0 = 0; k0 < K; k0 += 32) {
    __syncthreads();
    {
      int r = tid >> 1, kq = (tid & 1) * 16;
      const float* ap = A + (long)arow0*K + k0 + kq;
      #pragma unroll
      for (int q = 0; q < 16; q += 4) {
        float4 v = *(const float4*)(ap + q);
        short h0,l0,h1,l1,h2,l2,h3,l3;
        bsplit(v.x,h0,l0); bsplit(v.y,h1,l1); bsplit(v.z,h2,l2); bsplit(v.w,h3,l3);
        *(short4*)&Ah[r][kq+q] = make_short4(h0,h1,h2,h3);
        *(short4*)&Al[r][kq+q] = make_short4(l0,l1,l2,l3);
      }
    }
    {
      int kr = tid >> 3, nq = (tid & 7) * 16;
      const float* bp = Bm + (long)(k0 + kr)*N + n0 + nq;
      #pragma unroll
      for (int q = 0; q < 16; q += 4) {
        float4 v = *(const float4*)(bp + q);
        short h0,l0,h1,l1,h2,l2,h3,l3;
        bsplit(v.x,h0,l0); bsplit(v.y,h1,l1); bsplit(v.z,h2,l2); bsplit(v.w,h3,l3);
        *(short4*)&Bh[kr][nq+q] = make_short4(h0,h1,h2,h3);
        *(short4*)&Bl[kr][nq+q] = make_short4(l0,l1,l2,l3);
      }
    }
    __syncthreads();
    bf16x8 bh[4], bl[4];
    #pragma unroll
    for (int nf = 0; nf < 4; nf++) {
      int col = wn + nf*16 + lrow;
      #pragma unroll
      for (int j = 0; j < 8; j++) {
        bh[nf][j] = __builtin_bit_cast(__bf16, Bh[lk+j][col]);
        bl[nf][j] = __builtin_bit_cast(__bf16, Bl[lk+j][col]);
      }
    }
    #pragma unroll
    for (int mf = 0; mf < 4; mf++) {
      int ar2 = wm + mf*16 + lrow;
      bf16x8 ah = *(const bf16x8*)&Ah[ar2][lk];
      bf16x8 al = *(const bf16x8*)&Al[ar2][lk];
      #pragma unroll
      for (int nf = 0; nf < 4; nf++) {
        acc[mf][nf] = __builtin_amdgcn_mfma_f32_16x16x32_bf16(ah, bh[nf], acc[mf][nf], 0, 0, 0);
        acc[mf][nf] = __builtin_amdgcn_mfma_f32_16x16x32_bf16(ah, bl[nf], acc[mf][nf], 0, 0, 0);
        acc[mf][nf] = __builtin_amdgcn_mfma_f32_16x16x32_bf16(al, bh[nf], acc[mf][nf], 0, 0, 0);
      }
    }
  }
  #pragma unroll
  for (int mf = 0; mf < 4; mf++) {
    #pragma unroll
    for (int nf = 0; nf < 4; nf++) {
      int col = n0 + wn + nf*16 + lrow;
      float bv = bias[col];
      #pragma unroll
      for (int j = 0; j < 4; j++) {
        int row = m0 + wm + mf*16 + (lane >> 4)*4 + j;
        if (row < M) C[(long)row*N + col] = acc[mf][nf][j] + bv;
      }
    }
  }
}

// ------- fused K/V/Q projection via bf16-split MFMA (M=256, per-matrix N=1024) ----
__global__ __launch_bounds__(256) void k_gemmkvq_m(
    const float* __restrict__ A,
    const float* __restrict__ Wk, const float* __restrict__ bk,
    const float* __restrict__ Wv, const float* __restrict__ bv,
    const float* __restrict__ Wq, const float* __restrict__ bq,
    float* __restrict__ KMo, float* __restrict__ VMo, float* __restrict__ Q1o)
{
  __shared__ short Ah[128][48];
  __shared__ short Al[128][48];
  __shared__ short Bh[32][132];
  __shared__ short Bl[32][132];
  int bx = blockIdx.x;
  int sel = bx >> 3;
  int n0 = (bx & 7) * 128;
  int m0 = blockIdx.y * 128;
  const float* Bm   = sel == 0 ? Wk : sel == 1 ? Wv : Wq;
  const float* bias = sel == 0 ? bk : sel == 1 ? bv : bq;
  float* C          = sel == 0 ? KMo : sel == 1 ? VMo : Q1o;
  int tid = threadIdx.x;
  int wave = tid >> 6, lane = tid & 63;
  int wm = (wave >> 1) * 64, wn = (wave & 1) * 64;
  int lrow = lane & 15, lk = (lane >> 4) * 8;
  f32x4 acc[4][4] = {};
  for (int k0 = 0; k0 < D_; k0 += 32) {
    __syncthreads();
    {
      int r = tid >> 1, kq = (tid & 1) * 16;
      const float* ap = A + (long)(m0 + r)*D_ + k0 + kq;
      #pragma unroll
      for (int q = 0; q < 16; q += 4) {
        float4 v = *(const float4*)(ap + q);
        short h0,l0,h1,l1,h2,l2,h3,l3;
        bsplit(v.x,h0,l0); bsplit(v.y,h1,l1); bsplit(v.z,h2,l2); bsplit(v.w,h3,l3);
        *(short4*)&Ah[r][kq+q] = make_short4(h0,h1,h2,h3);
        *(short4*)&Al[r][kq+q] = make_short4(l0,l1,l2,l3);
      }
    }
    {
      int kr = tid >> 3, nq = (tid & 7) * 16;
      const float* bp = Bm + (long)(k0 + kr)*D_ + n0 + nq;
      #pragma unroll
      for (int q = 0; q < 16; q += 4) {
        float4 v = *(const float4*)(bp + q);
        short h0,l0,h1,l1,h2,l2,h3,l3;
        bsplit(v.x,h0,l0); bsplit(v.y,h1,l1); bsplit(v.z,h2,l2); bsplit(v.w,h3,l3);
        *(short4*)&Bh[kr][nq+q] = make_short4(h0,h1,h2,h3);
        *(short4*)&Bl[kr][nq+q] = make_short4(l0,l1,l2,l3);
      }
    }
    __syncthreads();
    bf16x8 bh[4], bl[4];
    #pragma unroll
    for (int nf = 0; nf < 4; nf++) {
      int col = wn + nf*16 + lrow;
      #pragma unroll
      for (int j = 0; j < 8; j++) {
        bh[nf][j] = __builtin_bit_cast(__bf16, Bh[lk+j][col]);
        bl[nf][j] = __builtin_bit_cast(__bf16, Bl[lk+j][col]);
      }
    }
    #pragma unroll
    for (int mf = 0; mf < 4; mf++) {
      int ar2 = wm + mf*16 + lrow;
      bf16x8 ah = *(const bf16x8*)&Ah[ar2][lk];
      bf16x8 al = *(const bf16x8*)&Al[ar2][lk];
      #pragma unroll
      for (int nf = 0; nf < 4; nf++) {
        acc[mf][nf] = __builtin_amdgcn_mfma_f32_16x16x32_bf16(ah, bh[nf], acc[mf][nf], 0, 0, 0);
        acc[mf][nf] = __builtin_amdgcn_mfma_f32_16x16x32_bf16(ah, bl[nf], acc[mf][nf], 0, 0, 0);
        acc[mf][nf] = __builtin_amdgcn_mfma_f32_16x16x32_bf16(al, bh[nf], acc[mf][nf], 0, 0, 0);
      }
    }
  }
  #pragma unroll
  for (int mf = 0; mf < 4; mf++) {
    #pragma unroll
    for (int nf = 0; nf < 4; nf++) {
      int col = n0 + wn + nf*16 + lrow;
      float bvx = bias[col];
      #pragma unroll
      for (int j = 0; j < 4; j++) {
        int row = m0 + wm + mf*16 + (lane >> 4)*4 + j;
        C[(long)row*D_ + col] = acc[mf][nf][j] + bvx;
      }
    }
  }
}

// ------- head GEMM via bf16-split MFMA -------
__global__ __launch_bounds__(256) void k_head_mfma(
    const float* __restrict__ A, const float* __restrict__ Bm,
    const float* __restrict__ bias, float* __restrict__ C,
    int M, int N, int K)
{
  __shared__ short Ah[128][48];
  __shared__ short Al[128][48];
  __shared__ short Bh[32][132];
  __shared__ short Bl[32][132];
  int n0 = blockIdx.x*128, m0 = blockIdx.y*128;
  int tid = threadIdx.x;
  int wave = tid >> 6, lane = tid & 63;
  int wm = (wave >> 1) * 64, wn = (wave & 1) * 64;
  int lrow = lane & 15, lk = (lane >> 4) * 8;
  f32x4 acc[4][4] = {};
  for (int k0 = 0; k0 < K; k0 += 32) {
    __syncthreads();
    {
      int r = tid >> 1, kq = (tid & 1) * 16;
      const float* ap = A + (long)(m0 + r)*K + k0 + kq;
      #pragma unroll
      for (int q = 0; q < 16; q += 4) {
        float4 v = *(const float4*)(ap + q);
        short h0,l0,h1,l1,h2,l2,h3,l3;
        bsplit(v.x,h0,l0); bsplit(v.y,h1,l1); bsplit(v.z,h2,l2); bsplit(v.w,h3,l3);
        *(short4*)&Ah[r][kq+q] = make_short4(h0,h1,h2,h3);
        *(short4*)&Al[r][kq+q] = make_short4(l0,l1,l2,l3);
      }
    }
    {
      int kr = tid >> 3, nq = (tid & 7) * 16;
      const float* bp = Bm + (long)(k0 + kr)*N + n0 + nq;
      #pragma unroll
      for (int q = 0; q < 16; q += 4) {
        float4 v = *(const float4*)(bp + q);
        short h0,l0,h1,l1,h2,l2,h3,l3;
        bsplit(v.x,h0,l0); bsplit(v.y,h1,l1); bsplit(v.z,h2,l2); bsplit(v.w,h3,l3);
        *(short4*)&Bh[kr][nq+q] = make_short4(h0,h1,h2,h3);
        *(short4*)&Bl[kr][nq+q] = make_short4(l0,l1,l2,l3);
      }
    }
    __syncthreads();
    bf16x8 bh[4], bl[4];
    #pragma unroll
    for (int nf = 0; nf < 4; nf++) {
      int col = wn + nf*16 + lrow;
      #pragma unroll
      for (int j = 0; j < 8; j++) {
        bh[nf][j] = __builtin_bit_cast(__bf16, Bh[lk+j][col]);
        bl[nf][j] = __builtin_bit_cast(__bf16, Bl[lk+j][col]);
      }
    }
    #pragma unroll
    for (int mf = 0; mf < 4; mf++) {
      int arow2 = wm + mf*16 + lrow;
      bf16x8 ah = *(const bf16x8*)&Ah[arow2][lk];
      bf16x8 al = *(const bf16x8*)&Al[arow2][lk];
      #pragma unroll
      for (int nf = 0; nf < 4; nf++) {
        acc[mf][nf] = __builtin_amdgcn_mfma_f32_16x16x32_bf16(ah, bh[nf], acc[mf][nf], 0, 0, 0);
        acc[mf][nf] = __builtin_amdgcn_mfma_f32_16x16x32_bf16(ah, bl[nf], acc[mf][nf], 0, 0, 0);
        acc[mf][nf] = __builtin_amdgcn_mfma_f32_16x16x32_bf16(al, bh[nf], acc[mf][nf], 0, 0, 0);
      }
    }
  }
  #pragma unroll
  for (int mf = 0; mf < 4; mf++) {
    #pragma unroll
    for (int nf = 0; nf < 4; nf++) {
      int col = n0 + wn + nf*16 + lrow;
      float bv = bias[col];
      #pragma unroll
      for (int j = 0; j < 4; j++) {
        int row = m0 + wm + mf*16 + (lane >> 4)*4 + j;
        C[(long)row*N + col] = acc[mf][nf][j] + bv;
      }
    }
  }
}

// ---------------- small kernels ----------------
__global__ void k_embed(const int* __restrict__ x, const float* __restrict__ emb,
                        float* __restrict__ xe)
{
  int row = blockIdx.x, tid = threadIdx.x;
  int idx = x[row];
  float4 v = *(const float4*)(emb + (long)idx*D_ + tid*4);
  *(float4*)(xe + (long)row*D_ + tid*4) = v;
}

#define PER_ 263296L
__global__ void k_init(const float* __restrict__ mW1in, const float* __restrict__ mb1in,
                       const float* __restrict__ mW2in, const float* __restrict__ mb2in,
                       float* __restrict__ pW1, float* __restrict__ pb1,
                       float* __restrict__ pW2T, float* __restrict__ pb2)
{
  long g = (long)blockIdx.x*256 + threadIdx.x;
  if (g >= 2*PER_) return;
  int b = (int)(g / PER_);
  long rr = g % PER_;
  if (rr < 131072)       pW1[(long)b*131072 + rr] = mW1in[rr];
  else if (rr < 131200)  pb1[b*W_ + (rr-131072)] = mb1in[rr-131072];
  else if (rr < 262272) { long l = rr-131200; int j=(int)(l>>7), h=(int)(l&127);
                          pW2T[(long)b*131072 + l] = mW2in[(long)h*D_ + j]; }
  else                   pb2[b*D_ + (rr-262272)] = mb2in[rr-262272];
}

__global__ void k_coef(float* __restrict__ c)
{
  if (blockIdx.x == 0 && threadIdx.x == 0) {
    c[0] = 1.f; c[128] = 1.f;
    float A = 1.f, eta_d = 1.f;
    for (int d = 1; d < 128; d++) {
      eta_d *= ETA_;
      A = PDEC_*A + eta_d;
      c[d] = A;
      c[128 + d] = eta_d;
    }
    c[256] = 1.f;
    float bp = 1.f;
    for (int t = 1; t <= 128; t++) { bp *= PDEC_; c[256 + t] = bp; }
  }
}

__global__ __launch_bounds__(256) void k_l2n(float* __restrict__ X)
{
  long row = blockIdx.x;
  float* p = X + row*D_;
  int tid = threadIdx.x;
  float4 v = *(float4*)(p + tid*4);
  float ss = v.x*v.x + v.y*v.y + v.z*v.z + v.w*v.w;
  for (int o=32;o;o>>=1) ss += __shfl_xor(ss,o);
  __shared__ float wsum[4];
  if ((tid&63)==0) wsum[tid>>6] = ss;
  __syncthreads();
  float tot = wsum[0]+wsum[1]+wsum[2]+wsum[3];
  float sc = 1.f/(sqrtf(tot)+EPSN_);
  v.x*=sc; v.y*=sc; v.z*=sc; v.w*=sc;
  *(float4*)(p + tid*4) = v;
}

__global__ void k_concat(const float* __restrict__ pers, const float* __restrict__ h,
                         const float* __restrict__ xemb, int s, float* __restrict__ comb)
{
  int row = blockIdx.x, b = blockIdx.y, tid = threadIdx.x;
  const float* src;
  if (row < NPT_)            src = pers + (long)row*D_;
  else if (row < NPT_+SEG_)  src = h    + ((long)b*SEG_ + (row-NPT_))*D_;
  else                       src = xemb + ((long)b*N_ + s*SEG_ + (row-NPT_-SEG_))*D_;
  float4 v = *(const float4*)(src + tid*4);
  *(float4*)(comb + ((long)b*T_ + row)*D_ + tid*4) = v;
}

__global__ __launch_bounds__(256) void k_attn(const float* __restrict__ qkv,
                                              float* __restrict__ outp)
{
  __shared__ float sQ[16][68];
  __shared__ float sKV[64][68];
  __shared__ float sS[16][273];
  int qt = blockIdx.x, head = blockIdx.y, b = blockIdx.z;
  int tid = threadIdx.x;
  const float* base = qkv + (long)b*T_*3*D_;
  int qoff = head*HD_, koff = D_ + head*HD_, voff = 2*D_ + head*HD_;
  int qrow0 = NPT_ + SEG_ + qt*16;
  {
    int rr = tid>>4, c4 = (tid&15)*4;
    float4 v = *(const float4*)(base + (long)(qrow0+rr)*3*D_ + qoff + c4);
    sQ[rr][c4]=v.x; sQ[rr][c4+1]=v.y; sQ[rr][c4+2]=v.z; sQ[rr][c4+3]=v.w;
  }
  __syncthreads();
  for (int j0 = 0; j0 < T_; j0 += 64) {
    int chunk = min(64, T_ - j0);
    {
      int jj = tid>>2, cq = (tid&3)*16;
      if (jj < chunk) {
        #pragma unroll
        for (int q4=0;q4<4;q4++) {
          float4 v = *(const float4*)(base + (long)(j0+jj)*3*D_ + koff + cq + q4*4);
          sKV[jj][cq+q4*4]=v.x; sKV[jj][cq+q4*4+1]=v.y; sKV[jj][cq+q4*4+2]=v.z; sKV[jj][cq+q4*4+3]=v.w;
        }
      }
    }
    __syncthreads();
    int rr = tid>>4, jj0 = tid&15;
    #pragma unroll
    for (int p=0;p<4;p++) {
      int jj = jj0 + p*16;
      if (jj < chunk) {
        float s = 0.f;
        #pragma unroll 8
        for (int c=0;c<HD_;c++) s = fmaf(sQ[rr][c], sKV[jj][c], s);
        s *= 0.125f;
        int jg = j0 + jj, qg = qrow0 + rr;
        if (jg > qg) s = -3.0e38f;
        sS[rr][jg] = s;
      }
    }
    __syncthreads();
  }
  {
    int rr = tid>>4, l16 = tid&15;
    float m = -3.4e38f;
    for (int j=l16; j<T_; j+=16) m = fmaxf(m, sS[rr][j]);
    for (int o=8;o;o>>=1) m = fmaxf(m, __shfl_xor(m,o));
    float sum = 0.f;
    for (int j=l16; j<T_; j+=16) { float e = expf(sS[rr][j]-m); sS[rr][j] = e; sum += e; }
    for (int o=8;o;o>>=1) sum += __shfl_xor(sum,o);
    float inv = 1.f/sum;
    for (int j=l16; j<T_; j+=16) sS[rr][j] *= inv;
  }
  __syncthreads();
  float acc[4] = {0.f,0.f,0.f,0.f};
  int rr = tid>>4, c4 = (tid&15)*4;
  for (int j0 = 0; j0 < T_; j0 += 64) {
    int chunk = min(64, T_ - j0);
    {
      int jj = tid>>2, cq = (tid&3)*16;
      if (jj < chunk) {
        #pragma unroll
        for (int q4=0;q4<4;q4++) {
          float4 v = *(const float4*)(base + (long)(j0+jj)*3*D_ + voff + cq + q4*4);
          sKV[jj][cq+q4*4]=v.x; sKV[jj][cq+q4*4+1]=v.y; sKV[jj][cq+q4*4+2]=v.z; sKV[jj][cq+q4*4+3]=v.w;
        }
      }
    }
    __syncthreads();
    for (int jj=0; jj<chunk; jj++) {
      float p = sS[rr][j0+jj];
      #pragma unroll
      for (int i=0;i<4;i++) acc[i] = fmaf(p, sKV[jj][c4+i], acc[i]);
    }
    __syncthreads();
  }
  float4 o4 = make_float4(acc[0],acc[1],acc[2],acc[3]);
  *(float4*)(outp + ((long)(b*SEG_) + qt*16 + rr)*D_ + head*HD_ + c4) = o4;
}

// ------- fence-free flag barrier ---------
__device__ __forceinline__ void gbar(int* flags, int blk, int gen)
{
  asm volatile("s_waitcnt vmcnt(0) lgkmcnt(0)" ::: "memory");
  __syncthreads();
  if (threadIdx.x == 0)
    __hip_atomic_store(flags + blk*FSTR_, gen, __ATOMIC_RELAXED, __HIP_MEMORY_SCOPE_AGENT);
  if (threadIdx.x < NB2_) {
    while (__hip_atomic_load(flags + threadIdx.x*FSTR_, __ATOMIC_RELAXED,
                             __HIP_MEMORY_SCOPE_AGENT) < gen)
      __builtin_amdgcn_s_sleep(1);
  }
  __syncthreads();
}

// ---- persistent token-space scan: full-h replicated, j 32-sliced, 1 barrier,
// ---- W2/mW2 slices REGISTER-RESIDENT for the whole segment.
__global__ __launch_bounds__(256) void k_scan(
  const float* __restrict__ pW2T, const float* __restrict__ mW2T,
  float* __restrict__ pb1, float* __restrict__ mb1,
  float* __restrict__ pb2, float* __restrict__ mb2,
  const float* __restrict__ Vm,
  const float* __restrict__ q1k, const float* __restrict__ q1km,
  const float* __restrict__ G,
  float* __restrict__ dz1o, float* __restrict__ a1o, float* __restrict__ eo,
  float* __restrict__ exR, float* __restrict__ exEE,
  const float* __restrict__ coef, int* __restrict__ barbase, int seg)
{
  __shared__ float sDZ[128][129];
  __shared__ float sA1[128][129];
  __shared__ float sEh[128][33];
  __shared__ float sB1[128], sMB1[128], sZ1[128], sR[128];
  __shared__ float sB2[32], sMB2[32];
  __shared__ float sAt[128];
  __shared__ float sBp[129];
  __shared__ float sGc[128];
  __shared__ float sS[128];
  __shared__ float sEEc[128];

  int b = blockIdx.y, blk = blockIdx.x, tid = threadIdx.x;
  int j0 = blk*32;
  int* flags = barbase + b*(NB2_*FSTR_);
  int gbase = seg*200;
  const float* W0 = pW2T + (long)b*131072;
  const float* Wm = mW2T + (long)b*131072;

  // register-resident W for phase D access pattern (j = tid>>3, h = l + 8k)
  int jD = tid >> 3, lD = tid & 7;
  float rD0[16], rDm[16];
  #pragma unroll
  for (int k = 0; k < 16; k++) {
    rD0[k] = W0[(long)(j0+jD)*128 + lD + 8*k];
    rDm[k] = Wm[(long)(j0+jD)*128 + lD + 8*k];
  }
  // register-resident W for phase E pattern (h = tid>>1, jj = half*16 + q)
  int hE = tid >> 1, halfE = tid & 1;
  float rE0[16], rEm[16];
  #pragma unroll
  for (int q = 0; q < 16; q++) {
    rE0[q] = W0[(long)(j0 + halfE*16 + q)*128 + hE];
    rEm[q] = Wm[(long)(j0 + halfE*16 + q)*128 + hE];
  }

  if (tid < 128) { sAt[tid] = coef[tid]; sB1[tid] = pb1[b*W_+tid]; sMB1[tid] = mb1[b*W_+tid]; }
  else if (tid < 160) { int j = tid-128; sB2[j] = pb2[b*D_+j0+j]; sMB2[j] = mb2[b*D_+j0+j]; }
  for (int i = tid; i < 129; i += 256) sBp[i] = coef[256+i];
  __syncthreads();

  for (int t = 0; t < SEG_; ++t) {
    int par = t & 1;
    float bp = sBp[t];
    float ca = (t>0) ? ETA_*sAt[t-1] : 0.f;

    // ---- A: bias recurrences, G-row prescale, q1k loads ----
    float rq1k = 0.f, rq1km = 0.f;
    if (tid < 128) {
      rq1k  = q1k [((long)b*SEG_+t)*W_ + tid];
      rq1km = q1km[((long)b*SEG_+t)*W_ + tid];
      if (t > 0) {
        float mm = ETA_*sMB1[tid] - THETA_*sDZ[t-1][tid];
        sMB1[tid] = mm; sB1[tid] = PDEC_*sB1[tid] + mm;
      }
      if (tid < t) sGc[tid] = sAt[t-1-tid]*G[((long)b*SEG_+t)*SEG_ + tid];
    } else if (tid < 160) {
      int j = tid-128;
      if (t > 0) {
        float mm = ETA_*sMB2[j] - 2.f*THETA_*sEh[t-1][j];
        sMB2[j] = mm; sB2[j] = PDEC_*sB2[j] + mm;
      }
    }
    __syncthreads();

    // ---- B: z1/a1 for ALL h ----
    if (tid < 128) {
      float acc = 0.f;
      for (int u = 0; u < t; ++u) acc = fmaf(sGc[u], sDZ[u][tid], acc);
      float z1 = bp*rq1k + ca*rq1km + sB1[tid] - THETA_*acc;
      sZ1[tid] = z1;
      sA1[t][tid] = z1 * sigf(z1);
    }
    __syncthreads();

    // ---- C: sS scalars from in-block a1 Gram ----
    if (tid < t) {
      float acc = 0.f;
      #pragma unroll 8
      for (int h = 0; h < 128; ++h) acc = fmaf(sA1[tid][h], sA1[t][h], acc);
      sS[tid] = -2.f*THETA_*sAt[t-1-tid]*acc;
    }
    __syncthreads();

    // ---- D: e slice (W in registers) ----
    {
      float g = 0.f, gm = 0.f;
      #pragma unroll
      for (int k = 0; k < 16; k++) {
        float a = sA1[t][lD + 8*k];
        g  = fmaf(rD0[k], a, g);
        gm = fmaf(rDm[k], a, gm);
      }
      float corr = 0.f;
      for (int u = lD; u < t; u += 8) corr = fmaf(sS[u], sEh[u][jD], corr);
      float tot = bp*g + ca*gm + corr;
      tot += __shfl_xor(tot,4); tot += __shfl_xor(tot,2); tot += __shfl_xor(tot,1);
      if (lD == 0) sEh[t][jD] = tot + sB2[jD] - Vm[((long)b*SEG_+t)*D_ + j0+jD];
    }
    __syncthreads();

    // ---- E: r partials (W in registers) + ee partials ----
    {
      float racc = 0.f;
      #pragma unroll
      for (int q = 0; q < 16; ++q) {
        float w = bp*rE0[q] + ca*rEm[q];
        racc = fmaf(w, sEh[t][halfE*16 + q], racc);
      }
      racc += __shfl_xor(racc,1);
      if (halfE == 0) gstore(&exR[(((long)par*B_ + b)*NB2_ + blk)*W_ + hE], racc);
      if (hE < t) {
        float eacc = 0.f;
        #pragma unroll
        for (int q = 0; q < 16; ++q)
          eacc = fmaf(sEh[hE][halfE*16 + q], sEh[t][halfE*16 + q], eacc);
        eacc += __shfl_xor(eacc,1);
        if (halfE == 0) gstore(&exEE[(((long)par*B_ + b)*NB2_ + blk)*W_ + hE], eacc);
      }
    }
    gbar(flags, blk, gbase + t + 1);

    // ---- F: gather r/ee, dz1 full-h ----
    {
      float racc = 0.f;
      #pragma unroll
      for (int k = 0; k < 16; ++k)
        racc += gload(&exR[(((long)par*B_ + b)*NB2_ + halfE*16 + k)*W_ + hE]);
      racc += __shfl_xor(racc,1);
      if (halfE == 0) sR[hE] = racc;
      if (hE < t) {
        float eacc = 0.f;
        #pragma unroll
        for (int k = 0; k < 16; ++k)
          eacc += gload(&exEE[(((long)par*B_ + b)*NB2_ + halfE*16 + k)*W_ + hE]);
        eacc += __shfl_xor(eacc,1);
        if (halfE == 0) sEEc[hE] = -2.f*THETA_*sAt[t-1-hE]*eacc;
      }
    }
    __syncthreads();
    if (tid < 128) {
      float macc = 0.f;
      for (int u = 0; u < t; ++u) macc = fmaf(sEEc[u], sA1[u][tid], macc);
      float z = sZ1[tid], sg = sigf(z);
      sDZ[t][tid] = 2.f*(sR[tid] + macc)*sg*(1.f + z*(1.f - sg));
    }
    __syncthreads();
  }

  // ---- epilogue ----
  if (tid < 128) {
    if (blk == 0) {
      float mm = ETA_*sMB1[tid] - THETA_*sDZ[127][tid];
      mb1[b*W_ + tid] = mm;
      pb1[b*W_ + tid] = PDEC_*sB1[tid] + mm;
    }
  } else if (tid < 160) {
    int j = tid-128;
    float mm = ETA_*sMB2[j] - 2.f*THETA_*sEh[127][j];
    mb2[b*D_ + j0+j] = mm;
    pb2[b*D_ + j0+j] = PDEC_*sB2[j] + mm;
  }
  for (int i = tid; i < 128*4; i += 256) {
    int t2 = i >> 2, hh = (i & 3) + blk*4;
    dz1o[((long)b*SEG_+t2)*W_ + hh] = sDZ[t2][hh];
    a1o [((long)b*SEG_+t2)*W_ + hh] = sA1[t2][hh];
  }
  for (int i = tid; i < 128*32; i += 256) {
    int t2 = i >> 5, jj = i & 31;
    eo[((long)b*SEG_+t2)*D_ + j0+jj] = sEh[t2][jj];
  }
}

// ---------------- weight/momentum reconstruction --------------------------
__global__ __launch_bounds__(256) void k_recon(
  float* __restrict__ pW1, float* __restrict__ mW1,
  float* __restrict__ pW2T, float* __restrict__ mW2T,
  const float* __restrict__ KMp, const float* __restrict__ Eh,
  const float* __restrict__ DZ1, const float* __restrict__ A1h,
  const float* __restrict__ coef)
{
  __shared__ float s1[16][33];
  __shared__ float s2[16][65];
  __shared__ float sCA[128], sCE[128];
  int dt = blockIdx.x, ht = blockIdx.y, kb = blockIdx.z;
  int kind = kb >> 1, b = kb & 1;
  int tid = threadIdx.x;
  int d0 = dt*32, hb = ht*64;
  const float* in1 = (kind ? Eh : KMp) + (long)b*SEG_*D_;
  const float* in2 = (kind ? A1h : DZ1) + (long)b*SEG_*W_;
  float* Pb = (kind ? pW2T : pW1) + (long)b*131072;
  float* Mb = (kind ? mW2T : mW1) + (long)b*131072;
  float f = kind ? -2.f*THETA_ : -THETA_;
  if (tid < 128) {
    sCA[tid] = f*coef[127 - tid];
    sCE[tid] = f*coef[128 + 127 - tid];
  }
  __syncthreads();
  int dd = tid >> 3, le = tid & 7;
  float accP[8] = {}, accM[8] = {};
  for (int u0 = 0; u0 < 128; u0 += 16) {
    for (int i = tid; i < 16*32; i += 256) {
      int uu = i >> 5, d2 = i & 31;
      s1[uu][d2] = in1[(long)(u0+uu)*D_ + d0 + d2];
    }
    for (int i = tid; i < 16*64; i += 256) {
      int uu = i >> 6, hl = i & 63;
      s2[uu][hl] = in2[(long)(u0+uu)*W_ + hb + hl];
    }
    __syncthreads();
    #pragma unroll
    for (int uu = 0; uu < 16; uu++) {
      float a = s1[uu][dd];
      float cAu = sCA[u0+uu], cEu = sCE[u0+uu];
      #pragma unroll
      for (int k = 0; k < 8; k++) {
        float v = a * s2[uu][k*8 + le];
        accP[k] = fmaf(cAu, v, accP[k]);
        accM[k] = fmaf(cEu, v, accM[k]);
      }
    }
    __syncthreads();
  }
  float b128 = coef[256 + 128];
  float eA   = ETA_*coef[127];
  float e128 = ETA_*coef[128 + 127];
  #pragma unroll
  for (int k = 0; k < 8; k++) {
    long idx = (long)(d0+dd)*W_ + hb + k*8 + le;
    float Po = Pb[idx], Mo = Mb[idx];
    Pb[idx] = b128*Po + eA*Mo + accP[k];
    Mb[idx] = e128*Mo + accM[k];
  }
}

__global__ void k_mul(const float* __restrict__ so, const float* __restrict__ mo,
                      float* __restrict__ outs, int s)
{
  int l = blockIdx.x, b = blockIdx.y, tid = threadIdx.x;
  long src = ((long)b*SEG_ + l)*D_ + tid*4;
  float4 a = *(const float4*)(so + src);
  float4 c = *(const float4*)(mo + src);
  a.x*=c.x; a.y*=c.y; a.z*=c.z; a.w*=c.w;
  *(float4*)(outs + ((long)b*N_ + s*SEG_ + l)*D_ + tid*4) = a;
}

// ---------------- host launcher ----------------
static inline void gemm(const float* A, const float* Bm, const float* bias, float* C,
                        int M, int N, int K, long sA, long sB, long sC, long sBias,
                        int batch, int bt, int silu_, hipStream_t st)
{
  dim3 g(N/64, (M+63)/64, batch), blk(256);
  if (!bt && !silu_) k_gemm<0,0><<<g,blk,0,st>>>(A,Bm,bias,C,M,N,K,sA,sB,sC,sBias);
  else if (!bt && silu_) k_gemm<0,1><<<g,blk,0,st>>>(A,Bm,bias,C,M,N,K,sA,sB,sC,sBias);
  else k_gemm<1,0><<<g,blk,0,st>>>(A,Bm,bias,C,M,N,K,sA,sB,sC,sBias);
}

extern "C" void kernel_launch(void* const* d_in, const int* in_sizes, int n_in,
                              void* d_out, int out_size, void* d_ws, size_t ws_size,
                              hipStream_t stream)
{
  (void)in_sizes; (void)n_in; (void)out_size; (void)ws_size;
  const int*   x     = (const int*)  d_in[0];
  const float* emb   = (const float*)d_in[1];
  const float* pers  = (const float*)d_in[2];
  const float* Wq    = (const float*)d_in[3];
  const float* bq    = (const float*)d_in[4];
  const float* Wk    = (const float*)d_in[5];
  const float* bk    = (const float*)d_in[6];
  const float* Wv    = (const float*)d_in[7];
  const float* bv    = (const float*)d_in[8];
  const float* aiw   = (const float*)d_in[9];
  const float* aib   = (const float*)d_in[10];
  const float* aow   = (const float*)d_in[11];
  const float* aob   = (const float*)d_in[12];
  const float* mW1in = (const float*)d_in[13];
  const float* mb1in = (const float*)d_in[14];
  const float* mW2in = (const float*)d_in[15];
  const float* mb2in = (const float*)d_in[16];
  const float* headw = (const float*)d_in[17];
  const float* headb = (const float*)d_in[18];
  float* out = (float*)d_out;
  float* ws  = (float*)d_ws;

  hipMemsetAsync(ws + MOM, 0, MOMSZ*sizeof(float), stream);
  hipMemsetAsync(ws + ZEROB, 0, 128*sizeof(float), stream);
  hipMemsetAsync(ws + CBAR, 0, (size_t)B_*NB2_*FSTR_*sizeof(int), stream);
  k_embed<<<dim3(B_*N_), dim3(256), 0, stream>>>(x, emb, ws+XEMB);
  k_init<<<dim3((2*PER_+255)/256), dim3(256), 0, stream>>>(
      mW1in, mb1in, mW2in, mb2in, ws+PW1, ws+PB1, ws+PW2T, ws+PB2);
  k_coef<<<dim3(1), dim3(64), 0, stream>>>(ws+COEF);

  for (int s = 0; s < NSEG_; s++) {
    const float* segA = ws + XEMB + (size_t)s*SEG_*D_;
    // h = mlp(p, l2n(seg @ Wq + bq))  (Q-proj via MFMA)
    k_gemm_mfma<<<dim3(8, 1, B_), dim3(256), 0, stream>>>(
        segA, Wq, bq, ws+Q1, SEG_, D_, D_, (long)N_*D_, 0, (long)SEG_*D_, 0);
    k_l2n<<<dim3(B_*SEG_), dim3(256), 0, stream>>>(ws+Q1);
    gemm(ws+Q1, ws+PW1, ws+PB1, ws+AH, SEG_, W_, D_, (long)SEG_*D_, (long)D_*W_, (long)SEG_*W_, W_, B_, 0, 1, stream);
    gemm(ws+AH, ws+PW2T, ws+PB2, ws+HBUF, SEG_, D_, W_, (long)SEG_*W_, (long)D_*W_, (long)SEG_*D_, D_, B_, 1, 0, stream);
    // attention
    k_concat<<<dim3(T_, B_), dim3(256), 0, stream>>>(pers, ws+HBUF, ws+XEMB, s, ws+COMB);
    k_gemm_mfma<<<dim3(3*D_/128, (B_*T_+127)/128, 1), dim3(256), 0, stream>>>(
        ws+COMB, aiw, aib, ws+QKV, B_*T_, 3*D_, D_, 0, 0, 0, 0);
    k_attn<<<dim3(8, NH_, B_), dim3(256), 0, stream>>>(ws+QKV, ws+ATTN);
    k_gemm_mfma<<<dim3(D_/128, 2, 1), dim3(256), 0, stream>>>(
        ws+ATTN, aow, aob, ws+SEGO, B_*SEG_, D_, D_, 0, 0, 0, 0);
    // fused K/V/Q projections of seg_out (MFMA)
    k_gemmkvq_m<<<dim3(24, 2), dim3(256), 0, stream>>>(
        ws+SEGO, Wk, bk, Wv, bv, Wq, bq, ws+KM, ws+VM, ws+Q1);
    k_l2n<<<dim3(B_*SEG_), dim3(256), 0, stream>>>(ws+KM);
    k_l2n<<<dim3(B_*SEG_), dim3(256), 0, stream>>>(ws+Q1);
    // scan precompute: {Q1K, Q1Km} fused; G = K@K^T
    k_gemm2<<<dim3(2, 2, B_), dim3(256), 0, stream>>>(
        ws+KM, ws+PW1, ws+MW1, ws+AQ1K, ws+AQ1KM,
        D_, (long)SEG_*D_, (long)D_*W_, (long)SEG_*W_);
    gemm(ws+KM, ws+KM,  ws+ZEROB, ws+AGRAM, SEG_, SEG_, D_, (long)SEG_*D_, (long)SEG_*D_, (long)SEG_*SEG_, 0, B_, 1, 0, stream);
    // the scan (register-resident W, one barrier per token)
    k_scan<<<dim3(NB2_, B_), dim3(256), 0, stream>>>(
        ws+PW2T, ws+MW2T, ws+PB1, ws+MB1, ws+PB2, ws+MB2, ws+VM,
        ws+AQ1K, ws+AQ1KM, ws+AGRAM,
        ws+ADZ1, ws+AA1H, ws+AEH,
        ws+AEXR, ws+AEXEE,
        ws+COEF, (int*)(ws+CBAR), s);
    // reconstruct weights/momenta
    k_recon<<<dim3(32, 2, 4), dim3(256), 0, stream>>>(
        ws+PW1, ws+MW1, ws+PW2T, ws+MW2T,
        ws+KM, ws+AEH, ws+ADZ1, ws+AA1H, ws+COEF);
    // mem_out = mlp(p_new, Q1)
    gemm(ws+Q1, ws+PW1, ws+PB1, ws+AH, SEG_, W_, D_, (long)SEG_*D_, (long)D_*W_, (long)SEG_*W_, W_, B_, 0, 1, stream);
    gemm(ws+AH, ws+PW2T, ws+PB2, ws+MEMO, SEG_, D_, W_, (long)SEG_*W_, (long)D_*W_, (long)SEG_*D_, D_, B_, 1, 0, stream);
    k_mul<<<dim3(SEG_, B_), dim3(256), 0, stream>>>(ws+SEGO, ws+MEMO, ws+OUTS, s);
  }
  // head via bf16-split MFMA
  k_head_mfma<<<dim3(V_/128, (B_*N_)/128), dim3(256), 0, stream>>>(
      ws+OUTS, headw, headb, out, B_*N_, V_, D_);
}